// Round 1
// baseline (437.678 us; speedup 1.0000x reference)
//
#include <hip/hip_runtime.h>
#include <hip/hip_bf16.h>
#include <math.h>

typedef __hip_bfloat16 bf16;
typedef __attribute__((ext_vector_type(8))) short short8;
typedef __attribute__((ext_vector_type(4))) float floatx4;
typedef __attribute__((ext_vector_type(2))) float f32x2;
typedef _Float16 h2 __attribute__((ext_vector_type(2)));

#define HH 40
#define WW 40
#define CC 128
#define TT 8
#define NIMG 16           // B*T
#define NTOK 25600        // NIMG*HH*WW
#define MDIM 512
#define NHEAD 4
#define KVP 1608          // K/V LDS plane stride in elems

// weight-transpose buffer offsets (bf16 elems), per layer
#define WT_QKV 0
#define WT_PROJ 49152
#define WT_FC1  65536
#define WT_FC2  131072
#define WT_L    196608

// ---- input transpose via LDS tiles: x (b,c,t,y,x) -> h (n,y,x,c), both coalesced.
__global__ __launch_bounds__(256) void k_transpose_in(const float* __restrict__ x,
                                                      float* __restrict__ h) {
    int blk = blockIdx.x;
    int n = blk / 200; int r = blk % 200; int ci = r / 50, ri = r % 50;
    int b = n >> 3, t = n & 7;
    int c0 = ci * 32, r0 = ri * 32;
    __shared__ float tile[32][33];
    int tid = threadIdx.x;
    int lc = tid >> 5, lr = tid & 31;         // 8 x 32
    #pragma unroll
    for (int it = 0; it < 4; ++it) {
        int cc = it * 8 + lc;
        tile[cc][lr] = x[((size_t)((b * 128 + c0 + cc) * 8 + t)) * 1600 + r0 + lr];
    }
    __syncthreads();
    #pragma unroll
    for (int it = 0; it < 4; ++it) {
        int rr = it * 8 + lc;
        h[((size_t)(n * 1600 + r0 + rr)) * 128 + c0 + lr] = tile[lr][rr];
    }
}

// ---- weight convert+transpose: W[K,N] fp32 -> Wt[N,K] bf16, 64x64 LDS tiles.
__global__ __launch_bounds__(256) void k_wt(const float* __restrict__ qkv_w,
                                            const float* __restrict__ proj_w,
                                            const float* __restrict__ fc1_w,
                                            const float* __restrict__ fc2_w,
                                            bf16* __restrict__ wt) {
    __shared__ float tile[64][65];
    int id = blockIdx.x;
    int l = id / 48, r = id % 48;
    const float* src; bf16* dst; int K_, N_, t;
    if (r < 12)      { src = qkv_w  + l * 128 * 384; dst = wt + l * WT_L + WT_QKV; K_ = 128; N_ = 384; t = r; }
    else if (r < 16) { src = proj_w + l * 128 * 128; dst = wt + l * WT_L + WT_PROJ; K_ = 128; N_ = 128; t = r - 12; }
    else if (r < 32) { src = fc1_w  + l * 128 * 512; dst = wt + l * WT_L + WT_FC1; K_ = 128; N_ = 512; t = r - 16; }
    else             { src = fc2_w  + l * 512 * 128; dst = wt + l * WT_L + WT_FC2; K_ = 512; N_ = 128; t = r - 32; }
    int KT = K_ >> 6;
    int k0 = (t % KT) * 64, n0 = (t / KT) * 64;
    int tid = threadIdx.x;
    for (int c = tid; c < 4096; c += 256) {
        int kk = c >> 6, nn = c & 63;
        tile[kk][nn] = src[(size_t)(k0 + kk) * N_ + n0 + nn];
    }
    __syncthreads();
    for (int c = tid; c < 4096; c += 256) {
        int nn = c >> 6, kk = c & 63;
        dst[(size_t)(n0 + nn) * K_ + k0 + kk] = __float2bfloat16(tile[kk][nn]);
    }
}

// ---- fused LayerNorm + MFMA GEMM (fp32 A): only layer-0 qkv.
template<typename OutT>
__global__ __launch_bounds__(256) void k_lngemm(const float* __restrict__ A,
                                                const bf16* __restrict__ Bt,
                                                const float* __restrict__ g,
                                                const float* __restrict__ be,
                                                const float* __restrict__ bias,
                                                OutT* __restrict__ D,
                                                int N) {
    constexpr int LDK = 40;
    __shared__ bf16 As[64 * LDK];
    __shared__ bf16 Bs[128 * LDK];
    __shared__ float sMean[64], sRstd[64], sG[128], sB[128];
    int tid = threadIdx.x;
    int m0 = blockIdx.y * 64, n0 = blockIdx.x * 128;
    {
        int row = tid >> 2, q4 = tid & 3;
        const float* p = A + (size_t)(m0 + row) * 128 + q4 * 32;
        float s = 0.f, q = 0.f;
        #pragma unroll
        for (int i = 0; i < 32; i += 4) {
            float4 f = *(const float4*)(p + i);
            s += f.x + f.y + f.z + f.w;
            q += f.x * f.x + f.y * f.y + f.z * f.z + f.w * f.w;
        }
        s += __shfl_xor(s, 1); q += __shfl_xor(q, 1);
        s += __shfl_xor(s, 2); q += __shfl_xor(q, 2);
        if (q4 == 0) {
            float mean = s * (1.0f / 128.0f);
            float var = q * (1.0f / 128.0f) - mean * mean;
            sMean[row] = mean;
            sRstd[row] = rsqrtf(var + 1e-5f);
        }
        if (tid < 128) { sG[tid] = g[tid]; sB[tid] = be[tid]; }
    }
    __syncthreads();
    int wave = tid >> 6, lane = tid & 63;
    int l15 = lane & 15, quad = lane >> 4;
    int wr = wave >> 1, wc = wave & 1;
    floatx4 acc[2][4];
    #pragma unroll
    for (int i = 0; i < 2; ++i)
        #pragma unroll
        for (int j = 0; j < 4; ++j)
            acc[i][j] = (floatx4){0.f, 0.f, 0.f, 0.f};

    for (int k0 = 0; k0 < 128; k0 += 32) {
        #pragma unroll
        for (int it = 0; it < 2; ++it) {
            int c = tid + it * 256;
            int row = c >> 3, kq = (c & 7) * 4;
            float4 f = *(const float4*)(A + (size_t)(m0 + row) * 128 + k0 + kq);
            float mean = sMean[row], rst = sRstd[row];
            float r0v = (f.x - mean) * rst * sG[k0 + kq]     + sB[k0 + kq];
            float r1v = (f.y - mean) * rst * sG[k0 + kq + 1] + sB[k0 + kq + 1];
            float r2v = (f.z - mean) * rst * sG[k0 + kq + 2] + sB[k0 + kq + 2];
            float r3v = (f.w - mean) * rst * sG[k0 + kq + 3] + sB[k0 + kq + 3];
            __hip_bfloat162 p0, p1;
            p0.x = __float2bfloat16(r0v); p0.y = __float2bfloat16(r1v);
            p1.x = __float2bfloat16(r2v); p1.y = __float2bfloat16(r3v);
            *(__hip_bfloat162*)&As[row * LDK + kq]     = p0;
            *(__hip_bfloat162*)&As[row * LDK + kq + 2] = p1;
        }
        #pragma unroll
        for (int c = tid; c < 512; c += 256) {
            int row = c >> 2, off = (c & 3) * 8;
            *(uint4*)&Bs[row * LDK + off] =
                *(const uint4*)&Bt[(size_t)(n0 + row) * 128 + k0 + off];
        }
        __syncthreads();
        short8 af[2], bfr[4];
        #pragma unroll
        for (int i = 0; i < 2; ++i)
            af[i] = *(const short8*)&As[(wr * 32 + i * 16 + l15) * LDK + quad * 8];
        #pragma unroll
        for (int j = 0; j < 4; ++j)
            bfr[j] = *(const short8*)&Bs[(wc * 64 + j * 16 + l15) * LDK + quad * 8];
        #pragma unroll
        for (int i = 0; i < 2; ++i)
            #pragma unroll
            for (int j = 0; j < 4; ++j)
                acc[i][j] = __builtin_amdgcn_mfma_f32_16x16x32_bf16(af[i], bfr[j], acc[i][j], 0, 0, 0);
        __syncthreads();
    }
    #pragma unroll
    for (int i = 0; i < 2; ++i) {
        #pragma unroll
        for (int j = 0; j < 4; ++j) {
            int nn = n0 + wc * 64 + j * 16 + l15;
            float bv = bias[nn];
            #pragma unroll
            for (int rg = 0; rg < 4; ++rg) {
                int m = m0 + wr * 32 + i * 16 + quad * 4 + rg;
                float v = acc[i][j][rg] + bv;
                if constexpr (sizeof(OutT) == 2)
                    D[(size_t)m * N + nn] = __float2bfloat16(v);
                else
                    D[(size_t)m * N + nn] = v;
            }
        }
    }
}

// ---- MFMA bf16 GEMM: D[M,N] = A[M,K] @ Bt[N,K]^T + bias (+R).
template<int BM, int BN, int WM, int WN, typename OutT>
__global__ __launch_bounds__(256) void k_gemm_mfma(const bf16* __restrict__ A,
                                                   const bf16* __restrict__ Bt,
                                                   const float* __restrict__ bias,
                                                   const float* __restrict__ R,
                                                   OutT* __restrict__ D,
                                                   int K, int N) {
    constexpr int LDK = 40;
    __shared__ bf16 As[BM * LDK];
    __shared__ bf16 Bs[BN * LDK];
    int tid = threadIdx.x;
    int wave = tid >> 6, lane = tid & 63;
    int l15 = lane & 15, quad = lane >> 4;
    constexpr int WCOLS = BN / WN;
    int wr = wave / WCOLS, wc = wave % WCOLS;
    int m0 = blockIdx.y * BM, n0 = blockIdx.x * BN;
    constexpr int MI = WM / 16, NJ = WN / 16;
    floatx4 acc[MI][NJ];
    #pragma unroll
    for (int i = 0; i < MI; ++i)
        #pragma unroll
        for (int j = 0; j < NJ; ++j)
            acc[i][j] = (floatx4){0.f, 0.f, 0.f, 0.f};

    for (int k0 = 0; k0 < K; k0 += 32) {
        #pragma unroll
        for (int c = tid; c < BM * 4; c += 256) {
            int row = c >> 2, off = (c & 3) * 8;
            *(uint4*)&As[row * LDK + off] =
                *(const uint4*)&A[(size_t)(m0 + row) * K + k0 + off];
        }
        #pragma unroll
        for (int c = tid; c < BN * 4; c += 256) {
            int row = c >> 2, off = (c & 3) * 8;
            *(uint4*)&Bs[row * LDK + off] =
                *(const uint4*)&Bt[(size_t)(n0 + row) * K + k0 + off];
        }
        __syncthreads();
        short8 af[MI], bfr[NJ];
        #pragma unroll
        for (int i = 0; i < MI; ++i)
            af[i] = *(const short8*)&As[(wr * WM + i * 16 + l15) * LDK + quad * 8];
        #pragma unroll
        for (int j = 0; j < NJ; ++j)
            bfr[j] = *(const short8*)&Bs[(wc * WN + j * 16 + l15) * LDK + quad * 8];
        #pragma unroll
        for (int i = 0; i < MI; ++i)
            #pragma unroll
            for (int j = 0; j < NJ; ++j)
                acc[i][j] = __builtin_amdgcn_mfma_f32_16x16x32_bf16(af[i], bfr[j], acc[i][j], 0, 0, 0);
        __syncthreads();
    }
    #pragma unroll
    for (int i = 0; i < MI; ++i) {
        #pragma unroll
        for (int j = 0; j < NJ; ++j) {
            int nn = n0 + wc * WN + j * 16 + l15;
            float bv = bias[nn];
            #pragma unroll
            for (int rg = 0; rg < 4; ++rg) {
                int m = m0 + wr * WM + i * 16 + quad * 4 + rg;
                float v = acc[i][j][rg] + bv;
                if (R) v += R[(size_t)m * N + nn];
                if constexpr (sizeof(OutT) == 2)
                    D[(size_t)m * N + nn] = __float2bfloat16(v);
                else
                    D[(size_t)m * N + nn] = v;
            }
        }
    }
}

// ---- GEMM (N=128) + residual + fused next-LayerNorm epilogue.
__global__ __launch_bounds__(256) void k_gemm_ln(const bf16* __restrict__ A,
                                                 const bf16* __restrict__ Bt,
                                                 const float* __restrict__ bias,
                                                 const float* __restrict__ R,
                                                 const float* __restrict__ g,
                                                 const float* __restrict__ be,
                                                 float* __restrict__ Dres,
                                                 bf16* __restrict__ Aout,
                                                 int K) {
    constexpr int LDK = 40;
    __shared__ bf16 As[32 * LDK];
    __shared__ bf16 Bs[128 * LDK];
    __shared__ float ot[32][132];
    __shared__ float sG[128], sB[128];
    int tid = threadIdx.x;
    int wave = tid >> 6, lane = tid & 63;
    int l15 = lane & 15, quad = lane >> 4;
    int wr = wave >> 1, wc = wave & 1;
    int m0 = blockIdx.x * 32;
    if (tid < 128) { sG[tid] = g[tid]; sB[tid] = be[tid]; }
    floatx4 acc[4];
    #pragma unroll
    for (int j = 0; j < 4; ++j) acc[j] = (floatx4){0.f, 0.f, 0.f, 0.f};

    for (int k0 = 0; k0 < K; k0 += 32) {
        if (tid < 128) {
            int row = tid >> 2, off = (tid & 3) * 8;
            *(uint4*)&As[row * LDK + off] =
                *(const uint4*)&A[(size_t)(m0 + row) * K + k0 + off];
        }
        #pragma unroll
        for (int c = tid; c < 512; c += 256) {
            int row = c >> 2, off = (c & 3) * 8;
            *(uint4*)&Bs[row * LDK + off] =
                *(const uint4*)&Bt[(size_t)row * K + k0 + off];
        }
        __syncthreads();
        short8 af = *(const short8*)&As[(wr * 16 + l15) * LDK + quad * 8];
        short8 bfr[4];
        #pragma unroll
        for (int j = 0; j < 4; ++j)
            bfr[j] = *(const short8*)&Bs[(wc * 64 + j * 16 + l15) * LDK + quad * 8];
        #pragma unroll
        for (int j = 0; j < 4; ++j)
            acc[j] = __builtin_amdgcn_mfma_f32_16x16x32_bf16(af, bfr[j], acc[j], 0, 0, 0);
        __syncthreads();
    }
    #pragma unroll
    for (int j = 0; j < 4; ++j) {
        int nn = wc * 64 + j * 16 + l15;
        float bv = bias[nn];
        #pragma unroll
        for (int rg = 0; rg < 4; ++rg) {
            int m = wr * 16 + quad * 4 + rg;
            ot[m][nn] = acc[j][rg] + bv + R[(size_t)(m0 + m) * 128 + nn];
        }
    }
    __syncthreads();
    int row = tid >> 3, sub = tid & 7;
    float vv[16];
    float s = 0.f, q = 0.f;
    #pragma unroll
    for (int i = 0; i < 16; ++i) {
        float v = ot[row][sub * 16 + i];
        vv[i] = v; s += v; q += v * v;
    }
    #pragma unroll
    for (int o = 4; o > 0; o >>= 1) { s += __shfl_xor(s, o); q += __shfl_xor(q, o); }
    float mean = s * (1.0f / 128.0f);
    float var = q * (1.0f / 128.0f) - mean * mean;
    float rst = rsqrtf(var + 1e-5f);
    size_t base = (size_t)(m0 + row) * 128 + sub * 16;
    #pragma unroll
    for (int i = 0; i < 16; i += 4)
        *(float4*)(Dres + base + i) = (float4){vv[i], vv[i+1], vv[i+2], vv[i+3]};
    #pragma unroll
    for (int i = 0; i < 16; i += 2) {
        int ch = sub * 16 + i;
        __hip_bfloat162 o2;
        o2.x = __float2bfloat16((vv[i]     - mean) * rst * sG[ch]     + sB[ch]);
        o2.y = __float2bfloat16((vv[i + 1] - mean) * rst * sG[ch + 1] + sB[ch + 1]);
        *(__hip_bfloat162*)(Aout + base + i) = o2;
    }
}

// ---- GEMM (N=128) + residual + FINAL LayerNorm + transposed store to (b,c,t,y,x).
__global__ __launch_bounds__(256) void k_gemm_lnout(const bf16* __restrict__ A,
                                                    const bf16* __restrict__ Bt,
                                                    const float* __restrict__ bias,
                                                    const float* __restrict__ R,
                                                    const float* __restrict__ g,
                                                    const float* __restrict__ be,
                                                    float* __restrict__ out,
                                                    int K) {
    constexpr int LDK = 40;
    __shared__ bf16 As[32 * LDK];
    __shared__ bf16 Bs[128 * LDK];
    __shared__ float ot[32][133];    // pad 133: conflict-free transposed reads
    __shared__ float sG[128], sB[128];
    int tid = threadIdx.x;
    int wave = tid >> 6, lane = tid & 63;
    int l15 = lane & 15, quad = lane >> 4;
    int wr = wave >> 1, wc = wave & 1;
    int m0 = blockIdx.x * 32;
    if (tid < 128) { sG[tid] = g[tid]; sB[tid] = be[tid]; }
    floatx4 acc[4];
    #pragma unroll
    for (int j = 0; j < 4; ++j) acc[j] = (floatx4){0.f, 0.f, 0.f, 0.f};

    for (int k0 = 0; k0 < K; k0 += 32) {
        if (tid < 128) {
            int row = tid >> 2, off = (tid & 3) * 8;
            *(uint4*)&As[row * LDK + off] =
                *(const uint4*)&A[(size_t)(m0 + row) * K + k0 + off];
        }
        #pragma unroll
        for (int c = tid; c < 512; c += 256) {
            int row = c >> 2, off = (c & 3) * 8;
            *(uint4*)&Bs[row * LDK + off] =
                *(const uint4*)&Bt[(size_t)row * K + k0 + off];
        }
        __syncthreads();
        short8 af = *(const short8*)&As[(wr * 16 + l15) * LDK + quad * 8];
        short8 bfr[4];
        #pragma unroll
        for (int j = 0; j < 4; ++j)
            bfr[j] = *(const short8*)&Bs[(wc * 64 + j * 16 + l15) * LDK + quad * 8];
        #pragma unroll
        for (int j = 0; j < 4; ++j)
            acc[j] = __builtin_amdgcn_mfma_f32_16x16x32_bf16(af, bfr[j], acc[j], 0, 0, 0);
        __syncthreads();
    }
    #pragma unroll
    for (int j = 0; j < 4; ++j) {
        int nn = wc * 64 + j * 16 + l15;
        float bv = bias[nn];
        #pragma unroll
        for (int rg = 0; rg < 4; ++rg) {
            int m = wr * 16 + quad * 4 + rg;
            ot[m][nn] = acc[j][rg] + bv + R[(size_t)(m0 + m) * 128 + nn];
        }
    }
    __syncthreads();
    int row = tid >> 3, sub = tid & 7;
    float vv[16];
    float s = 0.f, q = 0.f;
    #pragma unroll
    for (int i = 0; i < 16; ++i) {
        float v = ot[row][sub * 16 + i];
        vv[i] = v; s += v; q += v * v;
    }
    #pragma unroll
    for (int o = 4; o > 0; o >>= 1) { s += __shfl_xor(s, o); q += __shfl_xor(q, o); }
    float mean = s * (1.0f / 128.0f);
    float var = q * (1.0f / 128.0f) - mean * mean;
    float rst = rsqrtf(var + 1e-5f);
    #pragma unroll
    for (int i = 0; i < 16; ++i) {
        int ch = sub * 16 + i;
        ot[row][ch] = (vv[i] - mean) * rst * sG[ch] + sB[ch];
    }
    __syncthreads();
    int n = m0 / 1600, rem0 = m0 % 1600;
    int b = n >> 3, t = n & 7;
    #pragma unroll
    for (int it = 0; it < 16; ++it) {
        int idx = it * 256 + tid;
        int ch = idx >> 5, tk = idx & 31;
        out[((size_t)((b * 128 + ch) * 8 + t)) * 1600 + rem0 + tk] = ot[tk][ch];
    }
}

// ---- row-tiled 7x7 neighborhood attention; f16 K + fdot2 logits, q in LDS (f16).
// XCD-locality swizzle: same-XCD blocks get consecutive y (shared K/V windows).
__global__ __launch_bounds__(256) void k_attn(const bf16* __restrict__ qkv,
                                              const float* __restrict__ rpb,
                                              bf16* __restrict__ out) {
    int raw = blockIdx.x;                       // grid 2560
    int blk = (raw & 7) * 320 + (raw >> 3);     // chunk per XCD
    int head = blk & 3;
    int ny = blk >> 2;
    int n = ny / 40, y = ny % 40;
    int sy = min(max(y - 3, 0), HH - 7);
    __shared__ __align__(16) short KVs[7 * KVP];   // K (f16) then V (bf16)
    __shared__ __align__(16) short qs[40 * 40];    // q as f16, stride 40 (3.2 KB)
    __shared__ float lg[40][49];
    int tid = threadIdx.x;
    // q staging: bf16 -> f16, 160 threads x 8 elems
    if (tid < 160) {
        int xq = tid >> 2, d8 = (tid & 3) * 8;
        union { uint4 u; __hip_bfloat162 b[4]; } U;
        U.u = *(const uint4*)(qkv + ((size_t)(n * 1600 + y * 40 + xq)) * 384 + head * 32 + d8);
        union { short8 s; h2 h[4]; } W;
        #pragma unroll
        for (int c = 0; c < 4; ++c) {
            float2 f = __bfloat1622float2(U.b[c]);
            W.h[c].x = (_Float16)f.x; W.h[c].y = (_Float16)f.y;
        }
        *(short8*)&qs[xq * 40 + d8] = W.s;
    }
    // phase 1: K window, bf16 -> f16 in staging
    for (int i2 = tid; i2 < 1120; i2 += 256) {
        int d8 = i2 & 3, kx = (i2 >> 2) % 40, ky = i2 / 160;
        size_t base = ((size_t)(n * 1600 + (sy + ky) * 40 + kx)) * 384 + 128 + head * 32 + d8 * 8;
        union { uint4 u; __hip_bfloat162 b[4]; } U;
        U.u = *(const uint4*)(qkv + base);
        union { short8 s; h2 h[4]; } W;
        #pragma unroll
        for (int c = 0; c < 4; ++c) {
            float2 f = __bfloat1622float2(U.b[c]);
            W.h[c].x = (_Float16)f.x; W.h[c].y = (_Float16)f.y;
        }
        *(short8*)&KVs[ky * KVP + kx * 40 + d8 * 8] = W.s;
    }
    __syncthreads();
    // logits: thread per (xq, ky); q read from LDS as f16
    for (int p2 = tid; p2 < 280; p2 += 256) {
        int xq = p2 / 7, ky = p2 - (p2 / 7) * 7;
        int sx = min(max(xq - 3, 0), WW - 7);
        const h2* qp = (const h2*)&qs[xq * 40];
        h2 qh[16];
        #pragma unroll
        for (int c = 0; c < 16; ++c) qh[c] = qp[c];
        const float* rb = rpb + head * 169 + (sy + ky - y + 6) * 13 + (sx - xq + 6);
        int kbase = ky * KVP + sx * 40;
        #pragma unroll
        for (int jx = 0; jx < 7; ++jx) {
            const h2* kp = (const h2*)&KVs[kbase + jx * 40];
            float dot = 0.f;
            #pragma unroll
            for (int c = 0; c < 16; ++c)
                dot = __builtin_amdgcn_fdot2(qh[c], kp[c], dot, false);
            lg[xq][ky * 7 + jx] = dot * 0.1767766952966369f + rb[jx];
        }
    }
    __syncthreads();
    // phase 2: V window (raw bf16 bits), softmax concurrently
    for (int i2 = tid; i2 < 1120; i2 += 256) {
        int d8 = i2 & 3, kx = (i2 >> 2) % 40, ky = i2 / 160;
        size_t base = ((size_t)(n * 1600 + (sy + ky) * 40 + kx)) * 384 + 256 + head * 32 + d8 * 8;
        *(uint4*)&KVs[ky * KVP + kx * 40 + d8 * 8] = *(const uint4*)(qkv + base);
    }
    if (tid < 40) {
        float m = -1e30f;
        for (int j = 0; j < 49; ++j) m = fmaxf(m, lg[tid][j]);
        float s = 0.f;
        for (int j = 0; j < 49; ++j) { float e = expf(lg[tid][j] - m); lg[tid][j] = e; s += e; }
        float inv = 1.0f / s;
        for (int j = 0; j < 49; ++j) lg[tid][j] *= inv;
    }
    __syncthreads();
    for (int o = tid; o < 640; o += 256) {         // PV reduce (bf16 V)
        int xq = o >> 4, dp = (o & 15) * 2;
        int sx = min(max(xq - 3, 0), WW - 7);
        float a0 = 0.f, a1 = 0.f;
        #pragma unroll
        for (int ky = 0; ky < 7; ++ky) {
            int vbase = ky * KVP + sx * 40 + dp;
            #pragma unroll
            for (int jx = 0; jx < 7; ++jx) {
                float p = lg[xq][ky * 7 + jx];
                float2 v = __bfloat1622float2(*(const __hip_bfloat162*)&KVs[vbase + jx * 40]);
                a0 += p * v.x; a1 += p * v.y;
            }
        }
        __hip_bfloat162 o2;
        o2.x = __float2bfloat16(a0); o2.y = __float2bfloat16(a1);
        *(__hip_bfloat162*)(out + ((size_t)(n * 1600 + y * 40 + xq)) * 128 + head * 32 + dp) = o2;
    }
}

// ---- depthwise 3x3x3 conv + bias + exact GELU; fp32 in, bf16 out.
// v2: 2 channels/thread (float2 loads, half the load instructions), one-iteration
// software-pipelined x-walk (cn prefetch), row validity folded into zeroed weights
// with clamped (always in-bounds) row offsets -> branch-free inner loop.
// XCD-locality swizzle: same-XCD blocks get consecutive (n,y) chunks (shared rows).
__global__ __launch_bounds__(256, 3) void k_dwconv(const float* __restrict__ inp,
                                                   const float* __restrict__ w,
                                                   const float* __restrict__ bias,
                                                   bf16* __restrict__ outp) {
    int raw = blockIdx.x;                       // grid 1280
    int blk = (raw & 7) * 160 + (raw >> 3);     // chunk per XCD
    int xh = blk & 1;
    int ny = blk >> 1;
    int n = ny / 40, y = ny - n * 40;
    int b = n >> 3, t = n & 7;
    int m = threadIdx.x * 2;                    // channel pair
    f32x2 wr[27];
    int roff[9];                                // uniform -> SGPRs
    #pragma unroll
    for (int dt = 0; dt < 3; ++dt) {
        #pragma unroll
        for (int dy = 0; dy < 3; ++dy) {
            int p = dt * 3 + dy;
            int tt = t + dt - 1, yy = y + dy - 1;
            bool v = (tt >= 0 && tt < 8 && yy >= 0 && yy < 40);
            int tc = min(max(tt, 0), 7), yc = min(max(yy, 0), 39);
            roff[p] = ((b * 8 + tc) * 1600 + yc * 40) * 512;
            #pragma unroll
            for (int q = 0; q < 3; ++q) {
                f32x2 wv = *(const f32x2*)(w + (p * 3 + q) * 512 + m);
                wr[p * 3 + q] = v ? wv : (f32x2){0.f, 0.f};
            }
        }
    }
    f32x2 bs = *(const f32x2*)(bias + m);
    int x0 = xh * 20;
    f32x2 c0[9], c1[9], c2[9];
    #pragma unroll
    for (int p = 0; p < 9; ++p) {
        c0[p] = (x0 > 0) ? *(const f32x2*)(inp + roff[p] + (x0 - 1) * 512 + m)
                         : (f32x2){0.f, 0.f};
        c1[p] = *(const f32x2*)(inp + roff[p] + x0 * 512 + m);
        c2[p] = *(const f32x2*)(inp + roff[p] + (x0 + 1) * 512 + m);
    }
    size_t outbase = ((size_t)(n * 1600 + y * 40)) * 512 + m;
    for (int x = x0; x < x0 + 20; ++x) {
        int xn = x + 2;                          // prefetch column for next iter
        f32x2 cn[9];
        #pragma unroll
        for (int p = 0; p < 9; ++p)
            cn[p] = (xn < 40) ? *(const f32x2*)(inp + roff[p] + xn * 512 + m)
                              : (f32x2){0.f, 0.f};
        f32x2 acc = bs;
        #pragma unroll
        for (int p = 0; p < 9; ++p) {
            acc += wr[p * 3 + 0] * c0[p];
            acc += wr[p * 3 + 1] * c1[p];
            acc += wr[p * 3 + 2] * c2[p];
        }
        float g0 = 0.5f * acc.x * (1.0f + erff(acc.x * 0.70710678118654752f));
        float g1 = 0.5f * acc.y * (1.0f + erff(acc.y * 0.70710678118654752f));
        __hip_bfloat162 o2;
        o2.x = __float2bfloat16(g0); o2.y = __float2bfloat16(g1);
        *(__hip_bfloat162*)&outp[outbase + (size_t)x * 512] = o2;
        #pragma unroll
        for (int p = 0; p < 9; ++p) { c0[p] = c1[p]; c1[p] = c2[p]; c2[p] = cn[p]; }
    }
}

extern "C" void kernel_launch(void* const* d_in, const int* in_sizes, int n_in,
                              void* d_out, int out_size, void* d_ws, size_t ws_size,
                              hipStream_t stream) {
    const float* x      = (const float*)d_in[0];
    const float* ln1_g  = (const float*)d_in[1];
    const float* ln1_b  = (const float*)d_in[2];
    const float* qkv_w  = (const float*)d_in[3];
    const float* qkv_b  = (const float*)d_in[4];
    const float* rpb    = (const float*)d_in[5];
    const float* proj_w = (const float*)d_in[6];
    const float* proj_b = (const float*)d_in[7];
    const float* ln2_g  = (const float*)d_in[8];
    const float* ln2_b  = (const float*)d_in[9];
    const float* fc1_w  = (const float*)d_in[10];
    const float* fc1_b  = (const float*)d_in[11];
    const float* dw_w   = (const float*)d_in[12];
    const float* dw_b   = (const float*)d_in[13];
    const float* fc2_w  = (const float*)d_in[14];
    const float* fc2_b  = (const float*)d_in[15];
    const float* out_g  = (const float*)d_in[16];
    const float* out_b  = (const float*)d_in[17];
    float* out = (float*)d_out;

    // workspace: h f32 | f1 f32 | qkvb bf16 | f2b bf16 | abufA bf16 | abufL bf16 | wt
    float* h     = (float*)d_ws;
    float* f1    = h + (size_t)NTOK * 128;
    bf16* qkvb   = (bf16*)(f1 + (size_t)NTOK * 512);
    bf16* f2b    = qkvb + (size_t)NTOK * 384;
    bf16* abufA  = f2b  + (size_t)NTOK * 512;
    bf16* abufL  = abufA + (size_t)NTOK * 128;
    bf16* wt     = abufL + (size_t)NTOK * 128;

    k_wt<<<96, 256, 0, stream>>>(qkv_w, proj_w, fc1_w, fc2_w, wt);
    k_transpose_in<<<NIMG * 200, 256, 0, stream>>>(x, h);
    for (int l = 0; l < 2; ++l) {
        const bf16* wtl = wt + (size_t)l * WT_L;
        if (l == 0) {
            k_lngemm<bf16><<<dim3(3, 400), 256, 0, stream>>>(
                h, wtl + WT_QKV, ln1_g, ln1_b, qkv_b, qkvb, 384);
        } else {
            k_gemm_mfma<64, 128, 32, 64, bf16><<<dim3(3, 400), 256, 0, stream>>>(
                abufL, wtl + WT_QKV, qkv_b + 384, nullptr, qkvb, 128, 384);
        }
        k_attn<<<NIMG * HH * NHEAD, 256, 0, stream>>>(qkvb, rpb + l * 4 * 169, abufA);
        // proj + residual + fused LN2 epilogue -> abufL
        k_gemm_ln<<<800, 256, 0, stream>>>(
            abufA, wtl + WT_PROJ, proj_b + l * 128, h,
            ln2_g + l * 128, ln2_b + l * 128, h, abufL, 128);
        // fc1: plain bf16-A GEMM
        k_gemm_mfma<64, 128, 32, 64, float><<<dim3(4, 400), 256, 0, stream>>>(
            abufL, wtl + WT_FC1, fc1_b + l * 512, nullptr, f1, 128, 512);
        k_dwconv<<<NIMG * HH * 2, 256, 0, stream>>>(f1, dw_w + l * 27 * 512, dw_b + l * 512, f2b);
        if (l == 0) {
            // fc2 + residual + fused LN1(layer 1) epilogue -> abufL
            k_gemm_ln<<<800, 256, 0, stream>>>(
                f2b, wtl + WT_FC2, fc2_b, h,
                ln1_g + 128, ln1_b + 128, h, abufL, 512);
        } else {
            // fc2 + residual + FINAL LN + transposed store
            k_gemm_lnout<<<800, 256, 0, stream>>>(
                f2b, wtl + WT_FC2, fc2_b + 128, h, out_g, out_b, out, 512);
        }
    }
}

// Round 2
// 387.362 us; speedup vs baseline: 1.1299x; 1.1299x over previous
//
#include <hip/hip_runtime.h>
#include <hip/hip_bf16.h>
#include <math.h>

typedef __hip_bfloat16 bf16;
typedef __attribute__((ext_vector_type(8))) short short8;
typedef __attribute__((ext_vector_type(4))) float floatx4;
typedef __attribute__((ext_vector_type(2))) float f32x2;
typedef _Float16 h2 __attribute__((ext_vector_type(2)));

#define HH 40
#define WW 40
#define CC 128
#define TT 8
#define NIMG 16           // B*T
#define NTOK 25600        // NIMG*HH*WW
#define MDIM 512
#define NHEAD 4
#define KVP 1608          // K/V LDS plane stride in elems

// weight-transpose buffer offsets (bf16 elems), per layer
#define WT_QKV 0
#define WT_PROJ 49152
#define WT_FC1  65536
#define WT_FC2  131072
#define WT_L    196608

// ---- input transpose via LDS tiles: x (b,c,t,y,x) -> h (n,y,x,c), both coalesced.
__global__ __launch_bounds__(256) void k_transpose_in(const float* __restrict__ x,
                                                      float* __restrict__ h) {
    int blk = blockIdx.x;
    int n = blk / 200; int r = blk % 200; int ci = r / 50, ri = r % 50;
    int b = n >> 3, t = n & 7;
    int c0 = ci * 32, r0 = ri * 32;
    __shared__ float tile[32][33];
    int tid = threadIdx.x;
    int lc = tid >> 5, lr = tid & 31;         // 8 x 32
    #pragma unroll
    for (int it = 0; it < 4; ++it) {
        int cc = it * 8 + lc;
        tile[cc][lr] = x[((size_t)((b * 128 + c0 + cc) * 8 + t)) * 1600 + r0 + lr];
    }
    __syncthreads();
    #pragma unroll
    for (int it = 0; it < 4; ++it) {
        int rr = it * 8 + lc;
        h[((size_t)(n * 1600 + r0 + rr)) * 128 + c0 + lr] = tile[lr][rr];
    }
}

// ---- weight convert+transpose: W[K,N] fp32 -> Wt[N,K] bf16, 64x64 LDS tiles.
__global__ __launch_bounds__(256) void k_wt(const float* __restrict__ qkv_w,
                                            const float* __restrict__ proj_w,
                                            const float* __restrict__ fc1_w,
                                            const float* __restrict__ fc2_w,
                                            bf16* __restrict__ wt) {
    __shared__ float tile[64][65];
    int id = blockIdx.x;
    int l = id / 48, r = id % 48;
    const float* src; bf16* dst; int K_, N_, t;
    if (r < 12)      { src = qkv_w  + l * 128 * 384; dst = wt + l * WT_L + WT_QKV; K_ = 128; N_ = 384; t = r; }
    else if (r < 16) { src = proj_w + l * 128 * 128; dst = wt + l * WT_L + WT_PROJ; K_ = 128; N_ = 128; t = r - 12; }
    else if (r < 32) { src = fc1_w  + l * 128 * 512; dst = wt + l * WT_L + WT_FC1; K_ = 128; N_ = 512; t = r - 16; }
    else             { src = fc2_w  + l * 512 * 128; dst = wt + l * WT_L + WT_FC2; K_ = 512; N_ = 128; t = r - 32; }
    int KT = K_ >> 6;
    int k0 = (t % KT) * 64, n0 = (t / KT) * 64;
    int tid = threadIdx.x;
    for (int c = tid; c < 4096; c += 256) {
        int kk = c >> 6, nn = c & 63;
        tile[kk][nn] = src[(size_t)(k0 + kk) * N_ + n0 + nn];
    }
    __syncthreads();
    for (int c = tid; c < 4096; c += 256) {
        int nn = c >> 6, kk = c & 63;
        dst[(size_t)(n0 + nn) * K_ + k0 + kk] = __float2bfloat16(tile[kk][nn]);
    }
}

// ---- fused LayerNorm + MFMA GEMM (fp32 A): only layer-0 qkv.
template<typename OutT>
__global__ __launch_bounds__(256) void k_lngemm(const float* __restrict__ A,
                                                const bf16* __restrict__ Bt,
                                                const float* __restrict__ g,
                                                const float* __restrict__ be,
                                                const float* __restrict__ bias,
                                                OutT* __restrict__ D,
                                                int N) {
    constexpr int LDK = 40;
    __shared__ bf16 As[64 * LDK];
    __shared__ bf16 Bs[128 * LDK];
    __shared__ float sMean[64], sRstd[64], sG[128], sB[128];
    int tid = threadIdx.x;
    int m0 = blockIdx.y * 64, n0 = blockIdx.x * 128;
    {
        int row = tid >> 2, q4 = tid & 3;
        const float* p = A + (size_t)(m0 + row) * 128 + q4 * 32;
        float s = 0.f, q = 0.f;
        #pragma unroll
        for (int i = 0; i < 32; i += 4) {
            float4 f = *(const float4*)(p + i);
            s += f.x + f.y + f.z + f.w;
            q += f.x * f.x + f.y * f.y + f.z * f.z + f.w * f.w;
        }
        s += __shfl_xor(s, 1); q += __shfl_xor(q, 1);
        s += __shfl_xor(s, 2); q += __shfl_xor(q, 2);
        if (q4 == 0) {
            float mean = s * (1.0f / 128.0f);
            float var = q * (1.0f / 128.0f) - mean * mean;
            sMean[row] = mean;
            sRstd[row] = rsqrtf(var + 1e-5f);
        }
        if (tid < 128) { sG[tid] = g[tid]; sB[tid] = be[tid]; }
    }
    __syncthreads();
    int wave = tid >> 6, lane = tid & 63;
    int l15 = lane & 15, quad = lane >> 4;
    int wr = wave >> 1, wc = wave & 1;
    floatx4 acc[2][4];
    #pragma unroll
    for (int i = 0; i < 2; ++i)
        #pragma unroll
        for (int j = 0; j < 4; ++j)
            acc[i][j] = (floatx4){0.f, 0.f, 0.f, 0.f};

    for (int k0 = 0; k0 < 128; k0 += 32) {
        #pragma unroll
        for (int it = 0; it < 2; ++it) {
            int c = tid + it * 256;
            int row = c >> 3, kq = (c & 7) * 4;
            float4 f = *(const float4*)(A + (size_t)(m0 + row) * 128 + k0 + kq);
            float mean = sMean[row], rst = sRstd[row];
            float r0v = (f.x - mean) * rst * sG[k0 + kq]     + sB[k0 + kq];
            float r1v = (f.y - mean) * rst * sG[k0 + kq + 1] + sB[k0 + kq + 1];
            float r2v = (f.z - mean) * rst * sG[k0 + kq + 2] + sB[k0 + kq + 2];
            float r3v = (f.w - mean) * rst * sG[k0 + kq + 3] + sB[k0 + kq + 3];
            __hip_bfloat162 p0, p1;
            p0.x = __float2bfloat16(r0v); p0.y = __float2bfloat16(r1v);
            p1.x = __float2bfloat16(r2v); p1.y = __float2bfloat16(r3v);
            *(__hip_bfloat162*)&As[row * LDK + kq]     = p0;
            *(__hip_bfloat162*)&As[row * LDK + kq + 2] = p1;
        }
        #pragma unroll
        for (int c = tid; c < 512; c += 256) {
            int row = c >> 2, off = (c & 3) * 8;
            *(uint4*)&Bs[row * LDK + off] =
                *(const uint4*)&Bt[(size_t)(n0 + row) * 128 + k0 + off];
        }
        __syncthreads();
        short8 af[2], bfr[4];
        #pragma unroll
        for (int i = 0; i < 2; ++i)
            af[i] = *(const short8*)&As[(wr * 32 + i * 16 + l15) * LDK + quad * 8];
        #pragma unroll
        for (int j = 0; j < 4; ++j)
            bfr[j] = *(const short8*)&Bs[(wc * 64 + j * 16 + l15) * LDK + quad * 8];
        #pragma unroll
        for (int i = 0; i < 2; ++i)
            #pragma unroll
            for (int j = 0; j < 4; ++j)
                acc[i][j] = __builtin_amdgcn_mfma_f32_16x16x32_bf16(af[i], bfr[j], acc[i][j], 0, 0, 0);
        __syncthreads();
    }
    #pragma unroll
    for (int i = 0; i < 2; ++i) {
        #pragma unroll
        for (int j = 0; j < 4; ++j) {
            int nn = n0 + wc * 64 + j * 16 + l15;
            float bv = bias[nn];
            #pragma unroll
            for (int rg = 0; rg < 4; ++rg) {
                int m = m0 + wr * 32 + i * 16 + quad * 4 + rg;
                float v = acc[i][j][rg] + bv;
                if constexpr (sizeof(OutT) == 2)
                    D[(size_t)m * N + nn] = __float2bfloat16(v);
                else
                    D[(size_t)m * N + nn] = v;
            }
        }
    }
}

// ---- MFMA bf16 GEMM: D[M,N] = A[M,K] @ Bt[N,K]^T + bias (+R).
template<int BM, int BN, int WM, int WN, typename OutT>
__global__ __launch_bounds__(256) void k_gemm_mfma(const bf16* __restrict__ A,
                                                   const bf16* __restrict__ Bt,
                                                   const float* __restrict__ bias,
                                                   const float* __restrict__ R,
                                                   OutT* __restrict__ D,
                                                   int K, int N) {
    constexpr int LDK = 40;
    __shared__ bf16 As[BM * LDK];
    __shared__ bf16 Bs[BN * LDK];
    int tid = threadIdx.x;
    int wave = tid >> 6, lane = tid & 63;
    int l15 = lane & 15, quad = lane >> 4;
    constexpr int WCOLS = BN / WN;
    int wr = wave / WCOLS, wc = wave % WCOLS;
    int m0 = blockIdx.y * BM, n0 = blockIdx.x * BN;
    constexpr int MI = WM / 16, NJ = WN / 16;
    floatx4 acc[MI][NJ];
    #pragma unroll
    for (int i = 0; i < MI; ++i)
        #pragma unroll
        for (int j = 0; j < NJ; ++j)
            acc[i][j] = (floatx4){0.f, 0.f, 0.f, 0.f};

    for (int k0 = 0; k0 < K; k0 += 32) {
        #pragma unroll
        for (int c = tid; c < BM * 4; c += 256) {
            int row = c >> 2, off = (c & 3) * 8;
            *(uint4*)&As[row * LDK + off] =
                *(const uint4*)&A[(size_t)(m0 + row) * K + k0 + off];
        }
        #pragma unroll
        for (int c = tid; c < BN * 4; c += 256) {
            int row = c >> 2, off = (c & 3) * 8;
            *(uint4*)&Bs[row * LDK + off] =
                *(const uint4*)&Bt[(size_t)(n0 + row) * K + k0 + off];
        }
        __syncthreads();
        short8 af[MI], bfr[NJ];
        #pragma unroll
        for (int i = 0; i < MI; ++i)
            af[i] = *(const short8*)&As[(wr * WM + i * 16 + l15) * LDK + quad * 8];
        #pragma unroll
        for (int j = 0; j < NJ; ++j)
            bfr[j] = *(const short8*)&Bs[(wc * WN + j * 16 + l15) * LDK + quad * 8];
        #pragma unroll
        for (int i = 0; i < MI; ++i)
            #pragma unroll
            for (int j = 0; j < NJ; ++j)
                acc[i][j] = __builtin_amdgcn_mfma_f32_16x16x32_bf16(af[i], bfr[j], acc[i][j], 0, 0, 0);
        __syncthreads();
    }
    #pragma unroll
    for (int i = 0; i < MI; ++i) {
        #pragma unroll
        for (int j = 0; j < NJ; ++j) {
            int nn = n0 + wc * WN + j * 16 + l15;
            float bv = bias[nn];
            #pragma unroll
            for (int rg = 0; rg < 4; ++rg) {
                int m = m0 + wr * WM + i * 16 + quad * 4 + rg;
                float v = acc[i][j][rg] + bv;
                if (R) v += R[(size_t)m * N + nn];
                if constexpr (sizeof(OutT) == 2)
                    D[(size_t)m * N + nn] = __float2bfloat16(v);
                else
                    D[(size_t)m * N + nn] = v;
            }
        }
    }
}

// ---- GEMM (N=128) + residual + fused next-LayerNorm epilogue.
__global__ __launch_bounds__(256) void k_gemm_ln(const bf16* __restrict__ A,
                                                 const bf16* __restrict__ Bt,
                                                 const float* __restrict__ bias,
                                                 const float* __restrict__ R,
                                                 const float* __restrict__ g,
                                                 const float* __restrict__ be,
                                                 float* __restrict__ Dres,
                                                 bf16* __restrict__ Aout,
                                                 int K) {
    constexpr int LDK = 40;
    __shared__ bf16 As[32 * LDK];
    __shared__ bf16 Bs[128 * LDK];
    __shared__ float ot[32][132];
    __shared__ float sG[128], sB[128];
    int tid = threadIdx.x;
    int wave = tid >> 6, lane = tid & 63;
    int l15 = lane & 15, quad = lane >> 4;
    int wr = wave >> 1, wc = wave & 1;
    int m0 = blockIdx.x * 32;
    if (tid < 128) { sG[tid] = g[tid]; sB[tid] = be[tid]; }
    floatx4 acc[4];
    #pragma unroll
    for (int j = 0; j < 4; ++j) acc[j] = (floatx4){0.f, 0.f, 0.f, 0.f};

    for (int k0 = 0; k0 < K; k0 += 32) {
        if (tid < 128) {
            int row = tid >> 2, off = (tid & 3) * 8;
            *(uint4*)&As[row * LDK + off] =
                *(const uint4*)&A[(size_t)(m0 + row) * K + k0 + off];
        }
        #pragma unroll
        for (int c = tid; c < 512; c += 256) {
            int row = c >> 2, off = (c & 3) * 8;
            *(uint4*)&Bs[row * LDK + off] =
                *(const uint4*)&Bt[(size_t)row * K + k0 + off];
        }
        __syncthreads();
        short8 af = *(const short8*)&As[(wr * 16 + l15) * LDK + quad * 8];
        short8 bfr[4];
        #pragma unroll
        for (int j = 0; j < 4; ++j)
            bfr[j] = *(const short8*)&Bs[(wc * 64 + j * 16 + l15) * LDK + quad * 8];
        #pragma unroll
        for (int j = 0; j < 4; ++j)
            acc[j] = __builtin_amdgcn_mfma_f32_16x16x32_bf16(af, bfr[j], acc[j], 0, 0, 0);
        __syncthreads();
    }
    #pragma unroll
    for (int j = 0; j < 4; ++j) {
        int nn = wc * 64 + j * 16 + l15;
        float bv = bias[nn];
        #pragma unroll
        for (int rg = 0; rg < 4; ++rg) {
            int m = wr * 16 + quad * 4 + rg;
            ot[m][nn] = acc[j][rg] + bv + R[(size_t)(m0 + m) * 128 + nn];
        }
    }
    __syncthreads();
    int row = tid >> 3, sub = tid & 7;
    float vv[16];
    float s = 0.f, q = 0.f;
    #pragma unroll
    for (int i = 0; i < 16; ++i) {
        float v = ot[row][sub * 16 + i];
        vv[i] = v; s += v; q += v * v;
    }
    #pragma unroll
    for (int o = 4; o > 0; o >>= 1) { s += __shfl_xor(s, o); q += __shfl_xor(q, o); }
    float mean = s * (1.0f / 128.0f);
    float var = q * (1.0f / 128.0f) - mean * mean;
    float rst = rsqrtf(var + 1e-5f);
    size_t base = (size_t)(m0 + row) * 128 + sub * 16;
    #pragma unroll
    for (int i = 0; i < 16; i += 4)
        *(float4*)(Dres + base + i) = (float4){vv[i], vv[i+1], vv[i+2], vv[i+3]};
    #pragma unroll
    for (int i = 0; i < 16; i += 2) {
        int ch = sub * 16 + i;
        __hip_bfloat162 o2;
        o2.x = __float2bfloat16((vv[i]     - mean) * rst * sG[ch]     + sB[ch]);
        o2.y = __float2bfloat16((vv[i + 1] - mean) * rst * sG[ch + 1] + sB[ch + 1]);
        *(__hip_bfloat162*)(Aout + base + i) = o2;
    }
}

// ---- GEMM (N=128) + residual + FINAL LayerNorm + transposed store to (b,c,t,y,x).
__global__ __launch_bounds__(256) void k_gemm_lnout(const bf16* __restrict__ A,
                                                    const bf16* __restrict__ Bt,
                                                    const float* __restrict__ bias,
                                                    const float* __restrict__ R,
                                                    const float* __restrict__ g,
                                                    const float* __restrict__ be,
                                                    float* __restrict__ out,
                                                    int K) {
    constexpr int LDK = 40;
    __shared__ bf16 As[32 * LDK];
    __shared__ bf16 Bs[128 * LDK];
    __shared__ float ot[32][133];    // pad 133: conflict-free transposed reads
    __shared__ float sG[128], sB[128];
    int tid = threadIdx.x;
    int wave = tid >> 6, lane = tid & 63;
    int l15 = lane & 15, quad = lane >> 4;
    int wr = wave >> 1, wc = wave & 1;
    int m0 = blockIdx.x * 32;
    if (tid < 128) { sG[tid] = g[tid]; sB[tid] = be[tid]; }
    floatx4 acc[4];
    #pragma unroll
    for (int j = 0; j < 4; ++j) acc[j] = (floatx4){0.f, 0.f, 0.f, 0.f};

    for (int k0 = 0; k0 < K; k0 += 32) {
        if (tid < 128) {
            int row = tid >> 2, off = (tid & 3) * 8;
            *(uint4*)&As[row * LDK + off] =
                *(const uint4*)&A[(size_t)(m0 + row) * K + k0 + off];
        }
        #pragma unroll
        for (int c = tid; c < 512; c += 256) {
            int row = c >> 2, off = (c & 3) * 8;
            *(uint4*)&Bs[row * LDK + off] =
                *(const uint4*)&Bt[(size_t)row * K + k0 + off];
        }
        __syncthreads();
        short8 af = *(const short8*)&As[(wr * 16 + l15) * LDK + quad * 8];
        short8 bfr[4];
        #pragma unroll
        for (int j = 0; j < 4; ++j)
            bfr[j] = *(const short8*)&Bs[(wc * 64 + j * 16 + l15) * LDK + quad * 8];
        #pragma unroll
        for (int j = 0; j < 4; ++j)
            acc[j] = __builtin_amdgcn_mfma_f32_16x16x32_bf16(af, bfr[j], acc[j], 0, 0, 0);
        __syncthreads();
    }
    #pragma unroll
    for (int j = 0; j < 4; ++j) {
        int nn = wc * 64 + j * 16 + l15;
        float bv = bias[nn];
        #pragma unroll
        for (int rg = 0; rg < 4; ++rg) {
            int m = wr * 16 + quad * 4 + rg;
            ot[m][nn] = acc[j][rg] + bv + R[(size_t)(m0 + m) * 128 + nn];
        }
    }
    __syncthreads();
    int row = tid >> 3, sub = tid & 7;
    float vv[16];
    float s = 0.f, q = 0.f;
    #pragma unroll
    for (int i = 0; i < 16; ++i) {
        float v = ot[row][sub * 16 + i];
        vv[i] = v; s += v; q += v * v;
    }
    #pragma unroll
    for (int o = 4; o > 0; o >>= 1) { s += __shfl_xor(s, o); q += __shfl_xor(q, o); }
    float mean = s * (1.0f / 128.0f);
    float var = q * (1.0f / 128.0f) - mean * mean;
    float rst = rsqrtf(var + 1e-5f);
    #pragma unroll
    for (int i = 0; i < 16; ++i) {
        int ch = sub * 16 + i;
        ot[row][ch] = (vv[i] - mean) * rst * sG[ch] + sB[ch];
    }
    __syncthreads();
    int n = m0 / 1600, rem0 = m0 % 1600;
    int b = n >> 3, t = n & 7;
    #pragma unroll
    for (int it = 0; it < 16; ++it) {
        int idx = it * 256 + tid;
        int ch = idx >> 5, tk = idx & 31;
        out[((size_t)((b * 128 + ch) * 8 + t)) * 1600 + rem0 + tk] = ot[tk][ch];
    }
}

// ---- row-tiled 7x7 neighborhood attention; f16 K + fdot2 logits, q in LDS (f16).
// XCD-locality swizzle: same-XCD blocks get consecutive y (shared K/V windows).
__global__ __launch_bounds__(256) void k_attn(const bf16* __restrict__ qkv,
                                              const float* __restrict__ rpb,
                                              bf16* __restrict__ out) {
    int raw = blockIdx.x;                       // grid 2560
    int blk = (raw & 7) * 320 + (raw >> 3);     // chunk per XCD
    int head = blk & 3;
    int ny = blk >> 2;
    int n = ny / 40, y = ny % 40;
    int sy = min(max(y - 3, 0), HH - 7);
    __shared__ __align__(16) short KVs[7 * KVP];   // K (f16) then V (bf16)
    __shared__ __align__(16) short qs[40 * 40];    // q as f16, stride 40 (3.2 KB)
    __shared__ float lg[40][49];
    int tid = threadIdx.x;
    // q staging: bf16 -> f16, 160 threads x 8 elems
    if (tid < 160) {
        int xq = tid >> 2, d8 = (tid & 3) * 8;
        union { uint4 u; __hip_bfloat162 b[4]; } U;
        U.u = *(const uint4*)(qkv + ((size_t)(n * 1600 + y * 40 + xq)) * 384 + head * 32 + d8);
        union { short8 s; h2 h[4]; } W;
        #pragma unroll
        for (int c = 0; c < 4; ++c) {
            float2 f = __bfloat1622float2(U.b[c]);
            W.h[c].x = (_Float16)f.x; W.h[c].y = (_Float16)f.y;
        }
        *(short8*)&qs[xq * 40 + d8] = W.s;
    }
    // phase 1: K window, bf16 -> f16 in staging
    for (int i2 = tid; i2 < 1120; i2 += 256) {
        int d8 = i2 & 3, kx = (i2 >> 2) % 40, ky = i2 / 160;
        size_t base = ((size_t)(n * 1600 + (sy + ky) * 40 + kx)) * 384 + 128 + head * 32 + d8 * 8;
        union { uint4 u; __hip_bfloat162 b[4]; } U;
        U.u = *(const uint4*)(qkv + base);
        union { short8 s; h2 h[4]; } W;
        #pragma unroll
        for (int c = 0; c < 4; ++c) {
            float2 f = __bfloat1622float2(U.b[c]);
            W.h[c].x = (_Float16)f.x; W.h[c].y = (_Float16)f.y;
        }
        *(short8*)&KVs[ky * KVP + kx * 40 + d8 * 8] = W.s;
    }
    __syncthreads();
    // logits: thread per (xq, ky); q read from LDS as f16
    for (int p2 = tid; p2 < 280; p2 += 256) {
        int xq = p2 / 7, ky = p2 - (p2 / 7) * 7;
        int sx = min(max(xq - 3, 0), WW - 7);
        const h2* qp = (const h2*)&qs[xq * 40];
        h2 qh[16];
        #pragma unroll
        for (int c = 0; c < 16; ++c) qh[c] = qp[c];
        const float* rb = rpb + head * 169 + (sy + ky - y + 6) * 13 + (sx - xq + 6);
        int kbase = ky * KVP + sx * 40;
        #pragma unroll
        for (int jx = 0; jx < 7; ++jx) {
            const h2* kp = (const h2*)&KVs[kbase + jx * 40];
            float dot = 0.f;
            #pragma unroll
            for (int c = 0; c < 16; ++c)
                dot = __builtin_amdgcn_fdot2(qh[c], kp[c], dot, false);
            lg[xq][ky * 7 + jx] = dot * 0.1767766952966369f + rb[jx];
        }
    }
    __syncthreads();
    // phase 2: V window (raw bf16 bits), softmax concurrently
    for (int i2 = tid; i2 < 1120; i2 += 256) {
        int d8 = i2 & 3, kx = (i2 >> 2) % 40, ky = i2 / 160;
        size_t base = ((size_t)(n * 1600 + (sy + ky) * 40 + kx)) * 384 + 256 + head * 32 + d8 * 8;
        *(uint4*)&KVs[ky * KVP + kx * 40 + d8 * 8] = *(const uint4*)(qkv + base);
    }
    if (tid < 40) {
        float m = -1e30f;
        for (int j = 0; j < 49; ++j) m = fmaxf(m, lg[tid][j]);
        float s = 0.f;
        for (int j = 0; j < 49; ++j) { float e = expf(lg[tid][j] - m); lg[tid][j] = e; s += e; }
        float inv = 1.0f / s;
        for (int j = 0; j < 49; ++j) lg[tid][j] *= inv;
    }
    __syncthreads();
    for (int o = tid; o < 640; o += 256) {         // PV reduce (bf16 V)
        int xq = o >> 4, dp = (o & 15) * 2;
        int sx = min(max(xq - 3, 0), WW - 7);
        float a0 = 0.f, a1 = 0.f;
        #pragma unroll
        for (int ky = 0; ky < 7; ++ky) {
            int vbase = ky * KVP + sx * 40 + dp;
            #pragma unroll
            for (int jx = 0; jx < 7; ++jx) {
                float p = lg[xq][ky * 7 + jx];
                float2 v = __bfloat1622float2(*(const __hip_bfloat162*)&KVs[vbase + jx * 40]);
                a0 += p * v.x; a1 += p * v.y;
            }
        }
        __hip_bfloat162 o2;
        o2.x = __float2bfloat16(a0); o2.y = __float2bfloat16(a1);
        *(__hip_bfloat162*)(out + ((size_t)(n * 1600 + y * 40 + xq)) * 128 + head * 32 + dp) = o2;
    }
}

// ---- depthwise 3x3x3 conv + bias + exact GELU; fp32 in, bf16 out.
// v3: back to 512 thr x 1 ch (round-0 occupancy), PLUS: branch-free loads
// (validity folded into zeroed weights, clamped uniform row offsets in SGPRs),
// one-iteration prefetch (cn loads for x+2 issued before consuming c0/c1/c2),
// compile-time x-half specialization + full unroll (register rotation becomes
// renaming; x+2<40 edge checks resolved at compile time).
// XCD-locality swizzle: same-XCD blocks get consecutive (n,y) chunks (shared rows).
template<int X0>
__device__ __forceinline__ void dw_body(const float* __restrict__ inp,
                                        const int* roff, const float* wr,
                                        float bs, int m, size_t outbase,
                                        bf16* __restrict__ outp) {
    float c0[9], c1[9], c2[9];
    #pragma unroll
    for (int p = 0; p < 9; ++p) {
        c0[p] = (X0 > 0) ? inp[roff[p] + (X0 - 1) * 512 + m] : 0.f;
        c1[p] = inp[roff[p] + X0 * 512 + m];
        c2[p] = inp[roff[p] + (X0 + 1) * 512 + m];
    }
    #pragma unroll
    for (int xi = 0; xi < 20; ++xi) {
        constexpr int XN_BASE = X0 + 2;
        int x = X0 + xi;
        float cn[9];
        if (XN_BASE + xi < 40) {
            #pragma unroll
            for (int p = 0; p < 9; ++p)
                cn[p] = inp[roff[p] + (XN_BASE + xi) * 512 + m];
        } else {
            #pragma unroll
            for (int p = 0; p < 9; ++p) cn[p] = 0.f;
        }
        float acc = bs;
        #pragma unroll
        for (int p = 0; p < 9; ++p)
            acc += wr[p * 3 + 0] * c0[p] + wr[p * 3 + 1] * c1[p] + wr[p * 3 + 2] * c2[p];
        float g = 0.5f * acc * (1.0f + erff(acc * 0.70710678118654752f));
        outp[outbase + (size_t)x * 512] = __float2bfloat16(g);
        #pragma unroll
        for (int p = 0; p < 9; ++p) { c0[p] = c1[p]; c1[p] = c2[p]; c2[p] = cn[p]; }
    }
}

__global__ __launch_bounds__(512, 4) void k_dwconv(const float* __restrict__ inp,
                                                   const float* __restrict__ w,
                                                   const float* __restrict__ bias,
                                                   bf16* __restrict__ outp) {
    int raw = blockIdx.x;                       // grid 1280
    int blk = (raw & 7) * 160 + (raw >> 3);     // chunk per XCD
    int xh = blk & 1;
    int ny = blk >> 1;
    int n = ny / 40, y = ny - n * 40;
    int b = n >> 3, t = n & 7;
    int m = threadIdx.x;
    float wr[27];
    int roff[9];                                // wave-uniform -> SGPRs
    #pragma unroll
    for (int dt = 0; dt < 3; ++dt) {
        #pragma unroll
        for (int dy = 0; dy < 3; ++dy) {
            int p = dt * 3 + dy;
            int tt = t + dt - 1, yy = y + dy - 1;
            bool v = (tt >= 0 && tt < 8 && yy >= 0 && yy < 40);
            int tc = min(max(tt, 0), 7), yc = min(max(yy, 0), 39);
            roff[p] = ((b * 8 + tc) * 1600 + yc * 40) * 512;
            #pragma unroll
            for (int q = 0; q < 3; ++q)
                wr[p * 3 + q] = v ? w[(p * 3 + q) * 512 + m] : 0.f;
        }
    }
    float bs = bias[m];
    size_t outbase = ((size_t)(n * 1600 + y * 40)) * 512 + m;
    if (xh == 0)
        dw_body<0>(inp, roff, wr, bs, m, outbase, outp);
    else
        dw_body<20>(inp, roff, wr, bs, m, outbase, outp);
}

extern "C" void kernel_launch(void* const* d_in, const int* in_sizes, int n_in,
                              void* d_out, int out_size, void* d_ws, size_t ws_size,
                              hipStream_t stream) {
    const float* x      = (const float*)d_in[0];
    const float* ln1_g  = (const float*)d_in[1];
    const float* ln1_b  = (const float*)d_in[2];
    const float* qkv_w  = (const float*)d_in[3];
    const float* qkv_b  = (const float*)d_in[4];
    const float* rpb    = (const float*)d_in[5];
    const float* proj_w = (const float*)d_in[6];
    const float* proj_b = (const float*)d_in[7];
    const float* ln2_g  = (const float*)d_in[8];
    const float* ln2_b  = (const float*)d_in[9];
    const float* fc1_w  = (const float*)d_in[10];
    const float* fc1_b  = (const float*)d_in[11];
    const float* dw_w   = (const float*)d_in[12];
    const float* dw_b   = (const float*)d_in[13];
    const float* fc2_w  = (const float*)d_in[14];
    const float* fc2_b  = (const float*)d_in[15];
    const float* out_g  = (const float*)d_in[16];
    const float* out_b  = (const float*)d_in[17];
    float* out = (float*)d_out;

    // workspace: h f32 | f1 f32 | qkvb bf16 | f2b bf16 | abufA bf16 | abufL bf16 | wt
    float* h     = (float*)d_ws;
    float* f1    = h + (size_t)NTOK * 128;
    bf16* qkvb   = (bf16*)(f1 + (size_t)NTOK * 512);
    bf16* f2b    = qkvb + (size_t)NTOK * 384;
    bf16* abufA  = f2b  + (size_t)NTOK * 512;
    bf16* abufL  = abufA + (size_t)NTOK * 128;
    bf16* wt     = abufL + (size_t)NTOK * 128;

    k_wt<<<96, 256, 0, stream>>>(qkv_w, proj_w, fc1_w, fc2_w, wt);
    k_transpose_in<<<NIMG * 200, 256, 0, stream>>>(x, h);
    for (int l = 0; l < 2; ++l) {
        const bf16* wtl = wt + (size_t)l * WT_L;
        if (l == 0) {
            k_lngemm<bf16><<<dim3(3, 400), 256, 0, stream>>>(
                h, wtl + WT_QKV, ln1_g, ln1_b, qkv_b, qkvb, 384);
        } else {
            k_gemm_mfma<64, 128, 32, 64, bf16><<<dim3(3, 400), 256, 0, stream>>>(
                abufL, wtl + WT_QKV, qkv_b + 384, nullptr, qkvb, 128, 384);
        }
        k_attn<<<NIMG * HH * NHEAD, 256, 0, stream>>>(qkvb, rpb + l * 4 * 169, abufA);
        // proj + residual + fused LN2 epilogue -> abufL
        k_gemm_ln<<<800, 256, 0, stream>>>(
            abufA, wtl + WT_PROJ, proj_b + l * 128, h,
            ln2_g + l * 128, ln2_b + l * 128, h, abufL, 128);
        // fc1: plain bf16-A GEMM
        k_gemm_mfma<64, 128, 32, 64, float><<<dim3(4, 400), 256, 0, stream>>>(
            abufL, wtl + WT_FC1, fc1_b + l * 512, nullptr, f1, 128, 512);
        k_dwconv<<<NIMG * HH * 2, 512, 0, stream>>>(f1, dw_w + l * 27 * 512, dw_b + l * 512, f2b);
        if (l == 0) {
            // fc2 + residual + fused LN1(layer 1) epilogue -> abufL
            k_gemm_ln<<<800, 256, 0, stream>>>(
                f2b, wtl + WT_FC2, fc2_b, h,
                ln1_g + 128, ln1_b + 128, h, abufL, 512);
        } else {
            // fc2 + residual + FINAL LN + transposed store
            k_gemm_lnout<<<800, 256, 0, stream>>>(
                f2b, wtl + WT_FC2, fc2_b + 128, h, out_g, out_b, out, 512);
        }
    }
}

// Round 3
// 381.902 us; speedup vs baseline: 1.1460x; 1.0143x over previous
//
#include <hip/hip_runtime.h>
#include <hip/hip_bf16.h>
#include <math.h>

typedef __hip_bfloat16 bf16;
typedef __attribute__((ext_vector_type(8))) short short8;
typedef __attribute__((ext_vector_type(4))) float floatx4;
typedef __attribute__((ext_vector_type(2))) float f32x2;
typedef _Float16 h2 __attribute__((ext_vector_type(2)));

#define HH 40
#define WW 40
#define CC 128
#define TT 8
#define NIMG 16           // B*T
#define NTOK 25600        // NIMG*HH*WW
#define MDIM 512
#define NHEAD 4
#define KVP 1608          // K LDS plane stride in shorts (40 sh/kx: b128-friendly)
#define VP  1280          // V LDS plane stride in shorts (32 sh/kx: PV conflict-free)

// weight-transpose buffer offsets (bf16 elems), per layer
#define WT_QKV 0
#define WT_PROJ 49152
#define WT_FC1  65536
#define WT_FC2  131072
#define WT_L    196608

// ---- input transpose via LDS tiles: x (b,c,t,y,x) -> h (n,y,x,c), both coalesced.
__global__ __launch_bounds__(256) void k_transpose_in(const float* __restrict__ x,
                                                      float* __restrict__ h) {
    int blk = blockIdx.x;
    int n = blk / 200; int r = blk % 200; int ci = r / 50, ri = r % 50;
    int b = n >> 3, t = n & 7;
    int c0 = ci * 32, r0 = ri * 32;
    __shared__ float tile[32][33];
    int tid = threadIdx.x;
    int lc = tid >> 5, lr = tid & 31;         // 8 x 32
    #pragma unroll
    for (int it = 0; it < 4; ++it) {
        int cc = it * 8 + lc;
        tile[cc][lr] = x[((size_t)((b * 128 + c0 + cc) * 8 + t)) * 1600 + r0 + lr];
    }
    __syncthreads();
    #pragma unroll
    for (int it = 0; it < 4; ++it) {
        int rr = it * 8 + lc;
        h[((size_t)(n * 1600 + r0 + rr)) * 128 + c0 + lr] = tile[lr][rr];
    }
}

// ---- weight convert+transpose: W[K,N] fp32 -> Wt[N,K] bf16, 64x64 LDS tiles.
__global__ __launch_bounds__(256) void k_wt(const float* __restrict__ qkv_w,
                                            const float* __restrict__ proj_w,
                                            const float* __restrict__ fc1_w,
                                            const float* __restrict__ fc2_w,
                                            bf16* __restrict__ wt) {
    __shared__ float tile[64][65];
    int id = blockIdx.x;
    int l = id / 48, r = id % 48;
    const float* src; bf16* dst; int K_, N_, t;
    if (r < 12)      { src = qkv_w  + l * 128 * 384; dst = wt + l * WT_L + WT_QKV; K_ = 128; N_ = 384; t = r; }
    else if (r < 16) { src = proj_w + l * 128 * 128; dst = wt + l * WT_L + WT_PROJ; K_ = 128; N_ = 128; t = r - 12; }
    else if (r < 32) { src = fc1_w  + l * 128 * 512; dst = wt + l * WT_L + WT_FC1; K_ = 128; N_ = 512; t = r - 16; }
    else             { src = fc2_w  + l * 512 * 128; dst = wt + l * WT_L + WT_FC2; K_ = 512; N_ = 128; t = r - 32; }
    int KT = K_ >> 6;
    int k0 = (t % KT) * 64, n0 = (t / KT) * 64;
    int tid = threadIdx.x;
    for (int c = tid; c < 4096; c += 256) {
        int kk = c >> 6, nn = c & 63;
        tile[kk][nn] = src[(size_t)(k0 + kk) * N_ + n0 + nn];
    }
    __syncthreads();
    for (int c = tid; c < 4096; c += 256) {
        int nn = c >> 6, kk = c & 63;
        dst[(size_t)(n0 + nn) * K_ + k0 + kk] = __float2bfloat16(tile[kk][nn]);
    }
}

// ---- fused LayerNorm + MFMA GEMM (fp32 A): only layer-0 qkv.
template<typename OutT>
__global__ __launch_bounds__(256) void k_lngemm(const float* __restrict__ A,
                                                const bf16* __restrict__ Bt,
                                                const float* __restrict__ g,
                                                const float* __restrict__ be,
                                                const float* __restrict__ bias,
                                                OutT* __restrict__ D,
                                                int N) {
    constexpr int LDK = 40;
    __shared__ bf16 As[64 * LDK];
    __shared__ bf16 Bs[128 * LDK];
    __shared__ float sMean[64], sRstd[64], sG[128], sB[128];
    int tid = threadIdx.x;
    int m0 = blockIdx.y * 64, n0 = blockIdx.x * 128;
    {
        int row = tid >> 2, q4 = tid & 3;
        const float* p = A + (size_t)(m0 + row) * 128 + q4 * 32;
        float s = 0.f, q = 0.f;
        #pragma unroll
        for (int i = 0; i < 32; i += 4) {
            float4 f = *(const float4*)(p + i);
            s += f.x + f.y + f.z + f.w;
            q += f.x * f.x + f.y * f.y + f.z * f.z + f.w * f.w;
        }
        s += __shfl_xor(s, 1); q += __shfl_xor(q, 1);
        s += __shfl_xor(s, 2); q += __shfl_xor(q, 2);
        if (q4 == 0) {
            float mean = s * (1.0f / 128.0f);
            float var = q * (1.0f / 128.0f) - mean * mean;
            sMean[row] = mean;
            sRstd[row] = rsqrtf(var + 1e-5f);
        }
        if (tid < 128) { sG[tid] = g[tid]; sB[tid] = be[tid]; }
    }
    __syncthreads();
    int wave = tid >> 6, lane = tid & 63;
    int l15 = lane & 15, quad = lane >> 4;
    int wr = wave >> 1, wc = wave & 1;
    floatx4 acc[2][4];
    #pragma unroll
    for (int i = 0; i < 2; ++i)
        #pragma unroll
        for (int j = 0; j < 4; ++j)
            acc[i][j] = (floatx4){0.f, 0.f, 0.f, 0.f};

    for (int k0 = 0; k0 < 128; k0 += 32) {
        #pragma unroll
        for (int it = 0; it < 2; ++it) {
            int c = tid + it * 256;
            int row = c >> 3, kq = (c & 7) * 4;
            float4 f = *(const float4*)(A + (size_t)(m0 + row) * 128 + k0 + kq);
            float mean = sMean[row], rst = sRstd[row];
            float r0v = (f.x - mean) * rst * sG[k0 + kq]     + sB[k0 + kq];
            float r1v = (f.y - mean) * rst * sG[k0 + kq + 1] + sB[k0 + kq + 1];
            float r2v = (f.z - mean) * rst * sG[k0 + kq + 2] + sB[k0 + kq + 2];
            float r3v = (f.w - mean) * rst * sG[k0 + kq + 3] + sB[k0 + kq + 3];
            __hip_bfloat162 p0, p1;
            p0.x = __float2bfloat16(r0v); p0.y = __float2bfloat16(r1v);
            p1.x = __float2bfloat16(r2v); p1.y = __float2bfloat16(r3v);
            *(__hip_bfloat162*)&As[row * LDK + kq]     = p0;
            *(__hip_bfloat162*)&As[row * LDK + kq + 2] = p1;
        }
        #pragma unroll
        for (int c = tid; c < 512; c += 256) {
            int row = c >> 2, off = (c & 3) * 8;
            *(uint4*)&Bs[row * LDK + off] =
                *(const uint4*)&Bt[(size_t)(n0 + row) * 128 + k0 + off];
        }
        __syncthreads();
        short8 af[2], bfr[4];
        #pragma unroll
        for (int i = 0; i < 2; ++i)
            af[i] = *(const short8*)&As[(wr * 32 + i * 16 + l15) * LDK + quad * 8];
        #pragma unroll
        for (int j = 0; j < 4; ++j)
            bfr[j] = *(const short8*)&Bs[(wc * 64 + j * 16 + l15) * LDK + quad * 8];
        #pragma unroll
        for (int i = 0; i < 2; ++i)
            #pragma unroll
            for (int j = 0; j < 4; ++j)
                acc[i][j] = __builtin_amdgcn_mfma_f32_16x16x32_bf16(af[i], bfr[j], acc[i][j], 0, 0, 0);
        __syncthreads();
    }
    #pragma unroll
    for (int i = 0; i < 2; ++i) {
        #pragma unroll
        for (int j = 0; j < 4; ++j) {
            int nn = n0 + wc * 64 + j * 16 + l15;
            float bv = bias[nn];
            #pragma unroll
            for (int rg = 0; rg < 4; ++rg) {
                int m = m0 + wr * 32 + i * 16 + quad * 4 + rg;
                float v = acc[i][j][rg] + bv;
                if constexpr (sizeof(OutT) == 2)
                    D[(size_t)m * N + nn] = __float2bfloat16(v);
                else
                    D[(size_t)m * N + nn] = v;
            }
        }
    }
}

// ---- MFMA bf16 GEMM: D[M,N] = A[M,K] @ Bt[N,K]^T + bias (+R).
template<int BM, int BN, int WM, int WN, typename OutT>
__global__ __launch_bounds__(256) void k_gemm_mfma(const bf16* __restrict__ A,
                                                   const bf16* __restrict__ Bt,
                                                   const float* __restrict__ bias,
                                                   const float* __restrict__ R,
                                                   OutT* __restrict__ D,
                                                   int K, int N) {
    constexpr int LDK = 40;
    __shared__ bf16 As[BM * LDK];
    __shared__ bf16 Bs[BN * LDK];
    int tid = threadIdx.x;
    int wave = tid >> 6, lane = tid & 63;
    int l15 = lane & 15, quad = lane >> 4;
    constexpr int WCOLS = BN / WN;
    int wr = wave / WCOLS, wc = wave % WCOLS;
    int m0 = blockIdx.y * BM, n0 = blockIdx.x * BN;
    constexpr int MI = WM / 16, NJ = WN / 16;
    floatx4 acc[MI][NJ];
    #pragma unroll
    for (int i = 0; i < MI; ++i)
        #pragma unroll
        for (int j = 0; j < NJ; ++j)
            acc[i][j] = (floatx4){0.f, 0.f, 0.f, 0.f};

    for (int k0 = 0; k0 < K; k0 += 32) {
        #pragma unroll
        for (int c = tid; c < BM * 4; c += 256) {
            int row = c >> 2, off = (c & 3) * 8;
            *(uint4*)&As[row * LDK + off] =
                *(const uint4*)&A[(size_t)(m0 + row) * K + k0 + off];
        }
        #pragma unroll
        for (int c = tid; c < BN * 4; c += 256) {
            int row = c >> 2, off = (c & 3) * 8;
            *(uint4*)&Bs[row * LDK + off] =
                *(const uint4*)&Bt[(size_t)(n0 + row) * K + k0 + off];
        }
        __syncthreads();
        short8 af[MI], bfr[NJ];
        #pragma unroll
        for (int i = 0; i < MI; ++i)
            af[i] = *(const short8*)&As[(wr * WM + i * 16 + l15) * LDK + quad * 8];
        #pragma unroll
        for (int j = 0; j < NJ; ++j)
            bfr[j] = *(const short8*)&Bs[(wc * WN + j * 16 + l15) * LDK + quad * 8];
        #pragma unroll
        for (int i = 0; i < MI; ++i)
            #pragma unroll
            for (int j = 0; j < NJ; ++j)
                acc[i][j] = __builtin_amdgcn_mfma_f32_16x16x32_bf16(af[i], bfr[j], acc[i][j], 0, 0, 0);
        __syncthreads();
    }
    #pragma unroll
    for (int i = 0; i < MI; ++i) {
        #pragma unroll
        for (int j = 0; j < NJ; ++j) {
            int nn = n0 + wc * WN + j * 16 + l15;
            float bv = bias[nn];
            #pragma unroll
            for (int rg = 0; rg < 4; ++rg) {
                int m = m0 + wr * WM + i * 16 + quad * 4 + rg;
                float v = acc[i][j][rg] + bv;
                if (R) v += R[(size_t)m * N + nn];
                if constexpr (sizeof(OutT) == 2)
                    D[(size_t)m * N + nn] = __float2bfloat16(v);
                else
                    D[(size_t)m * N + nn] = v;
            }
        }
    }
}

// ---- GEMM (N=128) + residual + fused next-LayerNorm epilogue.
__global__ __launch_bounds__(256) void k_gemm_ln(const bf16* __restrict__ A,
                                                 const bf16* __restrict__ Bt,
                                                 const float* __restrict__ bias,
                                                 const float* __restrict__ R,
                                                 const float* __restrict__ g,
                                                 const float* __restrict__ be,
                                                 float* __restrict__ Dres,
                                                 bf16* __restrict__ Aout,
                                                 int K) {
    constexpr int LDK = 40;
    __shared__ bf16 As[32 * LDK];
    __shared__ bf16 Bs[128 * LDK];
    __shared__ float ot[32][132];
    __shared__ float sG[128], sB[128];
    int tid = threadIdx.x;
    int wave = tid >> 6, lane = tid & 63;
    int l15 = lane & 15, quad = lane >> 4;
    int wr = wave >> 1, wc = wave & 1;
    int m0 = blockIdx.x * 32;
    if (tid < 128) { sG[tid] = g[tid]; sB[tid] = be[tid]; }
    floatx4 acc[4];
    #pragma unroll
    for (int j = 0; j < 4; ++j) acc[j] = (floatx4){0.f, 0.f, 0.f, 0.f};

    for (int k0 = 0; k0 < K; k0 += 32) {
        if (tid < 128) {
            int row = tid >> 2, off = (tid & 3) * 8;
            *(uint4*)&As[row * LDK + off] =
                *(const uint4*)&A[(size_t)(m0 + row) * K + k0 + off];
        }
        #pragma unroll
        for (int c = tid; c < 512; c += 256) {
            int row = c >> 2, off = (c & 3) * 8;
            *(uint4*)&Bs[row * LDK + off] =
                *(const uint4*)&Bt[(size_t)row * K + k0 + off];
        }
        __syncthreads();
        short8 af = *(const short8*)&As[(wr * 16 + l15) * LDK + quad * 8];
        short8 bfr[4];
        #pragma unroll
        for (int j = 0; j < 4; ++j)
            bfr[j] = *(const short8*)&Bs[(wc * 64 + j * 16 + l15) * LDK + quad * 8];
        #pragma unroll
        for (int j = 0; j < 4; ++j)
            acc[j] = __builtin_amdgcn_mfma_f32_16x16x32_bf16(af, bfr[j], acc[j], 0, 0, 0);
        __syncthreads();
    }
    #pragma unroll
    for (int j = 0; j < 4; ++j) {
        int nn = wc * 64 + j * 16 + l15;
        float bv = bias[nn];
        #pragma unroll
        for (int rg = 0; rg < 4; ++rg) {
            int m = wr * 16 + quad * 4 + rg;
            ot[m][nn] = acc[j][rg] + bv + R[(size_t)(m0 + m) * 128 + nn];
        }
    }
    __syncthreads();
    int row = tid >> 3, sub = tid & 7;
    float vv[16];
    float s = 0.f, q = 0.f;
    #pragma unroll
    for (int i = 0; i < 16; ++i) {
        float v = ot[row][sub * 16 + i];
        vv[i] = v; s += v; q += v * v;
    }
    #pragma unroll
    for (int o = 4; o > 0; o >>= 1) { s += __shfl_xor(s, o); q += __shfl_xor(q, o); }
    float mean = s * (1.0f / 128.0f);
    float var = q * (1.0f / 128.0f) - mean * mean;
    float rst = rsqrtf(var + 1e-5f);
    size_t base = (size_t)(m0 + row) * 128 + sub * 16;
    #pragma unroll
    for (int i = 0; i < 16; i += 4)
        *(float4*)(Dres + base + i) = (float4){vv[i], vv[i+1], vv[i+2], vv[i+3]};
    #pragma unroll
    for (int i = 0; i < 16; i += 2) {
        int ch = sub * 16 + i;
        __hip_bfloat162 o2;
        o2.x = __float2bfloat16((vv[i]     - mean) * rst * sG[ch]     + sB[ch]);
        o2.y = __float2bfloat16((vv[i + 1] - mean) * rst * sG[ch + 1] + sB[ch + 1]);
        *(__hip_bfloat162*)(Aout + base + i) = o2;
    }
}

// ---- GEMM (N=128) + residual + FINAL LayerNorm + transposed store to (b,c,t,y,x).
__global__ __launch_bounds__(256) void k_gemm_lnout(const bf16* __restrict__ A,
                                                    const bf16* __restrict__ Bt,
                                                    const float* __restrict__ bias,
                                                    const float* __restrict__ R,
                                                    const float* __restrict__ g,
                                                    const float* __restrict__ be,
                                                    float* __restrict__ out,
                                                    int K) {
    constexpr int LDK = 40;
    __shared__ bf16 As[32 * LDK];
    __shared__ bf16 Bs[128 * LDK];
    __shared__ float ot[32][133];    // pad 133: conflict-free transposed reads
    __shared__ float sG[128], sB[128];
    int tid = threadIdx.x;
    int wave = tid >> 6, lane = tid & 63;
    int l15 = lane & 15, quad = lane >> 4;
    int wr = wave >> 1, wc = wave & 1;
    int m0 = blockIdx.x * 32;
    if (tid < 128) { sG[tid] = g[tid]; sB[tid] = be[tid]; }
    floatx4 acc[4];
    #pragma unroll
    for (int j = 0; j < 4; ++j) acc[j] = (floatx4){0.f, 0.f, 0.f, 0.f};

    for (int k0 = 0; k0 < K; k0 += 32) {
        if (tid < 128) {
            int row = tid >> 2, off = (tid & 3) * 8;
            *(uint4*)&As[row * LDK + off] =
                *(const uint4*)&A[(size_t)(m0 + row) * K + k0 + off];
        }
        #pragma unroll
        for (int c = tid; c < 512; c += 256) {
            int row = c >> 2, off = (c & 3) * 8;
            *(uint4*)&Bs[row * LDK + off] =
                *(const uint4*)&Bt[(size_t)row * K + k0 + off];
        }
        __syncthreads();
        short8 af = *(const short8*)&As[(wr * 16 + l15) * LDK + quad * 8];
        short8 bfr[4];
        #pragma unroll
        for (int j = 0; j < 4; ++j)
            bfr[j] = *(const short8*)&Bs[(wc * 64 + j * 16 + l15) * LDK + quad * 8];
        #pragma unroll
        for (int j = 0; j < 4; ++j)
            acc[j] = __builtin_amdgcn_mfma_f32_16x16x32_bf16(af, bfr[j], acc[j], 0, 0, 0);
        __syncthreads();
    }
    #pragma unroll
    for (int j = 0; j < 4; ++j) {
        int nn = wc * 64 + j * 16 + l15;
        float bv = bias[nn];
        #pragma unroll
        for (int rg = 0; rg < 4; ++rg) {
            int m = wr * 16 + quad * 4 + rg;
            ot[m][nn] = acc[j][rg] + bv + R[(size_t)(m0 + m) * 128 + nn];
        }
    }
    __syncthreads();
    int row = tid >> 3, sub = tid & 7;
    float vv[16];
    float s = 0.f, q = 0.f;
    #pragma unroll
    for (int i = 0; i < 16; ++i) {
        float v = ot[row][sub * 16 + i];
        vv[i] = v; s += v; q += v * v;
    }
    #pragma unroll
    for (int o = 4; o > 0; o >>= 1) { s += __shfl_xor(s, o); q += __shfl_xor(q, o); }
    float mean = s * (1.0f / 128.0f);
    float var = q * (1.0f / 128.0f) - mean * mean;
    float rst = rsqrtf(var + 1e-5f);
    #pragma unroll
    for (int i = 0; i < 16; ++i) {
        int ch = sub * 16 + i;
        ot[row][ch] = (vv[i] - mean) * rst * sG[ch] + sB[ch];
    }
    __syncthreads();
    int n = m0 / 1600, rem0 = m0 % 1600;
    int b = n >> 3, t = n & 7;
    #pragma unroll
    for (int it = 0; it < 16; ++it) {
        int idx = it * 256 + tid;
        int ch = idx >> 5, tk = idx & 31;
        out[((size_t)((b * 128 + ch) * 8 + t)) * 1600 + rem0 + tk] = ot[tk][ch];
    }
}

// ---- row-tiled 7x7 neighborhood attention; f16 K + fdot2 logits.
// v2: no q LDS (logits threads load q from global -> LDS 30.3KB -> 5 blocks/CU);
// V staged at kx-stride 32 (plane VP=1280): PV wave bank pattern {0,16,0,16}
// = 2 lanes/bank = conflict-free. K keeps stride 40 (b128 5-groups-mod-8, fine).
// XCD-locality swizzle: same-XCD blocks get consecutive y (shared K/V windows).
__global__ __launch_bounds__(256) void k_attn(const bf16* __restrict__ qkv,
                                              const float* __restrict__ rpb,
                                              bf16* __restrict__ out) {
    int raw = blockIdx.x;                       // grid 2560
    int blk = (raw & 7) * 320 + (raw >> 3);     // chunk per XCD
    int head = blk & 3;
    int ny = blk >> 2;
    int n = ny / 40, y = ny % 40;
    int sy = min(max(y - 3, 0), HH - 7);
    __shared__ __align__(16) short KVs[7 * KVP];   // K (f16, stride 40) then V (bf16, stride 32)
    __shared__ float lg[40][49];
    int tid = threadIdx.x;
    // phase 1: K window, bf16 -> f16 in staging
    for (int i2 = tid; i2 < 1120; i2 += 256) {
        int d8 = i2 & 3, kx = (i2 >> 2) % 40, ky = i2 / 160;
        size_t base = ((size_t)(n * 1600 + (sy + ky) * 40 + kx)) * 384 + 128 + head * 32 + d8 * 8;
        union { uint4 u; __hip_bfloat162 b[4]; } U;
        U.u = *(const uint4*)(qkv + base);
        union { short8 s; h2 h[4]; } W;
        #pragma unroll
        for (int c = 0; c < 4; ++c) {
            float2 f = __bfloat1622float2(U.b[c]);
            W.h[c].x = (_Float16)f.x; W.h[c].y = (_Float16)f.y;
        }
        *(short8*)&KVs[ky * KVP + kx * 40 + d8 * 8] = W.s;
    }
    __syncthreads();
    // logits: thread per (xq, ky); q loaded from global, converted in regs
    for (int p2 = tid; p2 < 280; p2 += 256) {
        int xq = p2 / 7, ky = p2 - (p2 / 7) * 7;
        int sx = min(max(xq - 3, 0), WW - 7);
        const bf16* qg = qkv + ((size_t)(n * 1600 + y * 40 + xq)) * 384 + head * 32;
        union { uint4 u; __hip_bfloat162 b[4]; } U[4];
        #pragma unroll
        for (int u = 0; u < 4; ++u) U[u].u = *(const uint4*)(qg + u * 8);
        h2 qh[16];
        #pragma unroll
        for (int c = 0; c < 16; ++c) {
            float2 f = __bfloat1622float2(U[c >> 2].b[c & 3]);
            qh[c].x = (_Float16)f.x; qh[c].y = (_Float16)f.y;
        }
        const float* rb = rpb + head * 169 + (sy + ky - y + 6) * 13 + (sx - xq + 6);
        int kbase = ky * KVP + sx * 40;
        #pragma unroll
        for (int jx = 0; jx < 7; ++jx) {
            const h2* kp = (const h2*)&KVs[kbase + jx * 40];
            float dot = 0.f;
            #pragma unroll
            for (int c = 0; c < 16; ++c)
                dot = __builtin_amdgcn_fdot2(qh[c], kp[c], dot, false);
            lg[xq][ky * 7 + jx] = dot * 0.1767766952966369f + rb[jx];
        }
    }
    __syncthreads();
    // phase 2: V window (raw bf16 bits, stride 32), softmax concurrently
    for (int i2 = tid; i2 < 1120; i2 += 256) {
        int d8 = i2 & 3, kx = (i2 >> 2) % 40, ky = i2 / 160;
        size_t base = ((size_t)(n * 1600 + (sy + ky) * 40 + kx)) * 384 + 256 + head * 32 + d8 * 8;
        *(uint4*)&KVs[ky * VP + kx * 32 + d8 * 8] = *(const uint4*)(qkv + base);
    }
    if (tid < 40) {
        float m = -1e30f;
        for (int j = 0; j < 49; ++j) m = fmaxf(m, lg[tid][j]);
        float s = 0.f;
        for (int j = 0; j < 49; ++j) { float e = expf(lg[tid][j] - m); lg[tid][j] = e; s += e; }
        float inv = 1.0f / s;
        for (int j = 0; j < 49; ++j) lg[tid][j] *= inv;
    }
    __syncthreads();
    for (int o = tid; o < 640; o += 256) {         // PV reduce (bf16 V, stride 32)
        int xq = o >> 4, dp = (o & 15) * 2;
        int sx = min(max(xq - 3, 0), WW - 7);
        float a0 = 0.f, a1 = 0.f;
        #pragma unroll
        for (int ky = 0; ky < 7; ++ky) {
            int vbase = ky * VP + sx * 32 + dp;
            #pragma unroll
            for (int jx = 0; jx < 7; ++jx) {
                float p = lg[xq][ky * 7 + jx];
                float2 v = __bfloat1622float2(*(const __hip_bfloat162*)&KVs[vbase + jx * 32]);
                a0 += p * v.x; a1 += p * v.y;
            }
        }
        __hip_bfloat162 o2;
        o2.x = __float2bfloat16(a0); o2.y = __float2bfloat16(a1);
        *(__hip_bfloat162*)(out + ((size_t)(n * 1600 + y * 40 + xq)) * 128 + head * 32 + dp) = o2;
    }
}

// ---- depthwise 3x3x3 conv + bias + exact GELU; fp32 in, bf16 out.
// v3: 512 thr x 1 ch (high occupancy) + branch-free loads (validity folded into
// zeroed weights, clamped uniform row offsets in SGPRs) + one-iteration prefetch
// + compile-time x-half specialization with full unroll.
// XCD-locality swizzle: same-XCD blocks get consecutive (n,y) chunks (shared rows).
template<int X0>
__device__ __forceinline__ void dw_body(const float* __restrict__ inp,
                                        const int* roff, const float* wr,
                                        float bs, int m, size_t outbase,
                                        bf16* __restrict__ outp) {
    float c0[9], c1[9], c2[9];
    #pragma unroll
    for (int p = 0; p < 9; ++p) {
        c0[p] = (X0 > 0) ? inp[roff[p] + (X0 - 1) * 512 + m] : 0.f;
        c1[p] = inp[roff[p] + X0 * 512 + m];
        c2[p] = inp[roff[p] + (X0 + 1) * 512 + m];
    }
    #pragma unroll
    for (int xi = 0; xi < 20; ++xi) {
        constexpr int XN_BASE = X0 + 2;
        int x = X0 + xi;
        float cn[9];
        if (XN_BASE + xi < 40) {
            #pragma unroll
            for (int p = 0; p < 9; ++p)
                cn[p] = inp[roff[p] + (XN_BASE + xi) * 512 + m];
        } else {
            #pragma unroll
            for (int p = 0; p < 9; ++p) cn[p] = 0.f;
        }
        float acc = bs;
        #pragma unroll
        for (int p = 0; p < 9; ++p)
            acc += wr[p * 3 + 0] * c0[p] + wr[p * 3 + 1] * c1[p] + wr[p * 3 + 2] * c2[p];
        float g = 0.5f * acc * (1.0f + erff(acc * 0.70710678118654752f));
        outp[outbase + (size_t)x * 512] = __float2bfloat16(g);
        #pragma unroll
        for (int p = 0; p < 9; ++p) { c0[p] = c1[p]; c1[p] = c2[p]; c2[p] = cn[p]; }
    }
}

__global__ __launch_bounds__(512, 4) void k_dwconv(const float* __restrict__ inp,
                                                   const float* __restrict__ w,
                                                   const float* __restrict__ bias,
                                                   bf16* __restrict__ outp) {
    int raw = blockIdx.x;                       // grid 1280
    int blk = (raw & 7) * 160 + (raw >> 3);     // chunk per XCD
    int xh = blk & 1;
    int ny = blk >> 1;
    int n = ny / 40, y = ny - n * 40;
    int b = n >> 3, t = n & 7;
    int m = threadIdx.x;
    float wr[27];
    int roff[9];                                // wave-uniform -> SGPRs
    #pragma unroll
    for (int dt = 0; dt < 3; ++dt) {
        #pragma unroll
        for (int dy = 0; dy < 3; ++dy) {
            int p = dt * 3 + dy;
            int tt = t + dt - 1, yy = y + dy - 1;
            bool v = (tt >= 0 && tt < 8 && yy >= 0 && yy < 40);
            int tc = min(max(tt, 0), 7), yc = min(max(yy, 0), 39);
            roff[p] = ((b * 8 + tc) * 1600 + yc * 40) * 512;
            #pragma unroll
            for (int q = 0; q < 3; ++q)
                wr[p * 3 + q] = v ? w[(p * 3 + q) * 512 + m] : 0.f;
        }
    }
    float bs = bias[m];
    size_t outbase = ((size_t)(n * 1600 + y * 40)) * 512 + m;
    if (xh == 0)
        dw_body<0>(inp, roff, wr, bs, m, outbase, outp);
    else
        dw_body<20>(inp, roff, wr, bs, m, outbase, outp);
}

extern "C" void kernel_launch(void* const* d_in, const int* in_sizes, int n_in,
                              void* d_out, int out_size, void* d_ws, size_t ws_size,
                              hipStream_t stream) {
    const float* x      = (const float*)d_in[0];
    const float* ln1_g  = (const float*)d_in[1];
    const float* ln1_b  = (const float*)d_in[2];
    const float* qkv_w  = (const float*)d_in[3];
    const float* qkv_b  = (const float*)d_in[4];
    const float* rpb    = (const float*)d_in[5];
    const float* proj_w = (const float*)d_in[6];
    const float* proj_b = (const float*)d_in[7];
    const float* ln2_g  = (const float*)d_in[8];
    const float* ln2_b  = (const float*)d_in[9];
    const float* fc1_w  = (const float*)d_in[10];
    const float* fc1_b  = (const float*)d_in[11];
    const float* dw_w   = (const float*)d_in[12];
    const float* dw_b   = (const float*)d_in[13];
    const float* fc2_w  = (const float*)d_in[14];
    const float* fc2_b  = (const float*)d_in[15];
    const float* out_g  = (const float*)d_in[16];
    const float* out_b  = (const float*)d_in[17];
    float* out = (float*)d_out;

    // workspace: h f32 | f1 f32 | qkvb bf16 | f2b bf16 | abufA bf16 | abufL bf16 | wt
    float* h     = (float*)d_ws;
    float* f1    = h + (size_t)NTOK * 128;
    bf16* qkvb   = (bf16*)(f1 + (size_t)NTOK * 512);
    bf16* f2b    = qkvb + (size_t)NTOK * 384;
    bf16* abufA  = f2b  + (size_t)NTOK * 512;
    bf16* abufL  = abufA + (size_t)NTOK * 128;
    bf16* wt     = abufL + (size_t)NTOK * 128;

    k_wt<<<96, 256, 0, stream>>>(qkv_w, proj_w, fc1_w, fc2_w, wt);
    k_transpose_in<<<NIMG * 200, 256, 0, stream>>>(x, h);
    for (int l = 0; l < 2; ++l) {
        const bf16* wtl = wt + (size_t)l * WT_L;
        if (l == 0) {
            k_lngemm<bf16><<<dim3(3, 400), 256, 0, stream>>>(
                h, wtl + WT_QKV, ln1_g, ln1_b, qkv_b, qkvb, 384);
        } else {
            k_gemm_mfma<64, 128, 32, 64, bf16><<<dim3(3, 400), 256, 0, stream>>>(
                abufL, wtl + WT_QKV, qkv_b + 384, nullptr, qkvb, 128, 384);
        }
        k_attn<<<NIMG * HH * NHEAD, 256, 0, stream>>>(qkvb, rpb + l * 4 * 169, abufA);
        // proj + residual + fused LN2 epilogue -> abufL
        k_gemm_ln<<<800, 256, 0, stream>>>(
            abufA, wtl + WT_PROJ, proj_b + l * 128, h,
            ln2_g + l * 128, ln2_b + l * 128, h, abufL, 128);
        // fc1: plain bf16-A GEMM
        k_gemm_mfma<64, 128, 32, 64, float><<<dim3(4, 400), 256, 0, stream>>>(
            abufL, wtl + WT_FC1, fc1_b + l * 512, nullptr, f1, 128, 512);
        k_dwconv<<<NIMG * HH * 2, 512, 0, stream>>>(f1, dw_w + l * 27 * 512, dw_b + l * 512, f2b);
        if (l == 0) {
            // fc2 + residual + fused LN1(layer 1) epilogue -> abufL
            k_gemm_ln<<<800, 256, 0, stream>>>(
                f2b, wtl + WT_FC2, fc2_b, h,
                ln1_g + 128, ln1_b + 128, h, abufL, 512);
        } else {
            // fc2 + residual + FINAL LN + transposed store
            k_gemm_lnout<<<800, 256, 0, stream>>>(
                f2b, wtl + WT_FC2, fc2_b + 128, h, out_g, out_b, out, 512);
        }
    }
}

// Round 5
// 371.105 us; speedup vs baseline: 1.1794x; 1.0291x over previous
//
#include <hip/hip_runtime.h>
#include <hip/hip_bf16.h>
#include <math.h>

typedef __hip_bfloat16 bf16;
typedef __attribute__((ext_vector_type(8))) short short8;
typedef __attribute__((ext_vector_type(4))) float floatx4;
typedef __attribute__((ext_vector_type(2))) float f32x2;
typedef _Float16 h2 __attribute__((ext_vector_type(2)));
typedef __fp16 hraw2 __attribute__((ext_vector_type(2)));

// packed f32 pair -> f16 pair (cvt_pkrtz), bitcast to _Float16 vector
static __device__ __forceinline__ h2 cvt2h(float a, float b) {
    union { hraw2 r; h2 h; } u;
    u.r = __builtin_amdgcn_cvt_pkrtz(a, b);
    return u.h;
}

#define HH 40
#define WW 40
#define CC 128
#define TT 8
#define NIMG 16           // B*T
#define NTOK 25600        // NIMG*HH*WW
#define MDIM 512
#define NHEAD 4
#define KVP 1608          // K LDS plane stride in shorts (40 sh/kx: b128-friendly)
#define VP  1280          // V LDS plane stride in shorts (32 sh/kx: PV conflict-free)
#define LGS 68            // lg row stride in floats (16B-aligned, !=0 mod 32: conflict-free)

// weight-transpose buffer offsets (bf16 elems), per layer
#define WT_QKV 0
#define WT_PROJ 49152
#define WT_FC1  65536
#define WT_FC2  131072
#define WT_L    196608

// ---- input transpose via LDS tiles: x (b,c,t,y,x) -> h (n,y,x,c), both coalesced.
__global__ __launch_bounds__(256) void k_transpose_in(const float* __restrict__ x,
                                                      float* __restrict__ h) {
    int blk = blockIdx.x;
    int n = blk / 200; int r = blk % 200; int ci = r / 50, ri = r % 50;
    int b = n >> 3, t = n & 7;
    int c0 = ci * 32, r0 = ri * 32;
    __shared__ float tile[32][33];
    int tid = threadIdx.x;
    int lc = tid >> 5, lr = tid & 31;         // 8 x 32
    #pragma unroll
    for (int it = 0; it < 4; ++it) {
        int cc = it * 8 + lc;
        tile[cc][lr] = x[((size_t)((b * 128 + c0 + cc) * 8 + t)) * 1600 + r0 + lr];
    }
    __syncthreads();
    #pragma unroll
    for (int it = 0; it < 4; ++it) {
        int rr = it * 8 + lc;
        h[((size_t)(n * 1600 + r0 + rr)) * 128 + c0 + lr] = tile[lr][rr];
    }
}

// ---- weight convert+transpose: W[K,N] fp32 -> Wt[N,K] bf16, 64x64 LDS tiles.
__global__ __launch_bounds__(256) void k_wt(const float* __restrict__ qkv_w,
                                            const float* __restrict__ proj_w,
                                            const float* __restrict__ fc1_w,
                                            const float* __restrict__ fc2_w,
                                            bf16* __restrict__ wt) {
    __shared__ float tile[64][65];
    int id = blockIdx.x;
    int l = id / 48, r = id % 48;
    const float* src; bf16* dst; int K_, N_, t;
    if (r < 12)      { src = qkv_w  + l * 128 * 384; dst = wt + l * WT_L + WT_QKV; K_ = 128; N_ = 384; t = r; }
    else if (r < 16) { src = proj_w + l * 128 * 128; dst = wt + l * WT_L + WT_PROJ; K_ = 128; N_ = 128; t = r - 12; }
    else if (r < 32) { src = fc1_w  + l * 128 * 512; dst = wt + l * WT_L + WT_FC1; K_ = 128; N_ = 512; t = r - 16; }
    else             { src = fc2_w  + l * 512 * 128; dst = wt + l * WT_L + WT_FC2; K_ = 512; N_ = 128; t = r - 32; }
    int KT = K_ >> 6;
    int k0 = (t % KT) * 64, n0 = (t / KT) * 64;
    int tid = threadIdx.x;
    for (int c = tid; c < 4096; c += 256) {
        int kk = c >> 6, nn = c & 63;
        tile[kk][nn] = src[(size_t)(k0 + kk) * N_ + n0 + nn];
    }
    __syncthreads();
    for (int c = tid; c < 4096; c += 256) {
        int nn = c >> 6, kk = c & 63;
        dst[(size_t)(n0 + nn) * K_ + k0 + kk] = __float2bfloat16(tile[kk][nn]);
    }
}

// ---- fused LayerNorm + MFMA GEMM (fp32 A): only layer-0 qkv.
template<typename OutT>
__global__ __launch_bounds__(256) void k_lngemm(const float* __restrict__ A,
                                                const bf16* __restrict__ Bt,
                                                const float* __restrict__ g,
                                                const float* __restrict__ be,
                                                const float* __restrict__ bias,
                                                OutT* __restrict__ D,
                                                int N) {
    constexpr int LDK = 40;
    __shared__ bf16 As[64 * LDK];
    __shared__ bf16 Bs[128 * LDK];
    __shared__ float sMean[64], sRstd[64], sG[128], sB[128];
    int tid = threadIdx.x;
    int m0 = blockIdx.y * 64, n0 = blockIdx.x * 128;
    {
        int row = tid >> 2, q4 = tid & 3;
        const float* p = A + (size_t)(m0 + row) * 128 + q4 * 32;
        float s = 0.f, q = 0.f;
        #pragma unroll
        for (int i = 0; i < 32; i += 4) {
            float4 f = *(const float4*)(p + i);
            s += f.x + f.y + f.z + f.w;
            q += f.x * f.x + f.y * f.y + f.z * f.z + f.w * f.w;
        }
        s += __shfl_xor(s, 1); q += __shfl_xor(q, 1);
        s += __shfl_xor(s, 2); q += __shfl_xor(q, 2);
        if (q4 == 0) {
            float mean = s * (1.0f / 128.0f);
            float var = q * (1.0f / 128.0f) - mean * mean;
            sMean[row] = mean;
            sRstd[row] = rsqrtf(var + 1e-5f);
        }
        if (tid < 128) { sG[tid] = g[tid]; sB[tid] = be[tid]; }
    }
    __syncthreads();
    int wave = tid >> 6, lane = tid & 63;
    int l15 = lane & 15, quad = lane >> 4;
    int wr = wave >> 1, wc = wave & 1;
    floatx4 acc[2][4];
    #pragma unroll
    for (int i = 0; i < 2; ++i)
        #pragma unroll
        for (int j = 0; j < 4; ++j)
            acc[i][j] = (floatx4){0.f, 0.f, 0.f, 0.f};

    for (int k0 = 0; k0 < 128; k0 += 32) {
        #pragma unroll
        for (int it = 0; it < 2; ++it) {
            int c = tid + it * 256;
            int row = c >> 3, kq = (c & 7) * 4;
            float4 f = *(const float4*)(A + (size_t)(m0 + row) * 128 + k0 + kq);
            float mean = sMean[row], rst = sRstd[row];
            float r0v = (f.x - mean) * rst * sG[k0 + kq]     + sB[k0 + kq];
            float r1v = (f.y - mean) * rst * sG[k0 + kq + 1] + sB[k0 + kq + 1];
            float r2v = (f.z - mean) * rst * sG[k0 + kq + 2] + sB[k0 + kq + 2];
            float r3v = (f.w - mean) * rst * sG[k0 + kq + 3] + sB[k0 + kq + 3];
            __hip_bfloat162 p0, p1;
            p0.x = __float2bfloat16(r0v); p0.y = __float2bfloat16(r1v);
            p1.x = __float2bfloat16(r2v); p1.y = __float2bfloat16(r3v);
            *(__hip_bfloat162*)&As[row * LDK + kq]     = p0;
            *(__hip_bfloat162*)&As[row * LDK + kq + 2] = p1;
        }
        #pragma unroll
        for (int c = tid; c < 512; c += 256) {
            int row = c >> 2, off = (c & 3) * 8;
            *(uint4*)&Bs[row * LDK + off] =
                *(const uint4*)&Bt[(size_t)(n0 + row) * 128 + k0 + off];
        }
        __syncthreads();
        short8 af[2], bfr[4];
        #pragma unroll
        for (int i = 0; i < 2; ++i)
            af[i] = *(const short8*)&As[(wr * 32 + i * 16 + l15) * LDK + quad * 8];
        #pragma unroll
        for (int j = 0; j < 4; ++j)
            bfr[j] = *(const short8*)&Bs[(wc * 64 + j * 16 + l15) * LDK + quad * 8];
        #pragma unroll
        for (int i = 0; i < 2; ++i)
            #pragma unroll
            for (int j = 0; j < 4; ++j)
                acc[i][j] = __builtin_amdgcn_mfma_f32_16x16x32_bf16(af[i], bfr[j], acc[i][j], 0, 0, 0);
        __syncthreads();
    }
    #pragma unroll
    for (int i = 0; i < 2; ++i) {
        #pragma unroll
        for (int j = 0; j < 4; ++j) {
            int nn = n0 + wc * 64 + j * 16 + l15;
            float bv = bias[nn];
            #pragma unroll
            for (int rg = 0; rg < 4; ++rg) {
                int m = m0 + wr * 32 + i * 16 + quad * 4 + rg;
                float v = acc[i][j][rg] + bv;
                if constexpr (sizeof(OutT) == 2)
                    D[(size_t)m * N + nn] = __float2bfloat16(v);
                else
                    D[(size_t)m * N + nn] = v;
            }
        }
    }
}

// ---- MFMA bf16 GEMM: D[M,N] = A[M,K] @ Bt[N,K]^T + bias (+R).
template<int BM, int BN, int WM, int WN, typename OutT>
__global__ __launch_bounds__(256) void k_gemm_mfma(const bf16* __restrict__ A,
                                                   const bf16* __restrict__ Bt,
                                                   const float* __restrict__ bias,
                                                   const float* __restrict__ R,
                                                   OutT* __restrict__ D,
                                                   int K, int N) {
    constexpr int LDK = 40;
    __shared__ bf16 As[BM * LDK];
    __shared__ bf16 Bs[BN * LDK];
    int tid = threadIdx.x;
    int wave = tid >> 6, lane = tid & 63;
    int l15 = lane & 15, quad = lane >> 4;
    constexpr int WCOLS = BN / WN;
    int wr = wave / WCOLS, wc = wave % WCOLS;
    int m0 = blockIdx.y * BM, n0 = blockIdx.x * BN;
    constexpr int MI = WM / 16, NJ = WN / 16;
    floatx4 acc[MI][NJ];
    #pragma unroll
    for (int i = 0; i < MI; ++i)
        #pragma unroll
        for (int j = 0; j < NJ; ++j)
            acc[i][j] = (floatx4){0.f, 0.f, 0.f, 0.f};

    for (int k0 = 0; k0 < K; k0 += 32) {
        #pragma unroll
        for (int c = tid; c < BM * 4; c += 256) {
            int row = c >> 2, off = (c & 3) * 8;
            *(uint4*)&As[row * LDK + off] =
                *(const uint4*)&A[(size_t)(m0 + row) * K + k0 + off];
        }
        #pragma unroll
        for (int c = tid; c < BN * 4; c += 256) {
            int row = c >> 2, off = (c & 3) * 8;
            *(uint4*)&Bs[row * LDK + off] =
                *(const uint4*)&Bt[(size_t)(n0 + row) * K + k0 + off];
        }
        __syncthreads();
        short8 af[MI], bfr[NJ];
        #pragma unroll
        for (int i = 0; i < MI; ++i)
            af[i] = *(const short8*)&As[(wr * WM + i * 16 + l15) * LDK + quad * 8];
        #pragma unroll
        for (int j = 0; j < NJ; ++j)
            bfr[j] = *(const short8*)&Bs[(wc * WN + j * 16 + l15) * LDK + quad * 8];
        #pragma unroll
        for (int i = 0; i < MI; ++i)
            #pragma unroll
            for (int j = 0; j < NJ; ++j)
                acc[i][j] = __builtin_amdgcn_mfma_f32_16x16x32_bf16(af[i], bfr[j], acc[i][j], 0, 0, 0);
        __syncthreads();
    }
    #pragma unroll
    for (int i = 0; i < MI; ++i) {
        #pragma unroll
        for (int j = 0; j < NJ; ++j) {
            int nn = n0 + wc * WN + j * 16 + l15;
            float bv = bias[nn];
            #pragma unroll
            for (int rg = 0; rg < 4; ++rg) {
                int m = m0 + wr * WM + i * 16 + quad * 4 + rg;
                float v = acc[i][j][rg] + bv;
                if (R) v += R[(size_t)m * N + nn];
                if constexpr (sizeof(OutT) == 2)
                    D[(size_t)m * N + nn] = __float2bfloat16(v);
                else
                    D[(size_t)m * N + nn] = v;
            }
        }
    }
}

// ---- GEMM (N=128) + residual + fused next-LayerNorm epilogue.
__global__ __launch_bounds__(256) void k_gemm_ln(const bf16* __restrict__ A,
                                                 const bf16* __restrict__ Bt,
                                                 const float* __restrict__ bias,
                                                 const float* __restrict__ R,
                                                 const float* __restrict__ g,
                                                 const float* __restrict__ be,
                                                 float* __restrict__ Dres,
                                                 bf16* __restrict__ Aout,
                                                 int K) {
    constexpr int LDK = 40;
    __shared__ bf16 As[32 * LDK];
    __shared__ bf16 Bs[128 * LDK];
    __shared__ float ot[32][132];
    __shared__ float sG[128], sB[128];
    int tid = threadIdx.x;
    int wave = tid >> 6, lane = tid & 63;
    int l15 = lane & 15, quad = lane >> 4;
    int wr = wave >> 1, wc = wave & 1;
    int m0 = blockIdx.x * 32;
    if (tid < 128) { sG[tid] = g[tid]; sB[tid] = be[tid]; }
    floatx4 acc[4];
    #pragma unroll
    for (int j = 0; j < 4; ++j) acc[j] = (floatx4){0.f, 0.f, 0.f, 0.f};

    for (int k0 = 0; k0 < K; k0 += 32) {
        if (tid < 128) {
            int row = tid >> 2, off = (tid & 3) * 8;
            *(uint4*)&As[row * LDK + off] =
                *(const uint4*)&A[(size_t)(m0 + row) * K + k0 + off];
        }
        #pragma unroll
        for (int c = tid; c < 512; c += 256) {
            int row = c >> 2, off = (c & 3) * 8;
            *(uint4*)&Bs[row * LDK + off] =
                *(const uint4*)&Bt[(size_t)row * K + k0 + off];
        }
        __syncthreads();
        short8 af = *(const short8*)&As[(wr * 16 + l15) * LDK + quad * 8];
        short8 bfr[4];
        #pragma unroll
        for (int j = 0; j < 4; ++j)
            bfr[j] = *(const short8*)&Bs[(wc * 64 + j * 16 + l15) * LDK + quad * 8];
        #pragma unroll
        for (int j = 0; j < 4; ++j)
            acc[j] = __builtin_amdgcn_mfma_f32_16x16x32_bf16(af, bfr[j], acc[j], 0, 0, 0);
        __syncthreads();
    }
    #pragma unroll
    for (int j = 0; j < 4; ++j) {
        int nn = wc * 64 + j * 16 + l15;
        float bv = bias[nn];
        #pragma unroll
        for (int rg = 0; rg < 4; ++rg) {
            int m = wr * 16 + quad * 4 + rg;
            ot[m][nn] = acc[j][rg] + bv + R[(size_t)(m0 + m) * 128 + nn];
        }
    }
    __syncthreads();
    int row = tid >> 3, sub = tid & 7;
    float vv[16];
    float s = 0.f, q = 0.f;
    #pragma unroll
    for (int i = 0; i < 16; ++i) {
        float v = ot[row][sub * 16 + i];
        vv[i] = v; s += v; q += v * v;
    }
    #pragma unroll
    for (int o = 4; o > 0; o >>= 1) { s += __shfl_xor(s, o); q += __shfl_xor(q, o); }
    float mean = s * (1.0f / 128.0f);
    float var = q * (1.0f / 128.0f) - mean * mean;
    float rst = rsqrtf(var + 1e-5f);
    size_t base = (size_t)(m0 + row) * 128 + sub * 16;
    #pragma unroll
    for (int i = 0; i < 16; i += 4)
        *(float4*)(Dres + base + i) = (float4){vv[i], vv[i+1], vv[i+2], vv[i+3]};
    #pragma unroll
    for (int i = 0; i < 16; i += 2) {
        int ch = sub * 16 + i;
        __hip_bfloat162 o2;
        o2.x = __float2bfloat16((vv[i]     - mean) * rst * sG[ch]     + sB[ch]);
        o2.y = __float2bfloat16((vv[i + 1] - mean) * rst * sG[ch + 1] + sB[ch + 1]);
        *(__hip_bfloat162*)(Aout + base + i) = o2;
    }
}

// ---- GEMM (N=128) + residual + FINAL LayerNorm + transposed store to (b,c,t,y,x).
__global__ __launch_bounds__(256) void k_gemm_lnout(const bf16* __restrict__ A,
                                                    const bf16* __restrict__ Bt,
                                                    const float* __restrict__ bias,
                                                    const float* __restrict__ R,
                                                    const float* __restrict__ g,
                                                    const float* __restrict__ be,
                                                    float* __restrict__ out,
                                                    int K) {
    constexpr int LDK = 40;
    __shared__ bf16 As[32 * LDK];
    __shared__ bf16 Bs[128 * LDK];
    __shared__ float ot[32][133];    // pad 133: conflict-free transposed reads
    __shared__ float sG[128], sB[128];
    int tid = threadIdx.x;
    int wave = tid >> 6, lane = tid & 63;
    int l15 = lane & 15, quad = lane >> 4;
    int wr = wave >> 1, wc = wave & 1;
    int m0 = blockIdx.x * 32;
    if (tid < 128) { sG[tid] = g[tid]; sB[tid] = be[tid]; }
    floatx4 acc[4];
    #pragma unroll
    for (int j = 0; j < 4; ++j) acc[j] = (floatx4){0.f, 0.f, 0.f, 0.f};

    for (int k0 = 0; k0 < K; k0 += 32) {
        if (tid < 128) {
            int row = tid >> 2, off = (tid & 3) * 8;
            *(uint4*)&As[row * LDK + off] =
                *(const uint4*)&A[(size_t)(m0 + row) * K + k0 + off];
        }
        #pragma unroll
        for (int c = tid; c < 512; c += 256) {
            int row = c >> 2, off = (c & 3) * 8;
            *(uint4*)&Bs[row * LDK + off] =
                *(const uint4*)&Bt[(size_t)row * K + k0 + off];
        }
        __syncthreads();
        short8 af = *(const short8*)&As[(wr * 16 + l15) * LDK + quad * 8];
        short8 bfr[4];
        #pragma unroll
        for (int j = 0; j < 4; ++j)
            bfr[j] = *(const short8*)&Bs[(wc * 64 + j * 16 + l15) * LDK + quad * 8];
        #pragma unroll
        for (int j = 0; j < 4; ++j)
            acc[j] = __builtin_amdgcn_mfma_f32_16x16x32_bf16(af, bfr[j], acc[j], 0, 0, 0);
        __syncthreads();
    }
    #pragma unroll
    for (int j = 0; j < 4; ++j) {
        int nn = wc * 64 + j * 16 + l15;
        float bv = bias[nn];
        #pragma unroll
        for (int rg = 0; rg < 4; ++rg) {
            int m = wr * 16 + quad * 4 + rg;
            ot[m][nn] = acc[j][rg] + bv + R[(size_t)(m0 + m) * 128 + nn];
        }
    }
    __syncthreads();
    int row = tid >> 3, sub = tid & 7;
    float vv[16];
    float s = 0.f, q = 0.f;
    #pragma unroll
    for (int i = 0; i < 16; ++i) {
        float v = ot[row][sub * 16 + i];
        vv[i] = v; s += v; q += v * v;
    }
    #pragma unroll
    for (int o = 4; o > 0; o >>= 1) { s += __shfl_xor(s, o); q += __shfl_xor(q, o); }
    float mean = s * (1.0f / 128.0f);
    float var = q * (1.0f / 128.0f) - mean * mean;
    float rst = rsqrtf(var + 1e-5f);
    #pragma unroll
    for (int i = 0; i < 16; ++i) {
        int ch = sub * 16 + i;
        ot[row][ch] = (vv[i] - mean) * rst * sG[ch] + sB[ch];
    }
    __syncthreads();
    int n = m0 / 1600, rem0 = m0 % 1600;
    int b = n >> 3, t = n & 7;
    #pragma unroll
    for (int it = 0; it < 16; ++it) {
        int idx = it * 256 + tid;
        int ch = idx >> 5, tk = idx & 31;
        out[((size_t)((b * 128 + ch) * 8 + t)) * 1600 + rem0 + tk] = ot[tk][ch];
    }
}

// ---- row-tiled 7x7 neighborhood attention; f16 K + fdot2 logits.
// v3: LDS-pipe diet. lg -> [40][LGS] f32 with j=ky*8+jx, slot7=-1e30 (self-masking
// pad) so PV reads p via 2x ds_read_b128 per (item,ky) instead of 49x b32/item.
// PV re-tiled: thread per (xq, chan-quad) -> per jx ONE ds_read_b64 (4 chans).
// Softmax wave-parallel: 160 thr, 4 lanes/row, float4 reads + quad shfl reduce.
// K/q bf16->f16 via cvt_pkrtz (1 inst per pair).
// XCD-locality swizzle: same-XCD blocks get consecutive y (shared K/V windows).
__global__ __launch_bounds__(256) void k_attn(const bf16* __restrict__ qkv,
                                              const float* __restrict__ rpb,
                                              bf16* __restrict__ out) {
    int raw = blockIdx.x;                       // grid 2560
    int blk = (raw & 7) * 320 + (raw >> 3);     // chunk per XCD
    int head = blk & 3;
    int ny = blk >> 2;
    int n = ny / 40, y = ny % 40;
    int sy = min(max(y - 3, 0), HH - 7);
    __shared__ __align__(16) short KVs[7 * KVP];   // K (f16, stride 40) then V (bf16, stride 32)
    __shared__ __align__(16) float lg[40][LGS];
    int tid = threadIdx.x;
    // phase 1: K window, bf16 -> f16 (packed cvt)
    for (int i2 = tid; i2 < 1120; i2 += 256) {
        int d8 = i2 & 3, kx = (i2 >> 2) % 40, ky = i2 / 160;
        size_t base = ((size_t)(n * 1600 + (sy + ky) * 40 + kx)) * 384 + 128 + head * 32 + d8 * 8;
        union { uint4 u; __hip_bfloat162 b[4]; } U;
        U.u = *(const uint4*)(qkv + base);
        union { short8 s; h2 h[4]; } W;
        #pragma unroll
        for (int c = 0; c < 4; ++c) {
            float2 f = __bfloat1622float2(U.b[c]);
            W.h[c] = cvt2h(f.x, f.y);
        }
        *(short8*)&KVs[ky * KVP + kx * 40 + d8 * 8] = W.s;
    }
    __syncthreads();
    // logits: thread per (xq, ky); q loaded from global, converted in regs
    for (int p2 = tid; p2 < 280; p2 += 256) {
        int xq = p2 / 7, ky = p2 - (p2 / 7) * 7;
        int sx = min(max(xq - 3, 0), WW - 7);
        const bf16* qg = qkv + ((size_t)(n * 1600 + y * 40 + xq)) * 384 + head * 32;
        union { uint4 u; __hip_bfloat162 b[4]; } U[4];
        #pragma unroll
        for (int u = 0; u < 4; ++u) U[u].u = *(const uint4*)(qg + u * 8);
        h2 qh[16];
        #pragma unroll
        for (int c = 0; c < 16; ++c) {
            float2 f = __bfloat1622float2(U[c >> 2].b[c & 3]);
            qh[c] = cvt2h(f.x, f.y);
        }
        const float* rb = rpb + head * 169 + (sy + ky - y + 6) * 13 + (sx - xq + 6);
        int kbase = ky * KVP + sx * 40;
        #pragma unroll
        for (int jx = 0; jx < 7; ++jx) {
            const h2* kp = (const h2*)&KVs[kbase + jx * 40];
            float dot = 0.f;
            #pragma unroll
            for (int c = 0; c < 16; ++c)
                dot = __builtin_amdgcn_fdot2(qh[c], kp[c], dot, false);
            lg[xq][ky * 8 + jx] = dot * 0.1767766952966369f + rb[jx];
        }
        lg[xq][ky * 8 + 7] = -1e30f;   // pad slot: self-masking in softmax & PV
    }
    __syncthreads();
    // phase 2: V window (raw bf16 bits, stride 32), softmax concurrently
    for (int i2 = tid; i2 < 1120; i2 += 256) {
        int d8 = i2 & 3, kx = (i2 >> 2) % 40, ky = i2 / 160;
        size_t base = ((size_t)(n * 1600 + (sy + ky) * 40 + kx)) * 384 + 256 + head * 32 + d8 * 8;
        *(uint4*)&KVs[ky * VP + kx * 32 + d8 * 8] = *(const uint4*)(qkv + base);
    }
    // wave-parallel softmax over 56 padded slots: 4 lanes/row
    if (tid < 160) {
        int row = tid >> 2, q = tid & 3;
        int nb = (q == 3) ? 2 : 4;        // q<3: slots [q*16,+16); q3: [48,56)
        const float4* lp = (const float4*)&lg[row][q * 16];
        float4 f[4];
        #pragma unroll
        for (int i = 0; i < 4; ++i)
            if (i < nb) f[i] = lp[i];
        float m = -1e30f;
        #pragma unroll
        for (int i = 0; i < 4; ++i)
            if (i < nb) m = fmaxf(m, fmaxf(fmaxf(f[i].x, f[i].y), fmaxf(f[i].z, f[i].w)));
        m = fmaxf(m, __shfl_xor(m, 1));
        m = fmaxf(m, __shfl_xor(m, 2));
        float s = 0.f;
        #pragma unroll
        for (int i = 0; i < 4; ++i)
            if (i < nb) {
                f[i].x = expf(f[i].x - m); f[i].y = expf(f[i].y - m);
                f[i].z = expf(f[i].z - m); f[i].w = expf(f[i].w - m);
                s += f[i].x + f[i].y + f[i].z + f[i].w;
            }
        s += __shfl_xor(s, 1);
        s += __shfl_xor(s, 2);
        float inv = 1.0f / s;
        float4* sp = (float4*)&lg[row][q * 16];
        #pragma unroll
        for (int i = 0; i < 4; ++i)
            if (i < nb) {
                f[i].x *= inv; f[i].y *= inv; f[i].z *= inv; f[i].w *= inv;
                sp[i] = f[i];
            }
    }
    __syncthreads();
    // PV: thread per (xq, chan-quad); per jx one b64 V read; p via 2 b128/ky
    for (int o = tid; o < 320; o += 256) {
        int xq = o >> 3, cq = o & 7;
        int sx = min(max(xq - 3, 0), WW - 7);
        float a0 = 0.f, a1 = 0.f, a2 = 0.f, a3 = 0.f;
        #pragma unroll
        for (int ky = 0; ky < 7; ++ky) {
            float4 pa = *(const float4*)&lg[xq][ky * 8];
            float4 pb = *(const float4*)&lg[xq][ky * 8 + 4];
            float ps[8] = {pa.x, pa.y, pa.z, pa.w, pb.x, pb.y, pb.z, pb.w};
            int vb = ky * VP + sx * 32 + cq * 4;
            #pragma unroll
            for (int jx = 0; jx < 7; ++jx) {
                float p = ps[jx];
                uint2 vv = *(const uint2*)&KVs[vb + jx * 32];
                float2 v0 = __bfloat1622float2(*(const __hip_bfloat162*)&vv.x);
                float2 v1 = __bfloat1622float2(*(const __hip_bfloat162*)&vv.y);
                a0 += p * v0.x; a1 += p * v0.y;
                a2 += p * v1.x; a3 += p * v1.y;
            }
        }
        __hip_bfloat162 o01, o23;
        o01.x = __float2bfloat16(a0); o01.y = __float2bfloat16(a1);
        o23.x = __float2bfloat16(a2); o23.y = __float2bfloat16(a3);
        bf16* op = out + ((size_t)(n * 1600 + y * 40 + xq)) * 128 + head * 32 + cq * 4;
        *(__hip_bfloat162*)op = o01;
        *(__hip_bfloat162*)(op + 2) = o23;
    }
}

// ---- depthwise 3x3x3 conv + bias + exact GELU; fp32 in, bf16 out.
// v3: 512 thr x 1 ch (high occupancy) + branch-free loads (validity folded into
// zeroed weights, clamped uniform row offsets in SGPRs) + one-iteration prefetch
// + compile-time x-half specialization with full unroll.
// XCD-locality swizzle: same-XCD blocks get consecutive (n,y) chunks (shared rows).
template<int X0>
__device__ __forceinline__ void dw_body(const float* __restrict__ inp,
                                        const int* roff, const float* wr,
                                        float bs, int m, size_t outbase,
                                        bf16* __restrict__ outp) {
    float c0[9], c1[9], c2[9];
    #pragma unroll
    for (int p = 0; p < 9; ++p) {
        c0[p] = (X0 > 0) ? inp[roff[p] + (X0 - 1) * 512 + m] : 0.f;
        c1[p] = inp[roff[p] + X0 * 512 + m];
        c2[p] = inp[roff[p] + (X0 + 1) * 512 + m];
    }
    #pragma unroll
    for (int xi = 0; xi < 20; ++xi) {
        constexpr int XN_BASE = X0 + 2;
        int x = X0 + xi;
        float cn[9];
        if (XN_BASE + xi < 40) {
            #pragma unroll
            for (int p = 0; p < 9; ++p)
                cn[p] = inp[roff[p] + (XN_BASE + xi) * 512 + m];
        } else {
            #pragma unroll
            for (int p = 0; p < 9; ++p) cn[p] = 0.f;
        }
        float acc = bs;
        #pragma unroll
        for (int p = 0; p < 9; ++p)
            acc += wr[p * 3 + 0] * c0[p] + wr[p * 3 + 1] * c1[p] + wr[p * 3 + 2] * c2[p];
        float g = 0.5f * acc * (1.0f + erff(acc * 0.70710678118654752f));
        outp[outbase + (size_t)x * 512] = __float2bfloat16(g);
        #pragma unroll
        for (int p = 0; p < 9; ++p) { c0[p] = c1[p]; c1[p] = c2[p]; c2[p] = cn[p]; }
    }
}

__global__ __launch_bounds__(512, 4) void k_dwconv(const float* __restrict__ inp,
                                                   const float* __restrict__ w,
                                                   const float* __restrict__ bias,
                                                   bf16* __restrict__ outp) {
    int raw = blockIdx.x;                       // grid 1280
    int blk = (raw & 7) * 160 + (raw >> 3);     // chunk per XCD
    int xh = blk & 1;
    int ny = blk >> 1;
    int n = ny / 40, y = ny - n * 40;
    int b = n >> 3, t = n & 7;
    int m = threadIdx.x;
    float wr[27];
    int roff[9];                                // wave-uniform -> SGPRs
    #pragma unroll
    for (int dt = 0; dt < 3; ++dt) {
        #pragma unroll
        for (int dy = 0; dy < 3; ++dy) {
            int p = dt * 3 + dy;
            int tt = t + dt - 1, yy = y + dy - 1;
            bool v = (tt >= 0 && tt < 8 && yy >= 0 && yy < 40);
            int tc = min(max(tt, 0), 7), yc = min(max(yy, 0), 39);
            roff[p] = ((b * 8 + tc) * 1600 + yc * 40) * 512;
            #pragma unroll
            for (int q = 0; q < 3; ++q)
                wr[p * 3 + q] = v ? w[(p * 3 + q) * 512 + m] : 0.f;
        }
    }
    float bs = bias[m];
    size_t outbase = ((size_t)(n * 1600 + y * 40)) * 512 + m;
    if (xh == 0)
        dw_body<0>(inp, roff, wr, bs, m, outbase, outp);
    else
        dw_body<20>(inp, roff, wr, bs, m, outbase, outp);
}

extern "C" void kernel_launch(void* const* d_in, const int* in_sizes, int n_in,
                              void* d_out, int out_size, void* d_ws, size_t ws_size,
                              hipStream_t stream) {
    const float* x      = (const float*)d_in[0];
    const float* ln1_g  = (const float*)d_in[1];
    const float* ln1_b  = (const float*)d_in[2];
    const float* qkv_w  = (const float*)d_in[3];
    const float* qkv_b  = (const float*)d_in[4];
    const float* rpb    = (const float*)d_in[5];
    const float* proj_w = (const float*)d_in[6];
    const float* proj_b = (const float*)d_in[7];
    const float* ln2_g  = (const float*)d_in[8];
    const float* ln2_b  = (const float*)d_in[9];
    const float* fc1_w  = (const float*)d_in[10];
    const float* fc1_b  = (const float*)d_in[11];
    const float* dw_w   = (const float*)d_in[12];
    const float* dw_b   = (const float*)d_in[13];
    const float* fc2_w  = (const float*)d_in[14];
    const float* fc2_b  = (const float*)d_in[15];
    const float* out_g  = (const float*)d_in[16];
    const float* out_b  = (const float*)d_in[17];
    float* out = (float*)d_out;

    // workspace: h f32 | f1 f32 | qkvb bf16 | f2b bf16 | abufA bf16 | abufL bf16 | wt
    float* h     = (float*)d_ws;
    float* f1    = h + (size_t)NTOK * 128;
    bf16* qkvb   = (bf16*)(f1 + (size_t)NTOK * 512);
    bf16* f2b    = qkvb + (size_t)NTOK * 384;
    bf16* abufA  = f2b  + (size_t)NTOK * 512;
    bf16* abufL  = abufA + (size_t)NTOK * 128;
    bf16* wt     = abufL + (size_t)NTOK * 128;

    k_wt<<<96, 256, 0, stream>>>(qkv_w, proj_w, fc1_w, fc2_w, wt);
    k_transpose_in<<<NIMG * 200, 256, 0, stream>>>(x, h);
    for (int l = 0; l < 2; ++l) {
        const bf16* wtl = wt + (size_t)l * WT_L;
        if (l == 0) {
            k_lngemm<bf16><<<dim3(3, 400), 256, 0, stream>>>(
                h, wtl + WT_QKV, ln1_g, ln1_b, qkv_b, qkvb, 384);
        } else {
            k_gemm_mfma<64, 128, 32, 64, bf16><<<dim3(3, 400), 256, 0, stream>>>(
                abufL, wtl + WT_QKV, qkv_b + 384, nullptr, qkvb, 128, 384);
        }
        k_attn<<<NIMG * HH * NHEAD, 256, 0, stream>>>(qkvb, rpb + l * 4 * 169, abufA);
        // proj + residual + fused LN2 epilogue -> abufL
        k_gemm_ln<<<800, 256, 0, stream>>>(
            abufA, wtl + WT_PROJ, proj_b + l * 128, h,
            ln2_g + l * 128, ln2_b + l * 128, h, abufL, 128);
        // fc1: plain bf16-A GEMM
        k_gemm_mfma<64, 128, 32, 64, float><<<dim3(4, 400), 256, 0, stream>>>(
            abufL, wtl + WT_FC1, fc1_b + l * 512, nullptr, f1, 128, 512);
        k_dwconv<<<NIMG * HH * 2, 512, 0, stream>>>(f1, dw_w + l * 27 * 512, dw_b + l * 512, f2b);
        if (l == 0) {
            // fc2 + residual + fused LN1(layer 1) epilogue -> abufL
            k_gemm_ln<<<800, 256, 0, stream>>>(
                f2b, wtl + WT_FC2, fc2_b, h,
                ln1_g + 128, ln1_b + 128, h, abufL, 512);
        } else {
            // fc2 + residual + FINAL LN + transposed store
            k_gemm_lnout<<<800, 256, 0, stream>>>(
                f2b, wtl + WT_FC2, fc2_b + 128, h, out_g, out_b, out, 512);
        }
    }
}

// Round 6
// 365.116 us; speedup vs baseline: 1.1987x; 1.0164x over previous
//
#include <hip/hip_runtime.h>
#include <hip/hip_bf16.h>
#include <math.h>

typedef __hip_bfloat16 bf16;
typedef __attribute__((ext_vector_type(8))) short short8;
typedef __attribute__((ext_vector_type(4))) float floatx4;
typedef __attribute__((ext_vector_type(2))) float f32x2;
typedef _Float16 h2 __attribute__((ext_vector_type(2)));
typedef __fp16 hraw2 __attribute__((ext_vector_type(2)));

// packed f32 pair -> f16 pair (cvt_pkrtz), bitcast to _Float16 vector
static __device__ __forceinline__ h2 cvt2h(float a, float b) {
    union { hraw2 r; h2 h; } u;
    u.r = __builtin_amdgcn_cvt_pkrtz(a, b);
    return u.h;
}

#define HH 40
#define WW 40
#define CC 128
#define TT 8
#define NIMG 16           // B*T
#define NTOK 25600        // NIMG*HH*WW
#define MDIM 512
#define NHEAD 4
#define KVP 1608          // K LDS plane stride in shorts (40 sh/kx: b128-friendly)
#define VP  1280          // V LDS plane stride in shorts (32 sh/kx: PV conflict-free)
#define LGS 60            // lg row stride in floats; 56 used. 60 keeps total LDS < 32KB -> 5 blk/CU

// weight-transpose buffer offsets (bf16 elems), per layer
#define WT_QKV 0
#define WT_PROJ 49152
#define WT_FC1  65536
#define WT_FC2  131072
#define WT_L    196608

// ---- input transpose via LDS tiles: x (b,c,t,y,x) -> h (n,y,x,c), both coalesced.
__global__ __launch_bounds__(256) void k_transpose_in(const float* __restrict__ x,
                                                      float* __restrict__ h) {
    int blk = blockIdx.x;
    int n = blk / 200; int r = blk % 200; int ci = r / 50, ri = r % 50;
    int b = n >> 3, t = n & 7;
    int c0 = ci * 32, r0 = ri * 32;
    __shared__ float tile[32][33];
    int tid = threadIdx.x;
    int lc = tid >> 5, lr = tid & 31;         // 8 x 32
    #pragma unroll
    for (int it = 0; it < 4; ++it) {
        int cc = it * 8 + lc;
        tile[cc][lr] = x[((size_t)((b * 128 + c0 + cc) * 8 + t)) * 1600 + r0 + lr];
    }
    __syncthreads();
    #pragma unroll
    for (int it = 0; it < 4; ++it) {
        int rr = it * 8 + lc;
        h[((size_t)(n * 1600 + r0 + rr)) * 128 + c0 + lr] = tile[lr][rr];
    }
}

// ---- weight convert+transpose: W[K,N] fp32 -> Wt[N,K] bf16, 64x64 LDS tiles.
__global__ __launch_bounds__(256) void k_wt(const float* __restrict__ qkv_w,
                                            const float* __restrict__ proj_w,
                                            const float* __restrict__ fc1_w,
                                            const float* __restrict__ fc2_w,
                                            bf16* __restrict__ wt) {
    __shared__ float tile[64][65];
    int id = blockIdx.x;
    int l = id / 48, r = id % 48;
    const float* src; bf16* dst; int K_, N_, t;
    if (r < 12)      { src = qkv_w  + l * 128 * 384; dst = wt + l * WT_L + WT_QKV; K_ = 128; N_ = 384; t = r; }
    else if (r < 16) { src = proj_w + l * 128 * 128; dst = wt + l * WT_L + WT_PROJ; K_ = 128; N_ = 128; t = r - 12; }
    else if (r < 32) { src = fc1_w  + l * 128 * 512; dst = wt + l * WT_L + WT_FC1; K_ = 128; N_ = 512; t = r - 16; }
    else             { src = fc2_w  + l * 512 * 128; dst = wt + l * WT_L + WT_FC2; K_ = 512; N_ = 128; t = r - 32; }
    int KT = K_ >> 6;
    int k0 = (t % KT) * 64, n0 = (t / KT) * 64;
    int tid = threadIdx.x;
    for (int c = tid; c < 4096; c += 256) {
        int kk = c >> 6, nn = c & 63;
        tile[kk][nn] = src[(size_t)(k0 + kk) * N_ + n0 + nn];
    }
    __syncthreads();
    for (int c = tid; c < 4096; c += 256) {
        int nn = c >> 6, kk = c & 63;
        dst[(size_t)(n0 + nn) * K_ + k0 + kk] = __float2bfloat16(tile[kk][nn]);
    }
}

// ---- fused LayerNorm + MFMA GEMM (fp32 A): only layer-0 qkv.
template<typename OutT>
__global__ __launch_bounds__(256) void k_lngemm(const float* __restrict__ A,
                                                const bf16* __restrict__ Bt,
                                                const float* __restrict__ g,
                                                const float* __restrict__ be,
                                                const float* __restrict__ bias,
                                                OutT* __restrict__ D,
                                                int N) {
    constexpr int LDK = 40;
    __shared__ bf16 As[64 * LDK];
    __shared__ bf16 Bs[128 * LDK];
    __shared__ float sMean[64], sRstd[64], sG[128], sB[128];
    int tid = threadIdx.x;
    int m0 = blockIdx.y * 64, n0 = blockIdx.x * 128;
    {
        int row = tid >> 2, q4 = tid & 3;
        const float* p = A + (size_t)(m0 + row) * 128 + q4 * 32;
        float s = 0.f, q = 0.f;
        #pragma unroll
        for (int i = 0; i < 32; i += 4) {
            float4 f = *(const float4*)(p + i);
            s += f.x + f.y + f.z + f.w;
            q += f.x * f.x + f.y * f.y + f.z * f.z + f.w * f.w;
        }
        s += __shfl_xor(s, 1); q += __shfl_xor(q, 1);
        s += __shfl_xor(s, 2); q += __shfl_xor(q, 2);
        if (q4 == 0) {
            float mean = s * (1.0f / 128.0f);
            float var = q * (1.0f / 128.0f) - mean * mean;
            sMean[row] = mean;
            sRstd[row] = rsqrtf(var + 1e-5f);
        }
        if (tid < 128) { sG[tid] = g[tid]; sB[tid] = be[tid]; }
    }
    __syncthreads();
    int wave = tid >> 6, lane = tid & 63;
    int l15 = lane & 15, quad = lane >> 4;
    int wr = wave >> 1, wc = wave & 1;
    floatx4 acc[2][4];
    #pragma unroll
    for (int i = 0; i < 2; ++i)
        #pragma unroll
        for (int j = 0; j < 4; ++j)
            acc[i][j] = (floatx4){0.f, 0.f, 0.f, 0.f};

    for (int k0 = 0; k0 < 128; k0 += 32) {
        #pragma unroll
        for (int it = 0; it < 2; ++it) {
            int c = tid + it * 256;
            int row = c >> 3, kq = (c & 7) * 4;
            float4 f = *(const float4*)(A + (size_t)(m0 + row) * 128 + k0 + kq);
            float mean = sMean[row], rst = sRstd[row];
            float r0v = (f.x - mean) * rst * sG[k0 + kq]     + sB[k0 + kq];
            float r1v = (f.y - mean) * rst * sG[k0 + kq + 1] + sB[k0 + kq + 1];
            float r2v = (f.z - mean) * rst * sG[k0 + kq + 2] + sB[k0 + kq + 2];
            float r3v = (f.w - mean) * rst * sG[k0 + kq + 3] + sB[k0 + kq + 3];
            __hip_bfloat162 p0, p1;
            p0.x = __float2bfloat16(r0v); p0.y = __float2bfloat16(r1v);
            p1.x = __float2bfloat16(r2v); p1.y = __float2bfloat16(r3v);
            *(__hip_bfloat162*)&As[row * LDK + kq]     = p0;
            *(__hip_bfloat162*)&As[row * LDK + kq + 2] = p1;
        }
        #pragma unroll
        for (int c = tid; c < 512; c += 256) {
            int row = c >> 2, off = (c & 3) * 8;
            *(uint4*)&Bs[row * LDK + off] =
                *(const uint4*)&Bt[(size_t)(n0 + row) * 128 + k0 + off];
        }
        __syncthreads();
        short8 af[2], bfr[4];
        #pragma unroll
        for (int i = 0; i < 2; ++i)
            af[i] = *(const short8*)&As[(wr * 32 + i * 16 + l15) * LDK + quad * 8];
        #pragma unroll
        for (int j = 0; j < 4; ++j)
            bfr[j] = *(const short8*)&Bs[(wc * 64 + j * 16 + l15) * LDK + quad * 8];
        #pragma unroll
        for (int i = 0; i < 2; ++i)
            #pragma unroll
            for (int j = 0; j < 4; ++j)
                acc[i][j] = __builtin_amdgcn_mfma_f32_16x16x32_bf16(af[i], bfr[j], acc[i][j], 0, 0, 0);
        __syncthreads();
    }
    #pragma unroll
    for (int i = 0; i < 2; ++i) {
        #pragma unroll
        for (int j = 0; j < 4; ++j) {
            int nn = n0 + wc * 64 + j * 16 + l15;
            float bv = bias[nn];
            #pragma unroll
            for (int rg = 0; rg < 4; ++rg) {
                int m = m0 + wr * 32 + i * 16 + quad * 4 + rg;
                float v = acc[i][j][rg] + bv;
                if constexpr (sizeof(OutT) == 2)
                    D[(size_t)m * N + nn] = __float2bfloat16(v);
                else
                    D[(size_t)m * N + nn] = v;
            }
        }
    }
}

// ---- MFMA bf16 GEMM: D[M,N] = A[M,K] @ Bt[N,K]^T + bias (+R).
template<int BM, int BN, int WM, int WN, typename OutT>
__global__ __launch_bounds__(256) void k_gemm_mfma(const bf16* __restrict__ A,
                                                   const bf16* __restrict__ Bt,
                                                   const float* __restrict__ bias,
                                                   const float* __restrict__ R,
                                                   OutT* __restrict__ D,
                                                   int K, int N) {
    constexpr int LDK = 40;
    __shared__ bf16 As[BM * LDK];
    __shared__ bf16 Bs[BN * LDK];
    int tid = threadIdx.x;
    int wave = tid >> 6, lane = tid & 63;
    int l15 = lane & 15, quad = lane >> 4;
    constexpr int WCOLS = BN / WN;
    int wr = wave / WCOLS, wc = wave % WCOLS;
    int m0 = blockIdx.y * BM, n0 = blockIdx.x * BN;
    constexpr int MI = WM / 16, NJ = WN / 16;
    floatx4 acc[MI][NJ];
    #pragma unroll
    for (int i = 0; i < MI; ++i)
        #pragma unroll
        for (int j = 0; j < NJ; ++j)
            acc[i][j] = (floatx4){0.f, 0.f, 0.f, 0.f};

    for (int k0 = 0; k0 < K; k0 += 32) {
        #pragma unroll
        for (int c = tid; c < BM * 4; c += 256) {
            int row = c >> 2, off = (c & 3) * 8;
            *(uint4*)&As[row * LDK + off] =
                *(const uint4*)&A[(size_t)(m0 + row) * K + k0 + off];
        }
        #pragma unroll
        for (int c = tid; c < BN * 4; c += 256) {
            int row = c >> 2, off = (c & 3) * 8;
            *(uint4*)&Bs[row * LDK + off] =
                *(const uint4*)&Bt[(size_t)(n0 + row) * K + k0 + off];
        }
        __syncthreads();
        short8 af[MI], bfr[NJ];
        #pragma unroll
        for (int i = 0; i < MI; ++i)
            af[i] = *(const short8*)&As[(wr * WM + i * 16 + l15) * LDK + quad * 8];
        #pragma unroll
        for (int j = 0; j < NJ; ++j)
            bfr[j] = *(const short8*)&Bs[(wc * WN + j * 16 + l15) * LDK + quad * 8];
        #pragma unroll
        for (int i = 0; i < MI; ++i)
            #pragma unroll
            for (int j = 0; j < NJ; ++j)
                acc[i][j] = __builtin_amdgcn_mfma_f32_16x16x32_bf16(af[i], bfr[j], acc[i][j], 0, 0, 0);
        __syncthreads();
    }
    #pragma unroll
    for (int i = 0; i < MI; ++i) {
        #pragma unroll
        for (int j = 0; j < NJ; ++j) {
            int nn = n0 + wc * WN + j * 16 + l15;
            float bv = bias[nn];
            #pragma unroll
            for (int rg = 0; rg < 4; ++rg) {
                int m = m0 + wr * WM + i * 16 + quad * 4 + rg;
                float v = acc[i][j][rg] + bv;
                if (R) v += R[(size_t)m * N + nn];
                if constexpr (sizeof(OutT) == 2)
                    D[(size_t)m * N + nn] = __float2bfloat16(v);
                else
                    D[(size_t)m * N + nn] = v;
            }
        }
    }
}

// ---- GEMM (N=128) + residual + fused next-LayerNorm epilogue.
// v2: register-resident LN. Each lane holds rows quad*4+rg, cols wc*64+j*16+l15;
// row sums via shfl over l15 + 512B LDS cross-wave combine. No ot[] buffer:
// LDS 30.4 -> 14.3 KB => occupancy cap 8 blocks/CU (was 5).
__global__ __launch_bounds__(256) void k_gemm_ln(const bf16* __restrict__ A,
                                                 const bf16* __restrict__ Bt,
                                                 const float* __restrict__ bias,
                                                 const float* __restrict__ R,
                                                 const float* __restrict__ g,
                                                 const float* __restrict__ be,
                                                 float* __restrict__ Dres,
                                                 bf16* __restrict__ Aout,
                                                 int K) {
    constexpr int LDK = 40;
    __shared__ bf16 As[32 * LDK];
    __shared__ bf16 Bs[128 * LDK];
    __shared__ float pSum[2][32], pSq[2][32];
    __shared__ float sG[128], sB[128];
    int tid = threadIdx.x;
    int wave = tid >> 6, lane = tid & 63;
    int l15 = lane & 15, quad = lane >> 4;
    int wr = wave >> 1, wc = wave & 1;
    int m0 = blockIdx.x * 32;
    if (tid < 128) { sG[tid] = g[tid]; sB[tid] = be[tid]; }
    floatx4 acc[4];
    #pragma unroll
    for (int j = 0; j < 4; ++j) acc[j] = (floatx4){0.f, 0.f, 0.f, 0.f};

    for (int k0 = 0; k0 < K; k0 += 32) {
        if (tid < 128) {
            int row = tid >> 2, off = (tid & 3) * 8;
            *(uint4*)&As[row * LDK + off] =
                *(const uint4*)&A[(size_t)(m0 + row) * K + k0 + off];
        }
        #pragma unroll
        for (int c = tid; c < 512; c += 256) {
            int row = c >> 2, off = (c & 3) * 8;
            *(uint4*)&Bs[row * LDK + off] =
                *(const uint4*)&Bt[(size_t)row * K + k0 + off];
        }
        __syncthreads();
        short8 af = *(const short8*)&As[(wr * 16 + l15) * LDK + quad * 8];
        short8 bfr[4];
        #pragma unroll
        for (int j = 0; j < 4; ++j)
            bfr[j] = *(const short8*)&Bs[(wc * 64 + j * 16 + l15) * LDK + quad * 8];
        #pragma unroll
        for (int j = 0; j < 4; ++j)
            acc[j] = __builtin_amdgcn_mfma_f32_16x16x32_bf16(af, bfr[j], acc[j], 0, 0, 0);
        __syncthreads();
    }
    // epilogue: bias + residual in regs, row-stats via shfl + tiny LDS
    float v[4][4];                       // [j][rg]
    float s[4] = {0.f, 0.f, 0.f, 0.f};
    float q[4] = {0.f, 0.f, 0.f, 0.f};
    #pragma unroll
    for (int j = 0; j < 4; ++j) {
        int nn = wc * 64 + j * 16 + l15;
        float bv = bias[nn];
        #pragma unroll
        for (int rg = 0; rg < 4; ++rg) {
            int m = wr * 16 + quad * 4 + rg;
            float val = acc[j][rg] + bv + R[(size_t)(m0 + m) * 128 + nn];
            v[j][rg] = val;
            s[rg] += val; q[rg] += val * val;
        }
    }
    #pragma unroll
    for (int o = 8; o > 0; o >>= 1) {
        #pragma unroll
        for (int rg = 0; rg < 4; ++rg) {
            s[rg] += __shfl_xor(s[rg], o);
            q[rg] += __shfl_xor(q[rg], o);
        }
    }
    if (l15 == 0) {
        #pragma unroll
        for (int rg = 0; rg < 4; ++rg) {
            int row = wr * 16 + quad * 4 + rg;
            pSum[wc][row] = s[rg];
            pSq[wc][row]  = q[rg];
        }
    }
    __syncthreads();
    #pragma unroll
    for (int rg = 0; rg < 4; ++rg) {
        int row = wr * 16 + quad * 4 + rg;
        float tot = pSum[0][row] + pSum[1][row];
        float tq  = pSq[0][row]  + pSq[1][row];
        float mean = tot * (1.0f / 128.0f);
        float var = tq * (1.0f / 128.0f) - mean * mean;
        float rst = rsqrtf(var + 1e-5f);
        size_t rb = (size_t)(m0 + row) * 128;
        #pragma unroll
        for (int j = 0; j < 4; ++j) {
            int nn = wc * 64 + j * 16 + l15;
            Dres[rb + nn] = v[j][rg];
            Aout[rb + nn] = __float2bfloat16((v[j][rg] - mean) * rst * sG[nn] + sB[nn]);
        }
    }
}

// ---- GEMM (N=128) + residual + FINAL LayerNorm + transposed store to (b,c,t,y,x).
__global__ __launch_bounds__(256) void k_gemm_lnout(const bf16* __restrict__ A,
                                                    const bf16* __restrict__ Bt,
                                                    const float* __restrict__ bias,
                                                    const float* __restrict__ R,
                                                    const float* __restrict__ g,
                                                    const float* __restrict__ be,
                                                    float* __restrict__ out,
                                                    int K) {
    constexpr int LDK = 40;
    __shared__ bf16 As[32 * LDK];
    __shared__ bf16 Bs[128 * LDK];
    __shared__ float ot[32][133];    // pad 133: conflict-free transposed reads
    __shared__ float sG[128], sB[128];
    int tid = threadIdx.x;
    int wave = tid >> 6, lane = tid & 63;
    int l15 = lane & 15, quad = lane >> 4;
    int wr = wave >> 1, wc = wave & 1;
    int m0 = blockIdx.x * 32;
    if (tid < 128) { sG[tid] = g[tid]; sB[tid] = be[tid]; }
    floatx4 acc[4];
    #pragma unroll
    for (int j = 0; j < 4; ++j) acc[j] = (floatx4){0.f, 0.f, 0.f, 0.f};

    for (int k0 = 0; k0 < K; k0 += 32) {
        if (tid < 128) {
            int row = tid >> 2, off = (tid & 3) * 8;
            *(uint4*)&As[row * LDK + off] =
                *(const uint4*)&A[(size_t)(m0 + row) * K + k0 + off];
        }
        #pragma unroll
        for (int c = tid; c < 512; c += 256) {
            int row = c >> 2, off = (c & 3) * 8;
            *(uint4*)&Bs[row * LDK + off] =
                *(const uint4*)&Bt[(size_t)row * K + k0 + off];
        }
        __syncthreads();
        short8 af = *(const short8*)&As[(wr * 16 + l15) * LDK + quad * 8];
        short8 bfr[4];
        #pragma unroll
        for (int j = 0; j < 4; ++j)
            bfr[j] = *(const short8*)&Bs[(wc * 64 + j * 16 + l15) * LDK + quad * 8];
        #pragma unroll
        for (int j = 0; j < 4; ++j)
            acc[j] = __builtin_amdgcn_mfma_f32_16x16x32_bf16(af, bfr[j], acc[j], 0, 0, 0);
        __syncthreads();
    }
    #pragma unroll
    for (int j = 0; j < 4; ++j) {
        int nn = wc * 64 + j * 16 + l15;
        float bv = bias[nn];
        #pragma unroll
        for (int rg = 0; rg < 4; ++rg) {
            int m = wr * 16 + quad * 4 + rg;
            ot[m][nn] = acc[j][rg] + bv + R[(size_t)(m0 + m) * 128 + nn];
        }
    }
    __syncthreads();
    int row = tid >> 3, sub = tid & 7;
    float vv[16];
    float s = 0.f, q = 0.f;
    #pragma unroll
    for (int i = 0; i < 16; ++i) {
        float v = ot[row][sub * 16 + i];
        vv[i] = v; s += v; q += v * v;
    }
    #pragma unroll
    for (int o = 4; o > 0; o >>= 1) { s += __shfl_xor(s, o); q += __shfl_xor(q, o); }
    float mean = s * (1.0f / 128.0f);
    float var = q * (1.0f / 128.0f) - mean * mean;
    float rst = rsqrtf(var + 1e-5f);
    #pragma unroll
    for (int i = 0; i < 16; ++i) {
        int ch = sub * 16 + i;
        ot[row][ch] = (vv[i] - mean) * rst * sG[ch] + sB[ch];
    }
    __syncthreads();
    int n = m0 / 1600, rem0 = m0 % 1600;
    int b = n >> 3, t = n & 7;
    #pragma unroll
    for (int it = 0; it < 16; ++it) {
        int idx = it * 256 + tid;
        int ch = idx >> 5, tk = idx & 31;
        out[((size_t)((b * 128 + ch) * 8 + t)) * 1600 + rem0 + tk] = ot[tk][ch];
    }
}

// ---- row-tiled 7x7 neighborhood attention; f16 K + fdot2 logits.
// v4: LGS 68->60 (LDS 32.1KB -> 5 blocks/CU). Otherwise v3 structure:
// lg [40][LGS] f32, j=ky*8+jx, slot7=-1e30 self-masking pad; PV per (xq,chan-quad)
// with b64 V reads + 2x b128 p reads per ky; wave-parallel softmax (4 lanes/row);
// K/q bf16->f16 via cvt_pkrtz. XCD-locality blockIdx swizzle.
__global__ __launch_bounds__(256) void k_attn(const bf16* __restrict__ qkv,
                                              const float* __restrict__ rpb,
                                              bf16* __restrict__ out) {
    int raw = blockIdx.x;                       // grid 2560
    int blk = (raw & 7) * 320 + (raw >> 3);     // chunk per XCD
    int head = blk & 3;
    int ny = blk >> 2;
    int n = ny / 40, y = ny % 40;
    int sy = min(max(y - 3, 0), HH - 7);
    __shared__ __align__(16) short KVs[7 * KVP];   // K (f16, stride 40) then V (bf16, stride 32)
    __shared__ __align__(16) float lg[40][LGS];
    int tid = threadIdx.x;
    // phase 1: K window, bf16 -> f16 (packed cvt)
    for (int i2 = tid; i2 < 1120; i2 += 256) {
        int d8 = i2 & 3, kx = (i2 >> 2) % 40, ky = i2 / 160;
        size_t base = ((size_t)(n * 1600 + (sy + ky) * 40 + kx)) * 384 + 128 + head * 32 + d8 * 8;
        union { uint4 u; __hip_bfloat162 b[4]; } U;
        U.u = *(const uint4*)(qkv + base);
        union { short8 s; h2 h[4]; } W;
        #pragma unroll
        for (int c = 0; c < 4; ++c) {
            float2 f = __bfloat1622float2(U.b[c]);
            W.h[c] = cvt2h(f.x, f.y);
        }
        *(short8*)&KVs[ky * KVP + kx * 40 + d8 * 8] = W.s;
    }
    __syncthreads();
    // logits: thread per (xq, ky); q loaded from global, converted in regs
    for (int p2 = tid; p2 < 280; p2 += 256) {
        int xq = p2 / 7, ky = p2 - (p2 / 7) * 7;
        int sx = min(max(xq - 3, 0), WW - 7);
        const bf16* qg = qkv + ((size_t)(n * 1600 + y * 40 + xq)) * 384 + head * 32;
        union { uint4 u; __hip_bfloat162 b[4]; } U[4];
        #pragma unroll
        for (int u = 0; u < 4; ++u) U[u].u = *(const uint4*)(qg + u * 8);
        h2 qh[16];
        #pragma unroll
        for (int c = 0; c < 16; ++c) {
            float2 f = __bfloat1622float2(U[c >> 2].b[c & 3]);
            qh[c] = cvt2h(f.x, f.y);
        }
        const float* rb = rpb + head * 169 + (sy + ky - y + 6) * 13 + (sx - xq + 6);
        int kbase = ky * KVP + sx * 40;
        #pragma unroll
        for (int jx = 0; jx < 7; ++jx) {
            const h2* kp = (const h2*)&KVs[kbase + jx * 40];
            float dot = 0.f;
            #pragma unroll
            for (int c = 0; c < 16; ++c)
                dot = __builtin_amdgcn_fdot2(qh[c], kp[c], dot, false);
            lg[xq][ky * 8 + jx] = dot * 0.1767766952966369f + rb[jx];
        }
        lg[xq][ky * 8 + 7] = -1e30f;   // pad slot: self-masking in softmax & PV
    }
    __syncthreads();
    // phase 2: V window (raw bf16 bits, stride 32), softmax concurrently
    for (int i2 = tid; i2 < 1120; i2 += 256) {
        int d8 = i2 & 3, kx = (i2 >> 2) % 40, ky = i2 / 160;
        size_t base = ((size_t)(n * 1600 + (sy + ky) * 40 + kx)) * 384 + 256 + head * 32 + d8 * 8;
        *(uint4*)&KVs[ky * VP + kx * 32 + d8 * 8] = *(const uint4*)(qkv + base);
    }
    // wave-parallel softmax over 56 padded slots: 4 lanes/row
    if (tid < 160) {
        int row = tid >> 2, q = tid & 3;
        int nb = (q == 3) ? 2 : 4;        // q<3: slots [q*16,+16); q3: [48,56)
        const float4* lp = (const float4*)&lg[row][q * 16];
        float4 f[4];
        #pragma unroll
        for (int i = 0; i < 4; ++i)
            if (i < nb) f[i] = lp[i];
        float m = -1e30f;
        #pragma unroll
        for (int i = 0; i < 4; ++i)
            if (i < nb) m = fmaxf(m, fmaxf(fmaxf(f[i].x, f[i].y), fmaxf(f[i].z, f[i].w)));
        m = fmaxf(m, __shfl_xor(m, 1));
        m = fmaxf(m, __shfl_xor(m, 2));
        float s = 0.f;
        #pragma unroll
        for (int i = 0; i < 4; ++i)
            if (i < nb) {
                f[i].x = expf(f[i].x - m); f[i].y = expf(f[i].y - m);
                f[i].z = expf(f[i].z - m); f[i].w = expf(f[i].w - m);
                s += f[i].x + f[i].y + f[i].z + f[i].w;
            }
        s += __shfl_xor(s, 1);
        s += __shfl_xor(s, 2);
        float inv = 1.0f / s;
        float4* sp = (float4*)&lg[row][q * 16];
        #pragma unroll
        for (int i = 0; i < 4; ++i)
            if (i < nb) {
                f[i].x *= inv; f[i].y *= inv; f[i].z *= inv; f[i].w *= inv;
                sp[i] = f[i];
            }
    }
    __syncthreads();
    // PV: thread per (xq, chan-quad); per jx one b64 V read; p via 2 b128/ky
    for (int o = tid; o < 320; o += 256) {
        int xq = o >> 3, cq = o & 7;
        int sx = min(max(xq - 3, 0), WW - 7);
        float a0 = 0.f, a1 = 0.f, a2 = 0.f, a3 = 0.f;
        #pragma unroll
        for (int ky = 0; ky < 7; ++ky) {
            float4 pa = *(const float4*)&lg[xq][ky * 8];
            float4 pb = *(const float4*)&lg[xq][ky * 8 + 4];
            float ps[8] = {pa.x, pa.y, pa.z, pa.w, pb.x, pb.y, pb.z, pb.w};
            int vb = ky * VP + sx * 32 + cq * 4;
            #pragma unroll
            for (int jx = 0; jx < 7; ++jx) {
                float p = ps[jx];
                uint2 vv = *(const uint2*)&KVs[vb + jx * 32];
                float2 v0 = __bfloat1622float2(*(const __hip_bfloat162*)&vv.x);
                float2 v1 = __bfloat1622float2(*(const __hip_bfloat162*)&vv.y);
                a0 += p * v0.x; a1 += p * v0.y;
                a2 += p * v1.x; a3 += p * v1.y;
            }
        }
        __hip_bfloat162 o01, o23;
        o01.x = __float2bfloat16(a0); o01.y = __float2bfloat16(a1);
        o23.x = __float2bfloat16(a2); o23.y = __float2bfloat16(a3);
        bf16* op = out + ((size_t)(n * 1600 + y * 40 + xq)) * 128 + head * 32 + cq * 4;
        *(__hip_bfloat162*)op = o01;
        *(__hip_bfloat162*)(op + 2) = o23;
    }
}

// ---- depthwise 3x3x3 conv + bias + exact GELU; fp32 in, bf16 out.
// v3: 512 thr x 1 ch (high occupancy) + branch-free loads (validity folded into
// zeroed weights, clamped uniform row offsets in SGPRs) + one-iteration prefetch
// + compile-time x-half specialization with full unroll.
// XCD-locality swizzle: same-XCD blocks get consecutive (n,y) chunks (shared rows).
template<int X0>
__device__ __forceinline__ void dw_body(const float* __restrict__ inp,
                                        const int* roff, const float* wr,
                                        float bs, int m, size_t outbase,
                                        bf16* __restrict__ outp) {
    float c0[9], c1[9], c2[9];
    #pragma unroll
    for (int p = 0; p < 9; ++p) {
        c0[p] = (X0 > 0) ? inp[roff[p] + (X0 - 1) * 512 + m] : 0.f;
        c1[p] = inp[roff[p] + X0 * 512 + m];
        c2[p] = inp[roff[p] + (X0 + 1) * 512 + m];
    }
    #pragma unroll
    for (int xi = 0; xi < 20; ++xi) {
        constexpr int XN_BASE = X0 + 2;
        int x = X0 + xi;
        float cn[9];
        if (XN_BASE + xi < 40) {
            #pragma unroll
            for (int p = 0; p < 9; ++p)
                cn[p] = inp[roff[p] + (XN_BASE + xi) * 512 + m];
        } else {
            #pragma unroll
            for (int p = 0; p < 9; ++p) cn[p] = 0.f;
        }
        float acc = bs;
        #pragma unroll
        for (int p = 0; p < 9; ++p)
            acc += wr[p * 3 + 0] * c0[p] + wr[p * 3 + 1] * c1[p] + wr[p * 3 + 2] * c2[p];
        float g = 0.5f * acc * (1.0f + erff(acc * 0.70710678118654752f));
        outp[outbase + (size_t)x * 512] = __float2bfloat16(g);
        #pragma unroll
        for (int p = 0; p < 9; ++p) { c0[p] = c1[p]; c1[p] = c2[p]; c2[p] = cn[p]; }
    }
}

__global__ __launch_bounds__(512, 4) void k_dwconv(const float* __restrict__ inp,
                                                   const float* __restrict__ w,
                                                   const float* __restrict__ bias,
                                                   bf16* __restrict__ outp) {
    int raw = blockIdx.x;                       // grid 1280
    int blk = (raw & 7) * 160 + (raw >> 3);     // chunk per XCD
    int xh = blk & 1;
    int ny = blk >> 1;
    int n = ny / 40, y = ny - n * 40;
    int b = n >> 3, t = n & 7;
    int m = threadIdx.x;
    float wr[27];
    int roff[9];                                // wave-uniform -> SGPRs
    #pragma unroll
    for (int dt = 0; dt < 3; ++dt) {
        #pragma unroll
        for (int dy = 0; dy < 3; ++dy) {
            int p = dt * 3 + dy;
            int tt = t + dt - 1, yy = y + dy - 1;
            bool v = (tt >= 0 && tt < 8 && yy >= 0 && yy < 40);
            int tc = min(max(tt, 0), 7), yc = min(max(yy, 0), 39);
            roff[p] = ((b * 8 + tc) * 1600 + yc * 40) * 512;
            #pragma unroll
            for (int q = 0; q < 3; ++q)
                wr[p * 3 + q] = v ? w[(p * 3 + q) * 512 + m] : 0.f;
        }
    }
    float bs = bias[m];
    size_t outbase = ((size_t)(n * 1600 + y * 40)) * 512 + m;
    if (xh == 0)
        dw_body<0>(inp, roff, wr, bs, m, outbase, outp);
    else
        dw_body<20>(inp, roff, wr, bs, m, outbase, outp);
}

extern "C" void kernel_launch(void* const* d_in, const int* in_sizes, int n_in,
                              void* d_out, int out_size, void* d_ws, size_t ws_size,
                              hipStream_t stream) {
    const float* x      = (const float*)d_in[0];
    const float* ln1_g  = (const float*)d_in[1];
    const float* ln1_b  = (const float*)d_in[2];
    const float* qkv_w  = (const float*)d_in[3];
    const float* qkv_b  = (const float*)d_in[4];
    const float* rpb    = (const float*)d_in[5];
    const float* proj_w = (const float*)d_in[6];
    const float* proj_b = (const float*)d_in[7];
    const float* ln2_g  = (const float*)d_in[8];
    const float* ln2_b  = (const float*)d_in[9];
    const float* fc1_w  = (const float*)d_in[10];
    const float* fc1_b  = (const float*)d_in[11];
    const float* dw_w   = (const float*)d_in[12];
    const float* dw_b   = (const float*)d_in[13];
    const float* fc2_w  = (const float*)d_in[14];
    const float* fc2_b  = (const float*)d_in[15];
    const float* out_g  = (const float*)d_in[16];
    const float* out_b  = (const float*)d_in[17];
    float* out = (float*)d_out;

    // workspace: h f32 | f1 f32 | qkvb bf16 | f2b bf16 | abufA bf16 | abufL bf16 | wt
    float* h     = (float*)d_ws;
    float* f1    = h + (size_t)NTOK * 128;
    bf16* qkvb   = (bf16*)(f1 + (size_t)NTOK * 512);
    bf16* f2b    = qkvb + (size_t)NTOK * 384;
    bf16* abufA  = f2b  + (size_t)NTOK * 512;
    bf16* abufL  = abufA + (size_t)NTOK * 128;
    bf16* wt     = abufL + (size_t)NTOK * 128;

    k_wt<<<96, 256, 0, stream>>>(qkv_w, proj_w, fc1_w, fc2_w, wt);
    k_transpose_in<<<NIMG * 200, 256, 0, stream>>>(x, h);
    for (int l = 0; l < 2; ++l) {
        const bf16* wtl = wt + (size_t)l * WT_L;
        if (l == 0) {
            k_lngemm<bf16><<<dim3(3, 400), 256, 0, stream>>>(
                h, wtl + WT_QKV, ln1_g, ln1_b, qkv_b, qkvb, 384);
        } else {
            k_gemm_mfma<64, 128, 32, 64, bf16><<<dim3(3, 400), 256, 0, stream>>>(
                abufL, wtl + WT_QKV, qkv_b + 384, nullptr, qkvb, 128, 384);
        }
        k_attn<<<NIMG * HH * NHEAD, 256, 0, stream>>>(qkvb, rpb + l * 4 * 169, abufA);
        // proj + residual + fused LN2 epilogue -> abufL
        k_gemm_ln<<<800, 256, 0, stream>>>(
            abufA, wtl + WT_PROJ, proj_b + l * 128, h,
            ln2_g + l * 128, ln2_b + l * 128, h, abufL, 128);
        // fc1: plain bf16-A GEMM
        k_gemm_mfma<64, 128, 32, 64, float><<<dim3(4, 400), 256, 0, stream>>>(
            abufL, wtl + WT_FC1, fc1_b + l * 512, nullptr, f1, 128, 512);
        k_dwconv<<<NIMG * HH * 2, 512, 0, stream>>>(f1, dw_w + l * 27 * 512, dw_b + l * 512, f2b);
        if (l == 0) {
            // fc2 + residual + fused LN1(layer 1) epilogue -> abufL
            k_gemm_ln<<<800, 256, 0, stream>>>(
                f2b, wtl + WT_FC2, fc2_b, h,
                ln1_g + 128, ln1_b + 128, h, abufL, 512);
        } else {
            // fc2 + residual + FINAL LN + transposed store
            k_gemm_lnout<<<800, 256, 0, stream>>>(
                f2b, wtl + WT_FC2, fc2_b + 128, h, out_g, out_b, out, 512);
        }
    }
}

// Round 7
// 338.017 us; speedup vs baseline: 1.2948x; 1.0802x over previous
//
#include <hip/hip_runtime.h>
#include <hip/hip_bf16.h>
#include <math.h>

typedef __hip_bfloat16 bf16;
typedef __attribute__((ext_vector_type(8))) short short8;
typedef __attribute__((ext_vector_type(4))) float floatx4;
typedef __attribute__((ext_vector_type(2))) float f32x2;
typedef _Float16 h2 __attribute__((ext_vector_type(2)));
typedef __fp16 hraw2 __attribute__((ext_vector_type(2)));

// packed f32 pair -> f16 pair (cvt_pkrtz), bitcast to _Float16 vector
static __device__ __forceinline__ h2 cvt2h(float a, float b) {
    union { hraw2 r; h2 h; } u;
    u.r = __builtin_amdgcn_cvt_pkrtz(a, b);
    return u.h;
}

#define HH 40
#define WW 40
#define CC 128
#define TT 8
#define NIMG 16           // B*T
#define NTOK 25600        // NIMG*HH*WW
#define MDIM 512
#define NHEAD 4
#define KVP 1608          // K LDS plane stride in shorts (40 sh/kx: b128-friendly)
#define VP  1280          // V LDS plane stride in shorts (32 sh/kx: PV conflict-free)
#define LGS 60            // lg row stride in floats; 56 used. total LDS 32.1KB -> 5 blk/CU

// weight-transpose buffer offsets (bf16 elems), per layer
#define WT_QKV 0
#define WT_PROJ 49152
#define WT_FC1  65536
#define WT_FC2  131072
#define WT_L    196608

// ---- merged prep: blocks [0,96) = weight convert+transpose; [96,3296) = input transpose.
__global__ __launch_bounds__(256) void k_prep(const float* __restrict__ x,
                                              const float* __restrict__ qkv_w,
                                              const float* __restrict__ proj_w,
                                              const float* __restrict__ fc1_w,
                                              const float* __restrict__ fc2_w,
                                              float* __restrict__ h,
                                              bf16* __restrict__ wt) {
    __shared__ float tileU[64 * 65];
    int tid = threadIdx.x;
    if (blockIdx.x < 96) {
        // weight convert+transpose: W[K,N] fp32 -> Wt[N,K] bf16, 64x64 LDS tiles.
        int id = blockIdx.x;
        int l = id / 48, r = id % 48;
        const float* src; bf16* dst; int K_, N_, t;
        if (r < 12)      { src = qkv_w  + l * 128 * 384; dst = wt + l * WT_L + WT_QKV; K_ = 128; N_ = 384; t = r; }
        else if (r < 16) { src = proj_w + l * 128 * 128; dst = wt + l * WT_L + WT_PROJ; K_ = 128; N_ = 128; t = r - 12; }
        else if (r < 32) { src = fc1_w  + l * 128 * 512; dst = wt + l * WT_L + WT_FC1; K_ = 128; N_ = 512; t = r - 16; }
        else             { src = fc2_w  + l * 512 * 128; dst = wt + l * WT_L + WT_FC2; K_ = 512; N_ = 128; t = r - 32; }
        int KT = K_ >> 6;
        int k0 = (t % KT) * 64, n0 = (t / KT) * 64;
        for (int c = tid; c < 4096; c += 256) {
            int kk = c >> 6, nn = c & 63;
            tileU[kk * 65 + nn] = src[(size_t)(k0 + kk) * N_ + n0 + nn];
        }
        __syncthreads();
        for (int c = tid; c < 4096; c += 256) {
            int nn = c >> 6, kk = c & 63;
            dst[(size_t)(n0 + nn) * K_ + k0 + kk] = __float2bfloat16(tileU[kk * 65 + nn]);
        }
    } else {
        // input transpose: x (b,c,t,y,x) -> h (n,y,x,c), both coalesced.
        int blk = blockIdx.x - 96;
        int n = blk / 200; int r = blk % 200; int ci = r / 50, ri = r % 50;
        int b = n >> 3, t = n & 7;
        int c0 = ci * 32, r0 = ri * 32;
        int lc = tid >> 5, lr = tid & 31;         // 8 x 32
        #pragma unroll
        for (int it = 0; it < 4; ++it) {
            int cc = it * 8 + lc;
            tileU[cc * 33 + lr] = x[((size_t)((b * 128 + c0 + cc) * 8 + t)) * 1600 + r0 + lr];
        }
        __syncthreads();
        #pragma unroll
        for (int it = 0; it < 4; ++it) {
            int rr = it * 8 + lc;
            h[((size_t)(n * 1600 + r0 + rr)) * 128 + c0 + lr] = tileU[lr * 33 + rr];
        }
    }
}

// ---- fused LayerNorm + MFMA GEMM (fp32 A): only layer-0 qkv.
template<typename OutT>
__global__ __launch_bounds__(256) void k_lngemm(const float* __restrict__ A,
                                                const bf16* __restrict__ Bt,
                                                const float* __restrict__ g,
                                                const float* __restrict__ be,
                                                const float* __restrict__ bias,
                                                OutT* __restrict__ D,
                                                int N) {
    constexpr int LDK = 40;
    __shared__ bf16 As[64 * LDK];
    __shared__ bf16 Bs[128 * LDK];
    __shared__ float sMean[64], sRstd[64], sG[128], sB[128];
    int tid = threadIdx.x;
    int m0 = blockIdx.y * 64, n0 = blockIdx.x * 128;
    {
        int row = tid >> 2, q4 = tid & 3;
        const float* p = A + (size_t)(m0 + row) * 128 + q4 * 32;
        float s = 0.f, q = 0.f;
        #pragma unroll
        for (int i = 0; i < 32; i += 4) {
            float4 f = *(const float4*)(p + i);
            s += f.x + f.y + f.z + f.w;
            q += f.x * f.x + f.y * f.y + f.z * f.z + f.w * f.w;
        }
        s += __shfl_xor(s, 1); q += __shfl_xor(q, 1);
        s += __shfl_xor(s, 2); q += __shfl_xor(q, 2);
        if (q4 == 0) {
            float mean = s * (1.0f / 128.0f);
            float var = q * (1.0f / 128.0f) - mean * mean;
            sMean[row] = mean;
            sRstd[row] = rsqrtf(var + 1e-5f);
        }
        if (tid < 128) { sG[tid] = g[tid]; sB[tid] = be[tid]; }
    }
    __syncthreads();
    int wave = tid >> 6, lane = tid & 63;
    int l15 = lane & 15, quad = lane >> 4;
    int wr = wave >> 1, wc = wave & 1;
    floatx4 acc[2][4];
    #pragma unroll
    for (int i = 0; i < 2; ++i)
        #pragma unroll
        for (int j = 0; j < 4; ++j)
            acc[i][j] = (floatx4){0.f, 0.f, 0.f, 0.f};

    for (int k0 = 0; k0 < 128; k0 += 32) {
        #pragma unroll
        for (int it = 0; it < 2; ++it) {
            int c = tid + it * 256;
            int row = c >> 3, kq = (c & 7) * 4;
            float4 f = *(const float4*)(A + (size_t)(m0 + row) * 128 + k0 + kq);
            float mean = sMean[row], rst = sRstd[row];
            float r0v = (f.x - mean) * rst * sG[k0 + kq]     + sB[k0 + kq];
            float r1v = (f.y - mean) * rst * sG[k0 + kq + 1] + sB[k0 + kq + 1];
            float r2v = (f.z - mean) * rst * sG[k0 + kq + 2] + sB[k0 + kq + 2];
            float r3v = (f.w - mean) * rst * sG[k0 + kq + 3] + sB[k0 + kq + 3];
            __hip_bfloat162 p0, p1;
            p0.x = __float2bfloat16(r0v); p0.y = __float2bfloat16(r1v);
            p1.x = __float2bfloat16(r2v); p1.y = __float2bfloat16(r3v);
            *(__hip_bfloat162*)&As[row * LDK + kq]     = p0;
            *(__hip_bfloat162*)&As[row * LDK + kq + 2] = p1;
        }
        #pragma unroll
        for (int c = tid; c < 512; c += 256) {
            int row = c >> 2, off = (c & 3) * 8;
            *(uint4*)&Bs[row * LDK + off] =
                *(const uint4*)&Bt[(size_t)(n0 + row) * 128 + k0 + off];
        }
        __syncthreads();
        short8 af[2], bfr[4];
        #pragma unroll
        for (int i = 0; i < 2; ++i)
            af[i] = *(const short8*)&As[(wr * 32 + i * 16 + l15) * LDK + quad * 8];
        #pragma unroll
        for (int j = 0; j < 4; ++j)
            bfr[j] = *(const short8*)&Bs[(wc * 64 + j * 16 + l15) * LDK + quad * 8];
        #pragma unroll
        for (int i = 0; i < 2; ++i)
            #pragma unroll
            for (int j = 0; j < 4; ++j)
                acc[i][j] = __builtin_amdgcn_mfma_f32_16x16x32_bf16(af[i], bfr[j], acc[i][j], 0, 0, 0);
        __syncthreads();
    }
    #pragma unroll
    for (int i = 0; i < 2; ++i) {
        #pragma unroll
        for (int j = 0; j < 4; ++j) {
            int nn = n0 + wc * 64 + j * 16 + l15;
            float bv = bias[nn];
            #pragma unroll
            for (int rg = 0; rg < 4; ++rg) {
                int m = m0 + wr * 32 + i * 16 + quad * 4 + rg;
                float v = acc[i][j][rg] + bv;
                if constexpr (sizeof(OutT) == 2)
                    D[(size_t)m * N + nn] = __float2bfloat16(v);
                else
                    D[(size_t)m * N + nn] = v;
            }
        }
    }
}

// ---- MFMA bf16 GEMM: D[M,N] = A[M,K] @ Bt[N,K]^T + bias (+R).
template<int BM, int BN, int WM, int WN, typename OutT>
__global__ __launch_bounds__(256) void k_gemm_mfma(const bf16* __restrict__ A,
                                                   const bf16* __restrict__ Bt,
                                                   const float* __restrict__ bias,
                                                   const float* __restrict__ R,
                                                   OutT* __restrict__ D,
                                                   int K, int N) {
    constexpr int LDK = 40;
    __shared__ bf16 As[BM * LDK];
    __shared__ bf16 Bs[BN * LDK];
    int tid = threadIdx.x;
    int wave = tid >> 6, lane = tid & 63;
    int l15 = lane & 15, quad = lane >> 4;
    constexpr int WCOLS = BN / WN;
    int wr = wave / WCOLS, wc = wave % WCOLS;
    int m0 = blockIdx.y * BM, n0 = blockIdx.x * BN;
    constexpr int MI = WM / 16, NJ = WN / 16;
    floatx4 acc[MI][NJ];
    #pragma unroll
    for (int i = 0; i < MI; ++i)
        #pragma unroll
        for (int j = 0; j < NJ; ++j)
            acc[i][j] = (floatx4){0.f, 0.f, 0.f, 0.f};

    for (int k0 = 0; k0 < K; k0 += 32) {
        #pragma unroll
        for (int c = tid; c < BM * 4; c += 256) {
            int row = c >> 2, off = (c & 3) * 8;
            *(uint4*)&As[row * LDK + off] =
                *(const uint4*)&A[(size_t)(m0 + row) * K + k0 + off];
        }
        #pragma unroll
        for (int c = tid; c < BN * 4; c += 256) {
            int row = c >> 2, off = (c & 3) * 8;
            *(uint4*)&Bs[row * LDK + off] =
                *(const uint4*)&Bt[(size_t)(n0 + row) * K + k0 + off];
        }
        __syncthreads();
        short8 af[MI], bfr[NJ];
        #pragma unroll
        for (int i = 0; i < MI; ++i)
            af[i] = *(const short8*)&As[(wr * WM + i * 16 + l15) * LDK + quad * 8];
        #pragma unroll
        for (int j = 0; j < NJ; ++j)
            bfr[j] = *(const short8*)&Bs[(wc * WN + j * 16 + l15) * LDK + quad * 8];
        #pragma unroll
        for (int i = 0; i < MI; ++i)
            #pragma unroll
            for (int j = 0; j < NJ; ++j)
                acc[i][j] = __builtin_amdgcn_mfma_f32_16x16x32_bf16(af[i], bfr[j], acc[i][j], 0, 0, 0);
        __syncthreads();
    }
    #pragma unroll
    for (int i = 0; i < MI; ++i) {
        #pragma unroll
        for (int j = 0; j < NJ; ++j) {
            int nn = n0 + wc * WN + j * 16 + l15;
            float bv = bias[nn];
            #pragma unroll
            for (int rg = 0; rg < 4; ++rg) {
                int m = m0 + wr * WM + i * 16 + quad * 4 + rg;
                float v = acc[i][j][rg] + bv;
                if (R) v += R[(size_t)m * N + nn];
                if constexpr (sizeof(OutT) == 2)
                    D[(size_t)m * N + nn] = __float2bfloat16(v);
                else
                    D[(size_t)m * N + nn] = v;
            }
        }
    }
}

// ---- GEMM (N=128) + residual + fused next-LayerNorm epilogue.
// v2: register-resident LN (shfl row sums + 512B LDS cross-wave combine).
__global__ __launch_bounds__(256) void k_gemm_ln(const bf16* __restrict__ A,
                                                 const bf16* __restrict__ Bt,
                                                 const float* __restrict__ bias,
                                                 const float* __restrict__ R,
                                                 const float* __restrict__ g,
                                                 const float* __restrict__ be,
                                                 float* __restrict__ Dres,
                                                 bf16* __restrict__ Aout,
                                                 int K) {
    constexpr int LDK = 40;
    __shared__ bf16 As[32 * LDK];
    __shared__ bf16 Bs[128 * LDK];
    __shared__ float pSum[2][32], pSq[2][32];
    __shared__ float sG[128], sB[128];
    int tid = threadIdx.x;
    int wave = tid >> 6, lane = tid & 63;
    int l15 = lane & 15, quad = lane >> 4;
    int wr = wave >> 1, wc = wave & 1;
    int m0 = blockIdx.x * 32;
    if (tid < 128) { sG[tid] = g[tid]; sB[tid] = be[tid]; }
    floatx4 acc[4];
    #pragma unroll
    for (int j = 0; j < 4; ++j) acc[j] = (floatx4){0.f, 0.f, 0.f, 0.f};

    for (int k0 = 0; k0 < K; k0 += 32) {
        if (tid < 128) {
            int row = tid >> 2, off = (tid & 3) * 8;
            *(uint4*)&As[row * LDK + off] =
                *(const uint4*)&A[(size_t)(m0 + row) * K + k0 + off];
        }
        #pragma unroll
        for (int c = tid; c < 512; c += 256) {
            int row = c >> 2, off = (c & 3) * 8;
            *(uint4*)&Bs[row * LDK + off] =
                *(const uint4*)&Bt[(size_t)row * K + k0 + off];
        }
        __syncthreads();
        short8 af = *(const short8*)&As[(wr * 16 + l15) * LDK + quad * 8];
        short8 bfr[4];
        #pragma unroll
        for (int j = 0; j < 4; ++j)
            bfr[j] = *(const short8*)&Bs[(wc * 64 + j * 16 + l15) * LDK + quad * 8];
        #pragma unroll
        for (int j = 0; j < 4; ++j)
            acc[j] = __builtin_amdgcn_mfma_f32_16x16x32_bf16(af, bfr[j], acc[j], 0, 0, 0);
        __syncthreads();
    }
    // epilogue: bias + residual in regs, row-stats via shfl + tiny LDS
    float v[4][4];                       // [j][rg]
    float s[4] = {0.f, 0.f, 0.f, 0.f};
    float q[4] = {0.f, 0.f, 0.f, 0.f};
    #pragma unroll
    for (int j = 0; j < 4; ++j) {
        int nn = wc * 64 + j * 16 + l15;
        float bv = bias[nn];
        #pragma unroll
        for (int rg = 0; rg < 4; ++rg) {
            int m = wr * 16 + quad * 4 + rg;
            float val = acc[j][rg] + bv + R[(size_t)(m0 + m) * 128 + nn];
            v[j][rg] = val;
            s[rg] += val; q[rg] += val * val;
        }
    }
    #pragma unroll
    for (int o = 8; o > 0; o >>= 1) {
        #pragma unroll
        for (int rg = 0; rg < 4; ++rg) {
            s[rg] += __shfl_xor(s[rg], o);
            q[rg] += __shfl_xor(q[rg], o);
        }
    }
    if (l15 == 0) {
        #pragma unroll
        for (int rg = 0; rg < 4; ++rg) {
            int row = wr * 16 + quad * 4 + rg;
            pSum[wc][row] = s[rg];
            pSq[wc][row]  = q[rg];
        }
    }
    __syncthreads();
    #pragma unroll
    for (int rg = 0; rg < 4; ++rg) {
        int row = wr * 16 + quad * 4 + rg;
        float tot = pSum[0][row] + pSum[1][row];
        float tq  = pSq[0][row]  + pSq[1][row];
        float mean = tot * (1.0f / 128.0f);
        float var = tq * (1.0f / 128.0f) - mean * mean;
        float rst = rsqrtf(var + 1e-5f);
        size_t rb = (size_t)(m0 + row) * 128;
        #pragma unroll
        for (int j = 0; j < 4; ++j) {
            int nn = wc * 64 + j * 16 + l15;
            Dres[rb + nn] = v[j][rg];
            Aout[rb + nn] = __float2bfloat16((v[j][rg] - mean) * rst * sG[nn] + sB[nn]);
        }
    }
}

// ---- GEMM (N=128) + residual + FINAL LayerNorm + transposed store to (b,c,t,y,x).
__global__ __launch_bounds__(256) void k_gemm_lnout(const bf16* __restrict__ A,
                                                    const bf16* __restrict__ Bt,
                                                    const float* __restrict__ bias,
                                                    const float* __restrict__ R,
                                                    const float* __restrict__ g,
                                                    const float* __restrict__ be,
                                                    float* __restrict__ out,
                                                    int K) {
    constexpr int LDK = 40;
    __shared__ bf16 As[32 * LDK];
    __shared__ bf16 Bs[128 * LDK];
    __shared__ float ot[32][133];    // pad 133: conflict-free transposed reads
    __shared__ float sG[128], sB[128];
    int tid = threadIdx.x;
    int wave = tid >> 6, lane = tid & 63;
    int l15 = lane & 15, quad = lane >> 4;
    int wr = wave >> 1, wc = wave & 1;
    int m0 = blockIdx.x * 32;
    if (tid < 128) { sG[tid] = g[tid]; sB[tid] = be[tid]; }
    floatx4 acc[4];
    #pragma unroll
    for (int j = 0; j < 4; ++j) acc[j] = (floatx4){0.f, 0.f, 0.f, 0.f};

    for (int k0 = 0; k0 < K; k0 += 32) {
        if (tid < 128) {
            int row = tid >> 2, off = (tid & 3) * 8;
            *(uint4*)&As[row * LDK + off] =
                *(const uint4*)&A[(size_t)(m0 + row) * K + k0 + off];
        }
        #pragma unroll
        for (int c = tid; c < 512; c += 256) {
            int row = c >> 2, off = (c & 3) * 8;
            *(uint4*)&Bs[row * LDK + off] =
                *(const uint4*)&Bt[(size_t)row * K + k0 + off];
        }
        __syncthreads();
        short8 af = *(const short8*)&As[(wr * 16 + l15) * LDK + quad * 8];
        short8 bfr[4];
        #pragma unroll
        for (int j = 0; j < 4; ++j)
            bfr[j] = *(const short8*)&Bs[(wc * 64 + j * 16 + l15) * LDK + quad * 8];
        #pragma unroll
        for (int j = 0; j < 4; ++j)
            acc[j] = __builtin_amdgcn_mfma_f32_16x16x32_bf16(af, bfr[j], acc[j], 0, 0, 0);
        __syncthreads();
    }
    #pragma unroll
    for (int j = 0; j < 4; ++j) {
        int nn = wc * 64 + j * 16 + l15;
        float bv = bias[nn];
        #pragma unroll
        for (int rg = 0; rg < 4; ++rg) {
            int m = wr * 16 + quad * 4 + rg;
            ot[m][nn] = acc[j][rg] + bv + R[(size_t)(m0 + m) * 128 + nn];
        }
    }
    __syncthreads();
    int row = tid >> 3, sub = tid & 7;
    float vv[16];
    float s = 0.f, q = 0.f;
    #pragma unroll
    for (int i = 0; i < 16; ++i) {
        float v = ot[row][sub * 16 + i];
        vv[i] = v; s += v; q += v * v;
    }
    #pragma unroll
    for (int o = 4; o > 0; o >>= 1) { s += __shfl_xor(s, o); q += __shfl_xor(q, o); }
    float mean = s * (1.0f / 128.0f);
    float var = q * (1.0f / 128.0f) - mean * mean;
    float rst = rsqrtf(var + 1e-5f);
    #pragma unroll
    for (int i = 0; i < 16; ++i) {
        int ch = sub * 16 + i;
        ot[row][ch] = (vv[i] - mean) * rst * sG[ch] + sB[ch];
    }
    __syncthreads();
    int n = m0 / 1600, rem0 = m0 % 1600;
    int b = n >> 3, t = n & 7;
    #pragma unroll
    for (int it = 0; it < 16; ++it) {
        int idx = it * 256 + tid;
        int ch = idx >> 5, tk = idx & 31;
        out[((size_t)((b * 128 + ch) * 8 + t)) * 1600 + rem0 + tk] = ot[tk][ch];
    }
}

// ---- row-tiled 7x7 neighborhood attention; f16 K + fdot2 logits.
// v5: 320-thread blocks (5 waves) eliminate the tail imbalance: logits 280 items
// <= 1/thread (was: 24 threads did 2 -> 2x phase cost), PV 320 items = exactly 1
// (was: 64 threads did 2). Staging 1120/320 = 3.5 iters. LDS unchanged (5 blk/CU).
__global__ __launch_bounds__(320) void k_attn(const bf16* __restrict__ qkv,
                                              const float* __restrict__ rpb,
                                              bf16* __restrict__ out) {
    int raw = blockIdx.x;                       // grid 2560
    int blk = (raw & 7) * 320 + (raw >> 3);     // chunk per XCD
    int head = blk & 3;
    int ny = blk >> 2;
    int n = ny / 40, y = ny % 40;
    int sy = min(max(y - 3, 0), HH - 7);
    __shared__ __align__(16) short KVs[7 * KVP];   // K (f16, stride 40) then V (bf16, stride 32)
    __shared__ __align__(16) float lg[40][LGS];
    int tid = threadIdx.x;
    // phase 1: K window, bf16 -> f16 (packed cvt)
    for (int i2 = tid; i2 < 1120; i2 += 320) {
        int d8 = i2 & 3, kx = (i2 >> 2) % 40, ky = i2 / 160;
        size_t base = ((size_t)(n * 1600 + (sy + ky) * 40 + kx)) * 384 + 128 + head * 32 + d8 * 8;
        union { uint4 u; __hip_bfloat162 b[4]; } U;
        U.u = *(const uint4*)(qkv + base);
        union { short8 s; h2 h[4]; } W;
        #pragma unroll
        for (int c = 0; c < 4; ++c) {
            float2 f = __bfloat1622float2(U.b[c]);
            W.h[c] = cvt2h(f.x, f.y);
        }
        *(short8*)&KVs[ky * KVP + kx * 40 + d8 * 8] = W.s;
    }
    __syncthreads();
    // logits: thread per (xq, ky) -- one item per thread (280 of 320 active)
    if (tid < 280) {
        int xq = tid / 7, ky = tid - (tid / 7) * 7;
        int sx = min(max(xq - 3, 0), WW - 7);
        const bf16* qg = qkv + ((size_t)(n * 1600 + y * 40 + xq)) * 384 + head * 32;
        union { uint4 u; __hip_bfloat162 b[4]; } U[4];
        #pragma unroll
        for (int u = 0; u < 4; ++u) U[u].u = *(const uint4*)(qg + u * 8);
        h2 qh[16];
        #pragma unroll
        for (int c = 0; c < 16; ++c) {
            float2 f = __bfloat1622float2(U[c >> 2].b[c & 3]);
            qh[c] = cvt2h(f.x, f.y);
        }
        const float* rb = rpb + head * 169 + (sy + ky - y + 6) * 13 + (sx - xq + 6);
        int kbase = ky * KVP + sx * 40;
        #pragma unroll
        for (int jx = 0; jx < 7; ++jx) {
            const h2* kp = (const h2*)&KVs[kbase + jx * 40];
            float dot = 0.f;
            #pragma unroll
            for (int c = 0; c < 16; ++c)
                dot = __builtin_amdgcn_fdot2(qh[c], kp[c], dot, false);
            lg[xq][ky * 8 + jx] = dot * 0.1767766952966369f + rb[jx];
        }
        lg[xq][ky * 8 + 7] = -1e30f;   // pad slot: self-masking in softmax & PV
    }
    __syncthreads();
    // phase 2: V window (raw bf16 bits, stride 32), softmax concurrently
    for (int i2 = tid; i2 < 1120; i2 += 320) {
        int d8 = i2 & 3, kx = (i2 >> 2) % 40, ky = i2 / 160;
        size_t base = ((size_t)(n * 1600 + (sy + ky) * 40 + kx)) * 384 + 256 + head * 32 + d8 * 8;
        *(uint4*)&KVs[ky * VP + kx * 32 + d8 * 8] = *(const uint4*)(qkv + base);
    }
    // wave-parallel softmax over 56 padded slots: 4 lanes/row
    if (tid < 160) {
        int row = tid >> 2, q = tid & 3;
        int nb = (q == 3) ? 2 : 4;        // q<3: slots [q*16,+16); q3: [48,56)
        const float4* lp = (const float4*)&lg[row][q * 16];
        float4 f[4];
        #pragma unroll
        for (int i = 0; i < 4; ++i)
            if (i < nb) f[i] = lp[i];
        float m = -1e30f;
        #pragma unroll
        for (int i = 0; i < 4; ++i)
            if (i < nb) m = fmaxf(m, fmaxf(fmaxf(f[i].x, f[i].y), fmaxf(f[i].z, f[i].w)));
        m = fmaxf(m, __shfl_xor(m, 1));
        m = fmaxf(m, __shfl_xor(m, 2));
        float s = 0.f;
        #pragma unroll
        for (int i = 0; i < 4; ++i)
            if (i < nb) {
                f[i].x = expf(f[i].x - m); f[i].y = expf(f[i].y - m);
                f[i].z = expf(f[i].z - m); f[i].w = expf(f[i].w - m);
                s += f[i].x + f[i].y + f[i].z + f[i].w;
            }
        s += __shfl_xor(s, 1);
        s += __shfl_xor(s, 2);
        float inv = 1.0f / s;
        float4* sp = (float4*)&lg[row][q * 16];
        #pragma unroll
        for (int i = 0; i < 4; ++i)
            if (i < nb) {
                f[i].x *= inv; f[i].y *= inv; f[i].z *= inv; f[i].w *= inv;
                sp[i] = f[i];
            }
    }
    __syncthreads();
    // PV: thread per (xq, chan-quad) -- exactly one item per thread
    {
        int xq = tid >> 3, cq = tid & 7;
        int sx = min(max(xq - 3, 0), WW - 7);
        float a0 = 0.f, a1 = 0.f, a2 = 0.f, a3 = 0.f;
        #pragma unroll
        for (int ky = 0; ky < 7; ++ky) {
            float4 pa = *(const float4*)&lg[xq][ky * 8];
            float4 pb = *(const float4*)&lg[xq][ky * 8 + 4];
            float ps[8] = {pa.x, pa.y, pa.z, pa.w, pb.x, pb.y, pb.z, pb.w};
            int vb = ky * VP + sx * 32 + cq * 4;
            #pragma unroll
            for (int jx = 0; jx < 7; ++jx) {
                float p = ps[jx];
                uint2 vv = *(const uint2*)&KVs[vb + jx * 32];
                float2 v0 = __bfloat1622float2(*(const __hip_bfloat162*)&vv.x);
                float2 v1 = __bfloat1622float2(*(const __hip_bfloat162*)&vv.y);
                a0 += p * v0.x; a1 += p * v0.y;
                a2 += p * v1.x; a3 += p * v1.y;
            }
        }
        __hip_bfloat162 o01, o23;
        o01.x = __float2bfloat16(a0); o01.y = __float2bfloat16(a1);
        o23.x = __float2bfloat16(a2); o23.y = __float2bfloat16(a3);
        bf16* op = out + ((size_t)(n * 1600 + y * 40 + xq)) * 128 + head * 32 + cq * 4;
        *(__hip_bfloat162*)op = o01;
        *(__hip_bfloat162*)(op + 2) = o23;
    }
}

// ---- depthwise 3x3x3 conv + bias + exact GELU; bf16 in (halved HBM traffic,
// 26MB hidden fits aggregate L2), bf16 out. 512 thr x 1 ch, branch-free loads,
// one-iteration prefetch, compile-time x-half specialization.
template<int X0>
__device__ __forceinline__ void dw_body(const bf16* __restrict__ inp,
                                        const int* roff, const float* wr,
                                        float bs, int m, size_t outbase,
                                        bf16* __restrict__ outp) {
    float c0[9], c1[9], c2[9];
    #pragma unroll
    for (int p = 0; p < 9; ++p) {
        c0[p] = (X0 > 0) ? __bfloat162float(inp[roff[p] + (X0 - 1) * 512 + m]) : 0.f;
        c1[p] = __bfloat162float(inp[roff[p] + X0 * 512 + m]);
        c2[p] = __bfloat162float(inp[roff[p] + (X0 + 1) * 512 + m]);
    }
    #pragma unroll
    for (int xi = 0; xi < 20; ++xi) {
        constexpr int XN_BASE = X0 + 2;
        int x = X0 + xi;
        float cn[9];
        if (XN_BASE + xi < 40) {
            #pragma unroll
            for (int p = 0; p < 9; ++p)
                cn[p] = __bfloat162float(inp[roff[p] + (XN_BASE + xi) * 512 + m]);
        } else {
            #pragma unroll
            for (int p = 0; p < 9; ++p) cn[p] = 0.f;
        }
        float acc = bs;
        #pragma unroll
        for (int p = 0; p < 9; ++p)
            acc += wr[p * 3 + 0] * c0[p] + wr[p * 3 + 1] * c1[p] + wr[p * 3 + 2] * c2[p];
        float g = 0.5f * acc * (1.0f + erff(acc * 0.70710678118654752f));
        outp[outbase + (size_t)x * 512] = __float2bfloat16(g);
        #pragma unroll
        for (int p = 0; p < 9; ++p) { c0[p] = c1[p]; c1[p] = c2[p]; c2[p] = cn[p]; }
    }
}

__global__ __launch_bounds__(512, 4) void k_dwconv(const bf16* __restrict__ inp,
                                                   const float* __restrict__ w,
                                                   const float* __restrict__ bias,
                                                   bf16* __restrict__ outp) {
    int raw = blockIdx.x;                       // grid 1280
    int blk = (raw & 7) * 160 + (raw >> 3);     // chunk per XCD
    int xh = blk & 1;
    int ny = blk >> 1;
    int n = ny / 40, y = ny - n * 40;
    int b = n >> 3, t = n & 7;
    int m = threadIdx.x;
    float wr[27];
    int roff[9];                                // wave-uniform -> SGPRs
    #pragma unroll
    for (int dt = 0; dt < 3; ++dt) {
        #pragma unroll
        for (int dy = 0; dy < 3; ++dy) {
            int p = dt * 3 + dy;
            int tt = t + dt - 1, yy = y + dy - 1;
            bool v = (tt >= 0 && tt < 8 && yy >= 0 && yy < 40);
            int tc = min(max(tt, 0), 7), yc = min(max(yy, 0), 39);
            roff[p] = ((b * 8 + tc) * 1600 + yc * 40) * 512;
            #pragma unroll
            for (int q = 0; q < 3; ++q)
                wr[p * 3 + q] = v ? w[(p * 3 + q) * 512 + m] : 0.f;
        }
    }
    float bs = bias[m];
    size_t outbase = ((size_t)(n * 1600 + y * 40)) * 512 + m;
    if (xh == 0)
        dw_body<0>(inp, roff, wr, bs, m, outbase, outp);
    else
        dw_body<20>(inp, roff, wr, bs, m, outbase, outp);
}

extern "C" void kernel_launch(void* const* d_in, const int* in_sizes, int n_in,
                              void* d_out, int out_size, void* d_ws, size_t ws_size,
                              hipStream_t stream) {
    const float* x      = (const float*)d_in[0];
    const float* ln1_g  = (const float*)d_in[1];
    const float* ln1_b  = (const float*)d_in[2];
    const float* qkv_w  = (const float*)d_in[3];
    const float* qkv_b  = (const float*)d_in[4];
    const float* rpb    = (const float*)d_in[5];
    const float* proj_w = (const float*)d_in[6];
    const float* proj_b = (const float*)d_in[7];
    const float* ln2_g  = (const float*)d_in[8];
    const float* ln2_b  = (const float*)d_in[9];
    const float* fc1_w  = (const float*)d_in[10];
    const float* fc1_b  = (const float*)d_in[11];
    const float* dw_w   = (const float*)d_in[12];
    const float* dw_b   = (const float*)d_in[13];
    const float* fc2_w  = (const float*)d_in[14];
    const float* fc2_b  = (const float*)d_in[15];
    const float* out_g  = (const float*)d_in[16];
    const float* out_b  = (const float*)d_in[17];
    float* out = (float*)d_out;

    // workspace: h f32 | f1b bf16 | qkvb bf16 | f2b bf16 | abufA bf16 | abufL bf16 | wt
    float* h     = (float*)d_ws;
    bf16* f1b    = (bf16*)(h + (size_t)NTOK * 128);
    bf16* qkvb   = f1b  + (size_t)NTOK * 512;
    bf16* f2b    = qkvb + (size_t)NTOK * 384;
    bf16* abufA  = f2b  + (size_t)NTOK * 512;
    bf16* abufL  = abufA + (size_t)NTOK * 128;
    bf16* wt     = abufL + (size_t)NTOK * 128;

    k_prep<<<96 + NIMG * 200, 256, 0, stream>>>(x, qkv_w, proj_w, fc1_w, fc2_w, h, wt);
    for (int l = 0; l < 2; ++l) {
        const bf16* wtl = wt + (size_t)l * WT_L;
        if (l == 0) {
            k_lngemm<bf16><<<dim3(3, 400), 256, 0, stream>>>(
                h, wtl + WT_QKV, ln1_g, ln1_b, qkv_b, qkvb, 384);
        } else {
            k_gemm_mfma<64, 128, 32, 64, bf16><<<dim3(3, 400), 256, 0, stream>>>(
                abufL, wtl + WT_QKV, qkv_b + 384, nullptr, qkvb, 128, 384);
        }
        k_attn<<<NIMG * HH * NHEAD, 320, 0, stream>>>(qkvb, rpb + l * 4 * 169, abufA);
        // proj + residual + fused LN2 epilogue -> abufL
        k_gemm_ln<<<800, 256, 0, stream>>>(
            abufA, wtl + WT_PROJ, proj_b + l * 128, h,
            ln2_g + l * 128, ln2_b + l * 128, h, abufL, 128);
        // fc1: bf16-A GEMM, bf16 out (halves write traffic; hidden fits L2)
        k_gemm_mfma<64, 128, 32, 64, bf16><<<dim3(4, 400), 256, 0, stream>>>(
            abufL, wtl + WT_FC1, fc1_b + l * 512, nullptr, f1b, 128, 512);
        k_dwconv<<<NIMG * HH * 2, 512, 0, stream>>>(f1b, dw_w + l * 27 * 512, dw_b + l * 512, f2b);
        if (l == 0) {
            // fc2 + residual + fused LN1(layer 1) epilogue -> abufL
            k_gemm_ln<<<800, 256, 0, stream>>>(
                f2b, wtl + WT_FC2, fc2_b, h,
                ln1_g + 128, ln1_b + 128, h, abufL, 512);
        } else {
            // fc2 + residual + FINAL LN + transposed store
            k_gemm_lnout<<<800, 256, 0, stream>>>(
                f2b, wtl + WT_FC2, fc2_b + 128, h, out_g, out_b, out, 512);
        }
    }
}